// Round 2
// baseline (6418.937 us; speedup 1.0000x reference)
//
#include <hip/hip_runtime.h>
#include <hip/hip_bf16.h>

// ---------------- constants ----------------
#define T_N    2048
#define H_N    32
#define NOPE_N 128
#define ROPE_N 64
#define VD_N   128
#define QLORA_N 1536
#define KVLORA_N 512
#define IDX_H_N 32
#define IDX_D_N 128
#define TOPK_N 512
#define HID_N  2048

// exact RNE float -> e4m3fn grid (|x| <= 448 guaranteed by caller's scaling)
static __device__ __forceinline__ float q_e4m3(float x) {
    float ax = fabsf(x);
    unsigned b = __float_as_uint(ax);
    int e = (int)(b >> 23) - 126;          // ax = m*2^e, m in [0.5,1) for normals
    int ue = (e - 4 > -9) ? (e - 4) : -9;  // mantissa=3 bits; subnormal floor 2^-9
    float ulp = __int_as_float((ue + 127) << 23);
    float q = rintf(ax / ulp) * ulp;       // exact pow2 scaling, RNE
    return copysignf(q, x);
}

// ---------------- rope tables (f64 for accuracy at large angles) ----------------
__global__ void k_rope_tables(const int* __restrict__ pos, float* __restrict__ cosT,
                              float* __restrict__ sinT) {
    int t = blockIdx.x, i = threadIdx.x;   // 32 threads
    double inv = 1.0 / pow(10000.0, (double)i / 32.0);
    double ang = (double)pos[t] * inv;
    cosT[t * 32 + i] = (float)cos(ang);
    sinT[t * 32 + i] = (float)sin(ang);
}

// ---------------- generic 128x128 f32 GEMM (BK=8), optional B-transposed ----------------
template <bool BT>
__global__ __launch_bounds__(256) void gemm128(
    const float* __restrict__ A, const float* __restrict__ B, float* __restrict__ C,
    int M, int N, int K, int lda, int ldb, int ldc,
    long batchOffA, long batchOffB, long batchOffC) {
    const float* Ab = A + (size_t)batchOffA * blockIdx.z;
    const float* Bb = B + (size_t)batchOffB * blockIdx.z;
    int bm = blockIdx.y * 128, bn = blockIdx.x * 128;
    int tid = threadIdx.x;
    __shared__ float As[8][128];
    __shared__ float Bs[8][128];
    float acc[8][8];
#pragma unroll
    for (int i = 0; i < 8; ++i)
#pragma unroll
        for (int j = 0; j < 8; ++j) acc[i][j] = 0.f;
    int tx = tid & 15, ty = tid >> 4;
    int ar = tid >> 1, ak = (tid & 1) * 4;
    for (int k0 = 0; k0 < K; k0 += 8) {
        float4 av = *(const float4*)(Ab + (size_t)(bm + ar) * lda + k0 + ak);
        As[ak + 0][ar] = av.x; As[ak + 1][ar] = av.y;
        As[ak + 2][ar] = av.z; As[ak + 3][ar] = av.w;
        if (BT) {
            int n = tid >> 1, kk = (tid & 1) * 4;
            float4 bv = *(const float4*)(Bb + (size_t)(bn + n) * ldb + k0 + kk);
            Bs[kk + 0][n] = bv.x; Bs[kk + 1][n] = bv.y;
            Bs[kk + 2][n] = bv.z; Bs[kk + 3][n] = bv.w;
        } else {
            int kk = tid >> 5, n = (tid & 31) * 4;
            float4 bv = *(const float4*)(Bb + (size_t)(k0 + kk) * ldb + bn + n);
            Bs[kk][n + 0] = bv.x; Bs[kk][n + 1] = bv.y;
            Bs[kk][n + 2] = bv.z; Bs[kk][n + 3] = bv.w;
        }
        __syncthreads();
#pragma unroll
        for (int kk = 0; kk < 8; ++kk) {
            float4 a0 = *(const float4*)(&As[kk][ty * 8]);
            float4 a1 = *(const float4*)(&As[kk][ty * 8 + 4]);
            float4 b0 = *(const float4*)(&Bs[kk][tx * 8]);
            float4 b1 = *(const float4*)(&Bs[kk][tx * 8 + 4]);
            float a[8] = {a0.x, a0.y, a0.z, a0.w, a1.x, a1.y, a1.z, a1.w};
            float b[8] = {b0.x, b0.y, b0.z, b0.w, b1.x, b1.y, b1.z, b1.w};
#pragma unroll
            for (int i = 0; i < 8; ++i)
#pragma unroll
                for (int j = 0; j < 8; ++j) acc[i][j] = fmaf(a[i], b[j], acc[i][j]);
        }
        __syncthreads();
    }
    size_t cbase = (size_t)batchOffC * blockIdx.z;
#pragma unroll
    for (int i = 0; i < 8; ++i) {
        size_t r = bm + ty * 8 + i;
#pragma unroll
        for (int j = 0; j < 8; ++j) {
            size_t c = bn + tx * 8 + j;
            C[cbase + r * (size_t)ldc + c] = acc[i][j];
        }
    }
}

// ---------------- kv postprocess: rms_norm(kv_c) + interleaved rope on k_pe ----------------
__global__ __launch_bounds__(256) void k_kv_post(const float* __restrict__ kv,
                                                 const float* __restrict__ lnw,
                                                 const float* __restrict__ cosT,
                                                 const float* __restrict__ sinT,
                                                 float* __restrict__ kvn, float* __restrict__ kpe) {
    int t = blockIdx.x, tid = threadIdx.x;
    const float* row = kv + (size_t)t * 576;
    float v0 = row[tid], v1 = row[tid + 256];
    float s = v0 * v0 + v1 * v1;
    for (int o = 32; o > 0; o >>= 1) s += __shfl_down(s, o);
    __shared__ float sm[4];
    if ((tid & 63) == 0) sm[tid >> 6] = s;
    __syncthreads();
    float tot = sm[0] + sm[1] + sm[2] + sm[3];
    float inv = 1.f / sqrtf(tot / 512.f + 1e-6f);
    kvn[(size_t)t * 512 + tid] = v0 * inv * lnw[tid];
    kvn[(size_t)t * 512 + tid + 256] = v1 * inv * lnw[tid + 256];
    if (tid < 32) {
        float c = cosT[t * 32 + tid], sn = sinT[t * 32 + tid];
        float x1 = row[512 + 2 * tid], x2 = row[512 + 2 * tid + 1];
        kpe[(size_t)t * 64 + 2 * tid] = x1 * c - x2 * sn;
        kpe[(size_t)t * 64 + 2 * tid + 1] = x2 * c + x1 * sn;
    }
}

// ---------------- interleaved rope on q_pe (dims 128..191 of qfull), in place ----------------
__global__ __launch_bounds__(256) void k_rope_q(float* __restrict__ q,
                                                const float* __restrict__ cosT,
                                                const float* __restrict__ sinT) {
    int b = blockIdx.x * 8 + (threadIdx.x >> 5);  // b = t*32 + h
    int i = threadIdx.x & 31;
    int t = b >> 5;
    float* p = q + (size_t)b * 192 + 128;
    float c = cosT[t * 32 + i], s = sinT[t * 32 + i];
    float x1 = p[2 * i], x2 = p[2 * i + 1];
    p[2 * i] = x1 * c - x2 * s;
    p[2 * i + 1] = x2 * c + x1 * s;
}

// ---------------- indexer k: layernorm + neox rope + fp8 quant (in place) ----------------
__global__ __launch_bounds__(128) void k_ki_post(float* __restrict__ kidx,
                                                 const float* __restrict__ g,
                                                 const float* __restrict__ be,
                                                 const float* __restrict__ cosT,
                                                 const float* __restrict__ sinT,
                                                 float* __restrict__ kscale) {
    int t = blockIdx.x, i = threadIdx.x;
    float* row = kidx + (size_t)t * 128;
    float x = row[i];
    float s = x;
    for (int o = 32; o > 0; o >>= 1) s += __shfl_down(s, o);
    __shared__ float sm[2];
    if ((i & 63) == 0) sm[i >> 6] = s;
    __syncthreads();
    float mean = (sm[0] + sm[1]) / 128.f;
    float d = x - mean;
    float s2 = d * d;
    for (int o = 32; o > 0; o >>= 1) s2 += __shfl_down(s2, o);
    __shared__ float sv[2];
    if ((i & 63) == 0) sv[i >> 6] = s2;
    __syncthreads();
    float var = (sv[0] + sv[1]) / 128.f;
    float nrm = d * (1.f / sqrtf(var + 1e-6f)) * g[i] + be[i];
    __shared__ float buf[128];
    buf[i] = nrm;
    __syncthreads();
    float out;
    if (i < 32)      out = buf[i] * cosT[t * 32 + i] - buf[i + 32] * sinT[t * 32 + i];
    else if (i < 64) out = buf[i] * cosT[t * 32 + i - 32] + buf[i - 32] * sinT[t * 32 + i - 32];
    else             out = nrm;
    float a = fabsf(out);
    for (int o = 32; o > 0; o >>= 1) a = fmaxf(a, __shfl_down(a, o));
    __shared__ float am[2];
    if ((i & 63) == 0) am[i >> 6] = a;
    __syncthreads();
    float amax = fmaxf(fmaxf(am[0], am[1]), 1e-10f);
    float scale = __int_as_float((((int)ceilf(log2f(amax / 448.f))) + 127) << 23);
    row[i] = q_e4m3(out / scale);
    if (i == 0) kscale[t] = scale;
}

// ---------------- indexer q: neox rope + fp8 quant per (t,h) row (in place) ----------------
__global__ __launch_bounds__(128) void k_qi_post(float* __restrict__ qi,
                                                 const float* __restrict__ cosT,
                                                 const float* __restrict__ sinT,
                                                 float* __restrict__ qscale) {
    int b = blockIdx.x;            // b = t*32 + h
    int t = b >> 5;
    int i = threadIdx.x;
    float* row = qi + (size_t)b * 128;
    float x = row[i];
    __shared__ float buf[128];
    buf[i] = x;
    __syncthreads();
    float out;
    if (i < 32)      out = buf[i] * cosT[t * 32 + i] - buf[i + 32] * sinT[t * 32 + i];
    else if (i < 64) out = buf[i] * cosT[t * 32 + i - 32] + buf[i - 32] * sinT[t * 32 + i - 32];
    else             out = x;
    float a = fabsf(out);
    for (int o = 32; o > 0; o >>= 1) a = fmaxf(a, __shfl_down(a, o));
    __shared__ float am[2];
    if ((i & 63) == 0) am[i >> 6] = a;
    __syncthreads();
    float amax = fmaxf(fmaxf(am[0], am[1]), 1e-10f);
    float scale = __int_as_float((((int)ceilf(log2f(amax / 448.f))) + 127) << 23);
    row[i] = q_e4m3(out / scale);
    if (i == 0) qscale[b] = scale;
}

// ---------------- indexer weights: (hs @ W_iw) * qscale * idx_scales ----------------
__global__ __launch_bounds__(256) void k_wiw(const float* __restrict__ hs,
                                             const float* __restrict__ W_iw,
                                             const float* __restrict__ qscale,
                                             float* __restrict__ wts) {
    int t = blockIdx.x, tid = threadIdx.x;
    __shared__ float hr[2048];
    for (int i = tid; i < 2048; i += 256) hr[i] = hs[(size_t)t * 2048 + i];
    __syncthreads();
    int h = tid & 31, p = tid >> 5;
    float s = 0;
    for (int k = p * 256; k < p * 256 + 256; ++k) s = fmaf(hr[k], W_iw[(size_t)k * 32 + h], s);
    __shared__ float part[8][32];
    part[p][h] = s;
    __syncthreads();
    if (tid < 32) {
        float tot = 0;
#pragma unroll
        for (int pp = 0; pp < 8; ++pp) tot += part[pp][tid];
        const float a = (float)0.08838834764831845;   // 128^-0.5
        const float b = (float)0.1767766952966369;    // 32^-0.5
        wts[t * 32 + tid] = tot * qscale[t * 32 + tid] * a * b;
    }
}

// ---------------- indexer score: score[t,s] = sum_h w[t,h]*relu((q.k)*kscale[s]) ----------------
__global__ __launch_bounds__(256) void k_score(const float* __restrict__ q,
                                               const float* __restrict__ k,
                                               const float* __restrict__ kscale,
                                               const float* __restrict__ wts,
                                               float* __restrict__ score) {
    int b = blockIdx.x;
    int ti = (int)((sqrtf(8.f * b + 1.f) - 1.f) * 0.5f);
    while ((ti + 1) * (ti + 2) / 2 <= b) ++ti;
    while (ti * (ti + 1) / 2 > b) --ti;
    int si = b - ti * (ti + 1) / 2;
    int t0 = ti * 32, s0 = si * 32;
    __shared__ float qs[32][132];
    __shared__ float ks_[32][132];
    __shared__ float ksc[32];
    __shared__ float w_s[32];
    int tid = threadIdx.x;
    if (tid < 32) ksc[tid] = kscale[s0 + tid];
    // k tile: constant over h
#pragma unroll
    for (int i = 0; i < 4; ++i) {
        int fi = tid + i * 256;
        int r = fi >> 5, d4 = (fi & 31) * 4;
        float4 u = *(const float4*)&k[(size_t)(s0 + r) * 128 + d4];
        ks_[r][d4 + 0] = u.x; ks_[r][d4 + 1] = u.y; ks_[r][d4 + 2] = u.z; ks_[r][d4 + 3] = u.w;
    }
    int tt = tid & 31, sg = tid >> 5;  // thread computes (tt, sg*4 .. sg*4+3)
    float acc0 = 0, acc1 = 0, acc2 = 0, acc3 = 0;
    for (int h = 0; h < 32; ++h) {
        __syncthreads();
        if (tid < 32) w_s[tid] = wts[(t0 + tid) * 32 + h];
#pragma unroll
        for (int i = 0; i < 4; ++i) {
            int fi = tid + i * 256;
            int r = fi >> 5, d4 = (fi & 31) * 4;
            float4 v = *(const float4*)&q[((size_t)(t0 + r) * 32 + h) * 128 + d4];
            qs[r][d4 + 0] = v.x; qs[r][d4 + 1] = v.y; qs[r][d4 + 2] = v.z; qs[r][d4 + 3] = v.w;
        }
        __syncthreads();
        float d0 = 0, d1 = 0, d2 = 0, d3 = 0;
#pragma unroll 4
        for (int d4 = 0; d4 < 32; ++d4) {
            float4 qv = *(const float4*)&qs[tt][d4 * 4];
            float4 k0 = *(const float4*)&ks_[sg * 4 + 0][d4 * 4];
            float4 k1 = *(const float4*)&ks_[sg * 4 + 1][d4 * 4];
            float4 k2 = *(const float4*)&ks_[sg * 4 + 2][d4 * 4];
            float4 k3 = *(const float4*)&ks_[sg * 4 + 3][d4 * 4];
            d0 = fmaf(qv.x, k0.x, fmaf(qv.y, k0.y, fmaf(qv.z, k0.z, fmaf(qv.w, k0.w, d0))));
            d1 = fmaf(qv.x, k1.x, fmaf(qv.y, k1.y, fmaf(qv.z, k1.z, fmaf(qv.w, k1.w, d1))));
            d2 = fmaf(qv.x, k2.x, fmaf(qv.y, k2.y, fmaf(qv.z, k2.z, fmaf(qv.w, k2.w, d2))));
            d3 = fmaf(qv.x, k3.x, fmaf(qv.y, k3.y, fmaf(qv.z, k3.z, fmaf(qv.w, k3.w, d3))));
        }
        float w = w_s[tt];
        acc0 += w * fmaxf(d0 * ksc[sg * 4 + 0], 0.f);
        acc1 += w * fmaxf(d1 * ksc[sg * 4 + 1], 0.f);
        acc2 += w * fmaxf(d2 * ksc[sg * 4 + 2], 0.f);
        acc3 += w * fmaxf(d3 * ksc[sg * 4 + 3], 0.f);
    }
    int t = t0 + tt;
    float accs[4] = {acc0, acc1, acc2, acc3};
#pragma unroll
    for (int j = 0; j < 4; ++j) {
        int s = s0 + sg * 4 + j;
        if (s <= t) score[(size_t)t * T_N + s] = accs[j];
    }
}

// ---------------- top-512 per row (stable: ties -> lowest index, like jax.lax.top_k) ------
__global__ __launch_bounds__(256) void k_topk(const float* __restrict__ score,
                                              int* __restrict__ tki, int* __restrict__ tkc) {
    int t = blockIdx.x;
    int n = t + 1;
    int tid = threadIdx.x;
    if (n <= TOPK_N) {
        for (int i = tid; i < n; i += 256) tki[(size_t)t * TOPK_N + i] = i;
        if (tid == 0) tkc[t] = n;
        return;
    }
    __shared__ unsigned keys[2048];
    const float* row = score + (size_t)t * T_N;
    for (int i = tid; i < n; i += 256) {
        float f = row[i] + 0.f;  // normalize -0 -> +0
        unsigned u = __float_as_uint(f);
        u = (u & 0x80000000u) ? ~u : (u | 0x80000000u);
        keys[i] = u;
    }
    __shared__ int hist[256];
    __shared__ unsigned sh_prefix;
    __shared__ int sh_need;
    if (tid == 0) { sh_prefix = 0u; sh_need = TOPK_N; }
    __syncthreads();
    unsigned maskHi = 0;
    for (int level = 3; level >= 0; --level) {
        hist[tid] = 0;
        __syncthreads();
        unsigned prefix = sh_prefix;
        int shift = level * 8;
        for (int i = tid; i < n; i += 256) {
            unsigned kk = keys[i];
            if ((kk & maskHi) == prefix) atomicAdd(&hist[(kk >> shift) & 255], 1);
        }
        __syncthreads();
        if (tid == 0) {
            int need = sh_need, cum = 0, bsel = 255;
            for (int bb = 255; bb >= 0; --bb) {
                if (cum + hist[bb] >= need) { bsel = bb; break; }
                cum += hist[bb];
            }
            sh_need = need - cum;
            sh_prefix = prefix | ((unsigned)bsel << shift);
        }
        __syncthreads();
        maskHi |= (0xFFu << shift);
    }
    unsigned thr = sh_prefix;
    int needEq = sh_need;  // count of ==thr to take, in ascending index order
    // contiguous chunks of 8 per thread -> ordered scans
    int base = tid * 8;
    int eqcnt = 0;
#pragma unroll
    for (int j = 0; j < 8; ++j) {
        int i = base + j;
        if (i < n && keys[i] == thr) eqcnt++;
    }
    __shared__ int scn[256];
    scn[tid] = eqcnt;
    __syncthreads();
    for (int off = 1; off < 256; off <<= 1) {
        int add = (tid >= off) ? scn[tid - off] : 0;
        __syncthreads();
        scn[tid] += add;
        __syncthreads();
    }
    int eq_excl = scn[tid] - eqcnt;
    // count allowed per chunk
    int acnt = 0;
    {
        int eqr = eq_excl;
#pragma unroll
        for (int j = 0; j < 8; ++j) {
            int i = base + j;
            if (i < n) {
                unsigned kk = keys[i];
                bool a = (kk > thr) || (kk == thr && eqr < needEq);
                if (kk == thr) eqr++;
                if (a) acnt++;
            }
        }
    }
    __syncthreads();
    scn[tid] = acnt;
    __syncthreads();
    for (int off = 1; off < 256; off <<= 1) {
        int add = (tid >= off) ? scn[tid - off] : 0;
        __syncthreads();
        scn[tid] += add;
        __syncthreads();
    }
    int pos = scn[tid] - acnt;
    {
        int eqr = eq_excl;
#pragma unroll
        for (int j = 0; j < 8; ++j) {
            int i = base + j;
            if (i < n) {
                unsigned kk = keys[i];
                bool a = (kk > thr) || (kk == thr && eqr < needEq);
                if (kk == thr) eqr++;
                if (a) tki[(size_t)t * TOPK_N + (pos++)] = i;
            }
        }
    }
    if (tid == 0) tkc[t] = TOPK_N;
}

// ---- fused sparse attention: scores (via k_up) -> softmax -> o_lat -> W_UV -> v ----------
__global__ __launch_bounds__(256) void k_attn(const float* __restrict__ qfull,
                                              const float* __restrict__ k_up,
                                              const float* __restrict__ kvn,
                                              const float* __restrict__ kpe,
                                              const float* __restrict__ W_kvb,
                                              const int* __restrict__ tki,
                                              const int* __restrict__ tkc,
                                              float* __restrict__ v) {
    int t = blockIdx.x, h = blockIdx.y;
    int tid = threadIdx.x;
    int S = tkc[t];
    __shared__ float qn[128];
    __shared__ float qp[64];
    __shared__ float sc[512];
    __shared__ float ol[512];
    __shared__ int idx[512];
    if (tid < 128)      qn[tid] = qfull[((size_t)t * H_N + h) * 192 + tid];
    else if (tid < 192) qp[tid - 128] = qfull[((size_t)t * H_N + h) * 192 + tid];
    for (int i = tid; i < S; i += 256) idx[i] = tki[(size_t)t * TOPK_N + i];
    __syncthreads();
    int lane = tid & 63, w = tid >> 6;
    const float SCALE_F = (float)0.07216878364870323;  // 192^-0.5
    for (int j = w; j < S; j += 4) {
        int s = idx[j];
        const float* ku = k_up + ((size_t)s * H_N + h) * 128;
        float acc = qn[lane] * ku[lane];
        acc = fmaf(qn[lane + 64], ku[lane + 64], acc);
        acc = fmaf(qp[lane], kpe[(size_t)s * 64 + lane], acc);
        for (int o = 32; o > 0; o >>= 1) acc += __shfl_down(acc, o);
        if (lane == 0) sc[j] = acc * SCALE_F;
    }
    __syncthreads();
    float m = -1e38f;
    for (int i = tid; i < S; i += 256) m = fmaxf(m, sc[i]);
    for (int o = 32; o > 0; o >>= 1) m = fmaxf(m, __shfl_down(m, o));
    __shared__ float red[4];
    if (lane == 0) red[w] = m;
    __syncthreads();
    m = fmaxf(fmaxf(red[0], red[1]), fmaxf(red[2], red[3]));
    float lsum = 0;
    for (int i = tid; i < S; i += 256) {
        float e = expf(sc[i] - m);
        sc[i] = e;
        lsum += e;
    }
    for (int o = 32; o > 0; o >>= 1) lsum += __shfl_down(lsum, o);
    __shared__ float red2[4];
    if (lane == 0) red2[w] = lsum;
    __syncthreads();
    float dinv = 1.f / (red2[0] + red2[1] + red2[2] + red2[3]);
    float o0 = 0, o1 = 0;
    for (int j = 0; j < S; ++j) {
        const float* kr = kvn + (size_t)idx[j] * 512;
        float p = sc[j] * dinv;
        o0 = fmaf(p, kr[tid], o0);
        o1 = fmaf(p, kr[tid + 256], o1);
    }
    ol[tid] = o0;
    ol[tid + 256] = o1;
    __syncthreads();
    int vd = tid & 127, half = tid >> 7;
    float acc = 0;
    const float* wuv = W_kvb + (size_t)h * 256 + 128 + vd;
    for (int r = half * 256; r < half * 256 + 256; ++r)
        acc = fmaf(ol[r], wuv[(size_t)r * 8192], acc);
    __shared__ float vred[128];
    if (half == 1) vred[vd] = acc;
    __syncthreads();
    if (half == 0) v[((size_t)t * H_N + h) * 128 + vd] = acc + vred[vd];
}

// ---------------- launch ----------------
extern "C" void kernel_launch(void* const* d_in, const int* in_sizes, int n_in,
                              void* d_out, int out_size, void* d_ws, size_t ws_size,
                              hipStream_t stream) {
    (void)in_sizes; (void)n_in; (void)out_size; (void)ws_size;
    const int*   positions = (const int*)d_in[0];
    const float* hs        = (const float*)d_in[1];
    const float* q_c       = (const float*)d_in[2];
    const float* kv_lora   = (const float*)d_in[3];
    const float* W_qb      = (const float*)d_in[4];
    const float* W_kvb     = (const float*)d_in[5];
    const float* W_o       = (const float*)d_in[6];
    const float* kv_ln     = (const float*)d_in[7];
    const float* W_iq      = (const float*)d_in[8];
    const float* W_ik      = (const float*)d_in[9];
    const float* gamma     = (const float*)d_in[10];
    const float* beta      = (const float*)d_in[11];
    const float* W_iw      = (const float*)d_in[12];

    float* ws = (float*)d_ws;
    // workspace layout (floats); high-water 32,116,736 floats = 122.5 MiB
    float* cosT  = ws;                     // 65,536
    float* sinT  = ws + 65536;             // 65,536
    int*   tki   = (int*)(ws + 131072);    // 1,048,576 ints
    int*   tkc   = (int*)(ws + 1179648);   // 2,048 ints
    float* kvn   = ws + 1181696;           // 1,048,576
    float* kpe   = ws + 2230272;           // 131,072
    float* kidx  = ws + 2361344;           // 262,144
    float* kscale= ws + 2623488;           // 2,048
    float* qscale= ws + 2625536;           // 65,536
    float* wts   = ws + 2691072;           // 65,536
    float* qi    = ws + 2756608;           // 8,388,608 (phase A)
    float* score = ws + 11145216;          // 4,194,304 (phase A)
    float* qfull = ws + 2756608;           // 12,582,912 (phase B, aliases qi+score)
    float* k_up  = ws + 15339520;          // 8,388,608
    float* vbuf  = ws + 23728128;          // 8,388,608

    // 1. rope tables
    k_rope_tables<<<T_N, 32, 0, stream>>>(positions, cosT, sinT);
    // 2. indexer k: hs @ W_ik  (2048x128x2048)
    gemm128<false><<<dim3(1, 16, 1), 256, 0, stream>>>(
        hs, W_ik, kidx, T_N, 128, HID_N, HID_N, 128, 128, 0, 0, 0);
    // 3. LN + neox rope + fp8 quant
    k_ki_post<<<T_N, 128, 0, stream>>>(kidx, gamma, beta, cosT, sinT, kscale);
    // 4. indexer q: q_c @ W_iq  (2048x4096x1536)
    gemm128<false><<<dim3(32, 16, 1), 256, 0, stream>>>(
        q_c, W_iq, qi, T_N, 4096, QLORA_N, QLORA_N, 4096, 4096, 0, 0, 0);
    // 5. neox rope + fp8 quant per (t,h)
    k_qi_post<<<T_N * IDX_H_N, 128, 0, stream>>>(qi, cosT, sinT, qscale);
    // 6. indexer weights
    k_wiw<<<T_N, 256, 0, stream>>>(hs, W_iw, qscale, wts);
    // 7. indexer score (causal lower-triangular tiles)
    k_score<<<2080, 256, 0, stream>>>(qi, kidx, kscale, wts, score);
    // 8. top-512 per row
    k_topk<<<T_N, 256, 0, stream>>>(score, tki, tkc);
    // 9. kv rms_norm + k_pe rope
    k_kv_post<<<T_N, 256, 0, stream>>>(kv_lora, kv_ln, cosT, sinT, kvn, kpe);
    // 10. k_up[s,h,n] = sum_r kvn[s,r] * W_UK[r,h,n]  (batched over h)
    gemm128<false><<<dim3(1, 16, H_N), 256, 0, stream>>>(
        kvn, W_kvb, k_up, T_N, 128, KVLORA_N, KVLORA_N, 8192, H_N * 128, 0, 256, 128);
    // 11. q = q_c @ W_qb (2048x6144x1536) -- overwrites phase-A scratch (after topk)
    gemm128<false><<<dim3(48, 16, 1), 256, 0, stream>>>(
        q_c, W_qb, qfull, T_N, 6144, QLORA_N, QLORA_N, 6144, 6144, 0, 0, 0);
    // 12. rope q_pe in place
    k_rope_q<<<T_N * H_N / 8, 256, 0, stream>>>(qfull, cosT, sinT);
    // 13. fused sparse attention -> v (T, H*VD)
    k_attn<<<dim3(T_N, H_N), 256, 0, stream>>>(qfull, k_up, kvn, kpe, W_kvb, tki, tkc, vbuf);
    // 14. out = v @ W_o -> f32
    gemm128<false><<<dim3(16, 16, 1), 256, 0, stream>>>(
        vbuf, W_o, (float*)d_out, T_N, HID_N, H_N * VD_N, H_N * VD_N, HID_N, HID_N, 0, 0, 0);
}

// Round 3
// 2999.710 us; speedup vs baseline: 2.1399x; 2.1399x over previous
//
#include <hip/hip_runtime.h>
#include <hip/hip_bf16.h>

// ---------------- constants ----------------
#define T_N    2048
#define H_N    32
#define NOPE_N 128
#define ROPE_N 64
#define VD_N   128
#define QLORA_N 1536
#define KVLORA_N 512
#define IDX_H_N 32
#define IDX_D_N 128
#define TOPK_N 512
#define HID_N  2048

typedef __attribute__((ext_vector_type(8))) short bf16x8;
typedef __attribute__((ext_vector_type(4))) float f32x4;
typedef unsigned short ushortT;

#define SCALE_F 0.07216878364870323f  // (NOPE+ROPE)^-0.5 = 192^-0.5

static __device__ __forceinline__ ushortT f2bf(float x) {
    __hip_bfloat16 b = __float2bfloat16(x);
    return *(ushortT*)&b;
}

// exact RNE float -> e4m3fn grid (|x| <= 448 guaranteed by caller's scaling)
static __device__ __forceinline__ float q_e4m3(float x) {
    float ax = fabsf(x);
    unsigned b = __float_as_uint(ax);
    int e = (int)(b >> 23) - 126;
    int ue = (e - 4 > -9) ? (e - 4) : -9;
    float ulp = __int_as_float((ue + 127) << 23);
    float q = rintf(ax / ulp) * ulp;
    return copysignf(q, x);
}

// ---------------- rope tables (f64 for accuracy at large angles) ----------------
__global__ void k_rope_tables(const int* __restrict__ pos, float* __restrict__ cosT,
                              float* __restrict__ sinT) {
    int t = blockIdx.x, i = threadIdx.x;   // 32 threads
    double inv = 1.0 / pow(10000.0, (double)i / 32.0);
    double ang = (double)pos[t] * inv;
    cosT[t * 32 + i] = (float)cos(ang);
    sinT[t * 32 + i] = (float)sin(ang);
}

// ---------------- generic 128x128 f32 GEMM (BK=8), optional B-transposed ----------------
// BF16S: write bf16(acc*scaleC) to ushort C instead of f32.
template <bool BT, bool BF16S>
__global__ __launch_bounds__(256) void gemm128(
    const float* __restrict__ A, const float* __restrict__ B, void* __restrict__ Cv,
    int M, int N, int K, int lda, int ldb, int ldc,
    long batchOffA, long batchOffB, long batchOffC, float scaleC) {
    const float* Ab = A + (size_t)batchOffA * blockIdx.z;
    const float* Bb = B + (size_t)batchOffB * blockIdx.z;
    int bm = blockIdx.y * 128, bn = blockIdx.x * 128;
    int tid = threadIdx.x;
    __shared__ float As[8][128];
    __shared__ float Bs[8][128];
    float acc[8][8];
#pragma unroll
    for (int i = 0; i < 8; ++i)
#pragma unroll
        for (int j = 0; j < 8; ++j) acc[i][j] = 0.f;
    int tx = tid & 15, ty = tid >> 4;
    int ar = tid >> 1, ak = (tid & 1) * 4;
    for (int k0 = 0; k0 < K; k0 += 8) {
        float4 av = *(const float4*)(Ab + (size_t)(bm + ar) * lda + k0 + ak);
        As[ak + 0][ar] = av.x; As[ak + 1][ar] = av.y;
        As[ak + 2][ar] = av.z; As[ak + 3][ar] = av.w;
        if (BT) {
            int n = tid >> 1, kk = (tid & 1) * 4;
            float4 bv = *(const float4*)(Bb + (size_t)(bn + n) * ldb + k0 + kk);
            Bs[kk + 0][n] = bv.x; Bs[kk + 1][n] = bv.y;
            Bs[kk + 2][n] = bv.z; Bs[kk + 3][n] = bv.w;
        } else {
            int kk = tid >> 5, n = (tid & 31) * 4;
            float4 bv = *(const float4*)(Bb + (size_t)(k0 + kk) * ldb + bn + n);
            Bs[kk][n + 0] = bv.x; Bs[kk][n + 1] = bv.y;
            Bs[kk][n + 2] = bv.z; Bs[kk][n + 3] = bv.w;
        }
        __syncthreads();
#pragma unroll
        for (int kk = 0; kk < 8; ++kk) {
            float4 a0 = *(const float4*)(&As[kk][ty * 8]);
            float4 a1 = *(const float4*)(&As[kk][ty * 8 + 4]);
            float4 b0 = *(const float4*)(&Bs[kk][tx * 8]);
            float4 b1 = *(const float4*)(&Bs[kk][tx * 8 + 4]);
            float a[8] = {a0.x, a0.y, a0.z, a0.w, a1.x, a1.y, a1.z, a1.w};
            float b[8] = {b0.x, b0.y, b0.z, b0.w, b1.x, b1.y, b1.z, b1.w};
#pragma unroll
            for (int i = 0; i < 8; ++i)
#pragma unroll
                for (int j = 0; j < 8; ++j) acc[i][j] = fmaf(a[i], b[j], acc[i][j]);
        }
        __syncthreads();
    }
    size_t cbase = (size_t)batchOffC * blockIdx.z;
#pragma unroll
    for (int i = 0; i < 8; ++i) {
        size_t r = bm + ty * 8 + i;
#pragma unroll
        for (int j = 0; j < 8; ++j) {
            size_t c = bn + tx * 8 + j;
            if (BF16S)
                ((ushortT*)Cv)[cbase + r * (size_t)ldc + c] = f2bf(acc[i][j] * scaleC);
            else
                ((float*)Cv)[cbase + r * (size_t)ldc + c] = acc[i][j];
        }
    }
}

// ------- kv postprocess: rms_norm(kv_c) + interleaved rope on k_pe -> kcat bf16 (T,576) ----
__global__ __launch_bounds__(256) void k_kv_post2(const float* __restrict__ kv,
                                                  const float* __restrict__ lnw,
                                                  const float* __restrict__ cosT,
                                                  const float* __restrict__ sinT,
                                                  ushortT* __restrict__ kcat) {
    int t = blockIdx.x, tid = threadIdx.x;
    const float* row = kv + (size_t)t * 576;
    float v0 = row[tid], v1 = row[tid + 256];
    float s = v0 * v0 + v1 * v1;
    for (int o = 32; o > 0; o >>= 1) s += __shfl_down(s, o);
    __shared__ float sm[4];
    if ((tid & 63) == 0) sm[tid >> 6] = s;
    __syncthreads();
    float tot = sm[0] + sm[1] + sm[2] + sm[3];
    float inv = 1.f / sqrtf(tot / 512.f + 1e-6f);
    ushortT* out = kcat + (size_t)t * 576;
    out[tid] = f2bf(v0 * inv * lnw[tid]);
    out[tid + 256] = f2bf(v1 * inv * lnw[tid + 256]);
    if (tid < 32) {
        float c = cosT[t * 32 + tid], sn = sinT[t * 32 + tid];
        float x1 = row[512 + 2 * tid], x2 = row[512 + 2 * tid + 1];
        out[512 + 2 * tid] = f2bf(x1 * c - x2 * sn);
        out[512 + 2 * tid + 1] = f2bf(x2 * c + x1 * sn);
    }
}

// ------- interleaved rope on q_pe -> qcat[...,512:576] bf16 (SCALE folded) ---------------
__global__ __launch_bounds__(256) void k_rope_q2(const float* __restrict__ qfull,
                                                 const float* __restrict__ cosT,
                                                 const float* __restrict__ sinT,
                                                 ushortT* __restrict__ qcat) {
    int b = blockIdx.x * 8 + (threadIdx.x >> 5);  // b = t*32 + h
    int i = threadIdx.x & 31;
    int t = b >> 5, h = b & 31;
    const float* p = qfull + (size_t)b * 192 + 128;
    float c = cosT[t * 32 + i], s = sinT[t * 32 + i];
    float x1 = p[2 * i], x2 = p[2 * i + 1];
    ushortT* q = qcat + (size_t)t * 18432 + h * 576 + 512;
    q[2 * i] = f2bf((x1 * c - x2 * s) * SCALE_F);
    q[2 * i + 1] = f2bf((x2 * c + x1 * s) * SCALE_F);
}

// ---------------- indexer k: layernorm + neox rope + fp8 quant (in place) ----------------
__global__ __launch_bounds__(128) void k_ki_post(float* __restrict__ kidx,
                                                 const float* __restrict__ g,
                                                 const float* __restrict__ be,
                                                 const float* __restrict__ cosT,
                                                 const float* __restrict__ sinT,
                                                 float* __restrict__ kscale) {
    int t = blockIdx.x, i = threadIdx.x;
    float* row = kidx + (size_t)t * 128;
    float x = row[i];
    float s = x;
    for (int o = 32; o > 0; o >>= 1) s += __shfl_down(s, o);
    __shared__ float sm[2];
    if ((i & 63) == 0) sm[i >> 6] = s;
    __syncthreads();
    float mean = (sm[0] + sm[1]) / 128.f;
    float d = x - mean;
    float s2 = d * d;
    for (int o = 32; o > 0; o >>= 1) s2 += __shfl_down(s2, o);
    __shared__ float sv[2];
    if ((i & 63) == 0) sv[i >> 6] = s2;
    __syncthreads();
    float var = (sv[0] + sv[1]) / 128.f;
    float nrm = d * (1.f / sqrtf(var + 1e-6f)) * g[i] + be[i];
    __shared__ float buf[128];
    buf[i] = nrm;
    __syncthreads();
    float out;
    if (i < 32)      out = buf[i] * cosT[t * 32 + i] - buf[i + 32] * sinT[t * 32 + i];
    else if (i < 64) out = buf[i] * cosT[t * 32 + i - 32] + buf[i - 32] * sinT[t * 32 + i - 32];
    else             out = nrm;
    float a = fabsf(out);
    for (int o = 32; o > 0; o >>= 1) a = fmaxf(a, __shfl_down(a, o));
    __shared__ float am[2];
    if ((i & 63) == 0) am[i >> 6] = a;
    __syncthreads();
    float amax = fmaxf(fmaxf(am[0], am[1]), 1e-10f);
    float scale = __int_as_float((((int)ceilf(log2f(amax / 448.f))) + 127) << 23);
    row[i] = q_e4m3(out / scale);
    if (i == 0) kscale[t] = scale;
}

// ---------------- indexer q: neox rope + fp8 quant per (t,h) row (in place) ----------------
__global__ __launch_bounds__(128) void k_qi_post(float* __restrict__ qi,
                                                 const float* __restrict__ cosT,
                                                 const float* __restrict__ sinT,
                                                 float* __restrict__ qscale) {
    int b = blockIdx.x;            // b = t*32 + h
    int t = b >> 5;
    int i = threadIdx.x;
    float* row = qi + (size_t)b * 128;
    float x = row[i];
    __shared__ float buf[128];
    buf[i] = x;
    __syncthreads();
    float out;
    if (i < 32)      out = buf[i] * cosT[t * 32 + i] - buf[i + 32] * sinT[t * 32 + i];
    else if (i < 64) out = buf[i] * cosT[t * 32 + i - 32] + buf[i - 32] * sinT[t * 32 + i - 32];
    else             out = x;
    float a = fabsf(out);
    for (int o = 32; o > 0; o >>= 1) a = fmaxf(a, __shfl_down(a, o));
    __shared__ float am[2];
    if ((i & 63) == 0) am[i >> 6] = a;
    __syncthreads();
    float amax = fmaxf(fmaxf(am[0], am[1]), 1e-10f);
    float scale = __int_as_float((((int)ceilf(log2f(amax / 448.f))) + 127) << 23);
    row[i] = q_e4m3(out / scale);
    if (i == 0) qscale[b] = scale;
}

// ---------------- indexer weights: (hs @ W_iw) * qscale * idx_scales ----------------
__global__ __launch_bounds__(256) void k_wiw(const float* __restrict__ hs,
                                             const float* __restrict__ W_iw,
                                             const float* __restrict__ qscale,
                                             float* __restrict__ wts) {
    int t = blockIdx.x, tid = threadIdx.x;
    __shared__ float hr[2048];
    for (int i = tid; i < 2048; i += 256) hr[i] = hs[(size_t)t * 2048 + i];
    __syncthreads();
    int h = tid & 31, p = tid >> 5;
    float s = 0;
    for (int k = p * 256; k < p * 256 + 256; ++k) s = fmaf(hr[k], W_iw[(size_t)k * 32 + h], s);
    __shared__ float part[8][32];
    part[p][h] = s;
    __syncthreads();
    if (tid < 32) {
        float tot = 0;
#pragma unroll
        for (int pp = 0; pp < 8; ++pp) tot += part[pp][tid];
        const float a = (float)0.08838834764831845;   // 128^-0.5
        const float b = (float)0.1767766952966369;    // 32^-0.5
        wts[t * 32 + tid] = tot * qscale[t * 32 + tid] * a * b;
    }
}

// ---------------- indexer score: score[t,s] = sum_h w[t,h]*relu((q.k)*kscale[s]) ----------------
__global__ __launch_bounds__(256) void k_score(const float* __restrict__ q,
                                               const float* __restrict__ k,
                                               const float* __restrict__ kscale,
                                               const float* __restrict__ wts,
                                               float* __restrict__ score) {
    int b = blockIdx.x;
    int ti = (int)((sqrtf(8.f * b + 1.f) - 1.f) * 0.5f);
    while ((ti + 1) * (ti + 2) / 2 <= b) ++ti;
    while (ti * (ti + 1) / 2 > b) --ti;
    int si = b - ti * (ti + 1) / 2;
    int t0 = ti * 32, s0 = si * 32;
    __shared__ float qs[32][132];
    __shared__ float ks_[32][132];
    __shared__ float ksc[32];
    __shared__ float w_s[32];
    int tid = threadIdx.x;
    if (tid < 32) ksc[tid] = kscale[s0 + tid];
#pragma unroll
    for (int i = 0; i < 4; ++i) {
        int fi = tid + i * 256;
        int r = fi >> 5, d4 = (fi & 31) * 4;
        float4 u = *(const float4*)&k[(size_t)(s0 + r) * 128 + d4];
        ks_[r][d4 + 0] = u.x; ks_[r][d4 + 1] = u.y; ks_[r][d4 + 2] = u.z; ks_[r][d4 + 3] = u.w;
    }
    int tt = tid & 31, sg = tid >> 5;
    float acc0 = 0, acc1 = 0, acc2 = 0, acc3 = 0;
    for (int h = 0; h < 32; ++h) {
        __syncthreads();
        if (tid < 32) w_s[tid] = wts[(t0 + tid) * 32 + h];
#pragma unroll
        for (int i = 0; i < 4; ++i) {
            int fi = tid + i * 256;
            int r = fi >> 5, d4 = (fi & 31) * 4;
            float4 v = *(const float4*)&q[((size_t)(t0 + r) * 32 + h) * 128 + d4];
            qs[r][d4 + 0] = v.x; qs[r][d4 + 1] = v.y; qs[r][d4 + 2] = v.z; qs[r][d4 + 3] = v.w;
        }
        __syncthreads();
        float d0 = 0, d1 = 0, d2 = 0, d3 = 0;
#pragma unroll 4
        for (int d4 = 0; d4 < 32; ++d4) {
            float4 qv = *(const float4*)&qs[tt][d4 * 4];
            float4 k0 = *(const float4*)&ks_[sg * 4 + 0][d4 * 4];
            float4 k1 = *(const float4*)&ks_[sg * 4 + 1][d4 * 4];
            float4 k2 = *(const float4*)&ks_[sg * 4 + 2][d4 * 4];
            float4 k3 = *(const float4*)&ks_[sg * 4 + 3][d4 * 4];
            d0 = fmaf(qv.x, k0.x, fmaf(qv.y, k0.y, fmaf(qv.z, k0.z, fmaf(qv.w, k0.w, d0))));
            d1 = fmaf(qv.x, k1.x, fmaf(qv.y, k1.y, fmaf(qv.z, k1.z, fmaf(qv.w, k1.w, d1))));
            d2 = fmaf(qv.x, k2.x, fmaf(qv.y, k2.y, fmaf(qv.z, k2.z, fmaf(qv.w, k2.w, d2))));
            d3 = fmaf(qv.x, k3.x, fmaf(qv.y, k3.y, fmaf(qv.z, k3.z, fmaf(qv.w, k3.w, d3))));
        }
        float w = w_s[tt];
        acc0 += w * fmaxf(d0 * ksc[sg * 4 + 0], 0.f);
        acc1 += w * fmaxf(d1 * ksc[sg * 4 + 1], 0.f);
        acc2 += w * fmaxf(d2 * ksc[sg * 4 + 2], 0.f);
        acc3 += w * fmaxf(d3 * ksc[sg * 4 + 3], 0.f);
    }
    int t = t0 + tt;
    float accs[4] = {acc0, acc1, acc2, acc3};
#pragma unroll
    for (int j = 0; j < 4; ++j) {
        int s = s0 + sg * 4 + j;
        if (s <= t) score[(size_t)t * T_N + s] = accs[j];
    }
}

// ---------------- top-512 per row (stable: ties -> lowest index) --------------------------
__global__ __launch_bounds__(256) void k_topk(const float* __restrict__ score,
                                              int* __restrict__ tki, int* __restrict__ tkc) {
    int t = blockIdx.x;
    int n = t + 1;
    int tid = threadIdx.x;
    if (n <= TOPK_N) {
        for (int i = tid; i < n; i += 256) tki[(size_t)t * TOPK_N + i] = i;
        if (tid == 0) tkc[t] = n;
        return;
    }
    __shared__ unsigned keys[2048];
    const float* row = score + (size_t)t * T_N;
    for (int i = tid; i < n; i += 256) {
        float f = row[i] + 0.f;
        unsigned u = __float_as_uint(f);
        u = (u & 0x80000000u) ? ~u : (u | 0x80000000u);
        keys[i] = u;
    }
    __shared__ int hist[256];
    __shared__ unsigned sh_prefix;
    __shared__ int sh_need;
    if (tid == 0) { sh_prefix = 0u; sh_need = TOPK_N; }
    __syncthreads();
    unsigned maskHi = 0;
    for (int level = 3; level >= 0; --level) {
        hist[tid] = 0;
        __syncthreads();
        unsigned prefix = sh_prefix;
        int shift = level * 8;
        for (int i = tid; i < n; i += 256) {
            unsigned kk = keys[i];
            if ((kk & maskHi) == prefix) atomicAdd(&hist[(kk >> shift) & 255], 1);
        }
        __syncthreads();
        if (tid == 0) {
            int need = sh_need, cum = 0, bsel = 255;
            for (int bb = 255; bb >= 0; --bb) {
                if (cum + hist[bb] >= need) { bsel = bb; break; }
                cum += hist[bb];
            }
            sh_need = need - cum;
            sh_prefix = prefix | ((unsigned)bsel << shift);
        }
        __syncthreads();
        maskHi |= (0xFFu << shift);
    }
    unsigned thr = sh_prefix;
    int needEq = sh_need;
    int base = tid * 8;
    int eqcnt = 0;
#pragma unroll
    for (int j = 0; j < 8; ++j) {
        int i = base + j;
        if (i < n && keys[i] == thr) eqcnt++;
    }
    __shared__ int scn[256];
    scn[tid] = eqcnt;
    __syncthreads();
    for (int off = 1; off < 256; off <<= 1) {
        int add = (tid >= off) ? scn[tid - off] : 0;
        __syncthreads();
        scn[tid] += add;
        __syncthreads();
    }
    int eq_excl = scn[tid] - eqcnt;
    int acnt = 0;
    {
        int eqr = eq_excl;
#pragma unroll
        for (int j = 0; j < 8; ++j) {
            int i = base + j;
            if (i < n) {
                unsigned kk = keys[i];
                bool a = (kk > thr) || (kk == thr && eqr < needEq);
                if (kk == thr) eqr++;
                if (a) acnt++;
            }
        }
    }
    __syncthreads();
    scn[tid] = acnt;
    __syncthreads();
    for (int off = 1; off < 256; off <<= 1) {
        int add = (tid >= off) ? scn[tid - off] : 0;
        __syncthreads();
        scn[tid] += add;
        __syncthreads();
    }
    int pos = scn[tid] - acnt;
    {
        int eqr = eq_excl;
#pragma unroll
        for (int j = 0; j < 8; ++j) {
            int i = base + j;
            if (i < n) {
                unsigned kk = keys[i];
                bool a = (kk > thr) || (kk == thr && eqr < needEq);
                if (kk == thr) eqr++;
                if (a) tki[(size_t)t * TOPK_N + (pos++)] = i;
            }
        }
    }
    if (tid == 0) tkc[t] = TOPK_N;
}

// ======== fused sparse MFMA attention: per-t block, 32 heads, scores+softmax+PV ==========
// qcat: (T,32,576) bf16 with SCALE folded. kcat: (T,576) bf16. o_lat out: (T,32,512) f32.
__global__ __launch_bounds__(512) void k_attn_mfma(const ushortT* __restrict__ qcat,
                                                   const ushortT* __restrict__ kcat,
                                                   const int* __restrict__ tki,
                                                   const int* __restrict__ tkc,
                                                   float* __restrict__ o_lat) {
    int t = blockIdx.x;
    int tid = threadIdx.x;
    int lane = tid & 63;
    int w = tid >> 6;            // wave 0..7
    int S = tkc[t];

    __shared__ int idx_s[512];
    __shared__ ushortT qs[18432];     // [32 heads][576] bf16, XOR-swizzled rows (1152B)
    __shared__ ushortT kb[41472];     // score: [64 keys][576] swz | PV: [512 dims][72 keys]
    __shared__ ushortT ps[16384];     // P: [32 heads][512 keys] bf16, swz (1024B rows)
    __shared__ float red[256];        // [head][wave]

    idx_s[tid] = (tid < S) ? tki[(size_t)t * TOPK_N + tid] : 0;
    {
        const uint4* src = (const uint4*)(qcat + (size_t)t * 18432);
        for (int c = tid; c < 2304; c += 512) {
            int head = c / 72;
            int byteoff = (c * 16) ^ ((head & 7) << 4);
            *(uint4*)((char*)qs + byteoff) = src[c];
        }
    }
    __syncthreads();

    int lr = lane & 15, lk = lane >> 4;
    int mt = w >> 2, nt = w & 3;     // wave handles heads mt*16.., keys p*64+nt*16..

    // ---- score pass: acc[p] = 16x16 scores tile for pair p ----
    f32x4 acc[8];
#pragma unroll
    for (int p = 0; p < 8; ++p) acc[p] = (f32x4){0.f, 0.f, 0.f, 0.f};

#pragma unroll
    for (int p = 0; p < 8; ++p) {
        if (p * 64 < S) {
            for (int c = tid; c < 4608; c += 512) {
                int keyl = c / 72, dg = c % 72;
                int gk = p * 64 + keyl;
                uint4 v = {0, 0, 0, 0};
                if (gk < S) v = *(const uint4*)(kcat + (size_t)idx_s[gk] * 576 + dg * 8);
                int byteoff = (keyl * 1152 + dg * 16) ^ ((keyl & 7) << 4);
                *(uint4*)((char*)kb + byteoff) = v;
            }
            __syncthreads();
#pragma unroll
            for (int kk = 0; kk < 18; ++kk) {
                int doff = (kk * 32 + lk * 8) * 2;
                bf16x8 a = *(const bf16x8*)((const char*)qs +
                            (((mt * 16 + lr) * 1152 + doff) ^ ((lr & 7) << 4)));
                bf16x8 b = *(const bf16x8*)((const char*)kb +
                            (((nt * 16 + lr) * 1152 + doff) ^ ((lr & 7) << 4)));
                acc[p] = __builtin_amdgcn_mfma_f32_16x16x32_bf16(a, b, acc[p], 0, 0, 0);
            }
            __syncthreads();
        }
    }

    // ---- softmax over keys (C layout: key = lane&15 within tile, head = (lane>>4)*4+reg)
    int hb = mt * 16 + (lane >> 4) * 4;
    float mx[4];
#pragma unroll
    for (int r = 0; r < 4; ++r) mx[r] = -1e30f;
#pragma unroll
    for (int p = 0; p < 8; ++p) {
        int key = p * 64 + nt * 16 + lr;
        if (key < S) {
#pragma unroll
            for (int r = 0; r < 4; ++r) mx[r] = fmaxf(mx[r], acc[p][r]);
        }
    }
#pragma unroll
    for (int off = 1; off < 16; off <<= 1)
#pragma unroll
        for (int r = 0; r < 4; ++r) mx[r] = fmaxf(mx[r], __shfl_xor(mx[r], off));
    if (lr == 0)
#pragma unroll
        for (int r = 0; r < 4; ++r) red[(hb + r) * 8 + w] = mx[r];
    __syncthreads();
    float m_[4];
#pragma unroll
    for (int r = 0; r < 4; ++r) {
        const float* rp = &red[(hb + r) * 8 + mt * 4];
        m_[r] = fmaxf(fmaxf(rp[0], rp[1]), fmaxf(rp[2], rp[3]));
    }
    __syncthreads();
    float sm_[4] = {0.f, 0.f, 0.f, 0.f};
#pragma unroll
    for (int p = 0; p < 8; ++p) {
        int key = p * 64 + nt * 16 + lr;
        if (key < S) {
#pragma unroll
            for (int r = 0; r < 4; ++r) sm_[r] += expf(acc[p][r] - m_[r]);
        }
    }
#pragma unroll
    for (int off = 1; off < 16; off <<= 1)
#pragma unroll
        for (int r = 0; r < 4; ++r) sm_[r] += __shfl_xor(sm_[r], off);
    if (lr == 0)
#pragma unroll
        for (int r = 0; r < 4; ++r) red[(hb + r) * 8 + w] = sm_[r];
    __syncthreads();
    float dv[4];
#pragma unroll
    for (int r = 0; r < 4; ++r) {
        const float* rp = &red[(hb + r) * 8 + mt * 4];
        dv[r] = 1.f / (rp[0] + rp[1] + rp[2] + rp[3]);
    }
    // write P (prob) bf16 to ps
#pragma unroll
    for (int p = 0; p < 8; ++p) {
        int key = p * 64 + nt * 16 + lr;
#pragma unroll
        for (int r = 0; r < 4; ++r) {
            float val = (key < S) ? expf(acc[p][r] - m_[r]) * dv[r] : 0.f;
            int head = hb + r;
            int byteoff = (head * 1024 + key * 2) ^ ((head & 7) << 4);
            *(ushortT*)((char*)ps + byteoff) = f2bf(val);
        }
    }
    __syncthreads();

    // ---- PV pass: o[h][dim] += P[h][key] * kv[key][dim]; wave w owns dims w*64..w*64+63
    f32x4 oa[2][4];
#pragma unroll
    for (int i = 0; i < 2; ++i)
#pragma unroll
        for (int j = 0; j < 4; ++j) oa[i][j] = (f32x4){0.f, 0.f, 0.f, 0.f};

#pragma unroll
    for (int p = 0; p < 8; ++p) {
        if (p * 64 < S) {
            // stage transposed: kb as [dim 0..511][72-key-padded rows, 144B each]
            for (int c = tid; c < 4608; c += 512) {
                int dg = c >> 6, keyl = c & 63;
                int gk = p * 64 + keyl;
                uint4 v = {0, 0, 0, 0};
                if (gk < S) v = *(const uint4*)(kcat + (size_t)idx_s[gk] * 576 + dg * 8);
                ushortT* pv = (ushortT*)&v;
#pragma unroll
                for (int j = 0; j < 8; ++j) kb[(dg * 8 + j) * 72 + keyl] = pv[j];
            }
            __syncthreads();
#pragma unroll
            for (int kk = 0; kk < 2; ++kk) {
#pragma unroll
                for (int m2 = 0; m2 < 2; ++m2) {
                    bf16x8 a = *(const bf16x8*)((const char*)ps +
                        (((m2 * 16 + lr) * 1024 + (p * 64 + kk * 32 + lk * 8) * 2) ^ ((lr & 7) << 4)));
#pragma unroll
                    for (int n2 = 0; n2 < 4; ++n2) {
                        bf16x8 b = *(const bf16x8*)((const char*)kb +
                            ((w * 64 + n2 * 16 + lr) * 144 + (kk * 32 + lk * 8) * 2));
                        oa[m2][n2] = __builtin_amdgcn_mfma_f32_16x16x32_bf16(a, b, oa[m2][n2], 0, 0, 0);
                    }
                }
            }
            __syncthreads();
        }
    }
    // write o_lat f32
#pragma unroll
    for (int m2 = 0; m2 < 2; ++m2)
#pragma unroll
        for (int n2 = 0; n2 < 4; ++n2) {
            int dim = w * 64 + n2 * 16 + lr;
#pragma unroll
            for (int r = 0; r < 4; ++r) {
                int head = m2 * 16 + (lane >> 4) * 4 + r;
                o_lat[((size_t)t * H_N + head) * 512 + dim] = oa[m2][n2][r];
            }
        }
}

// ---------------- launch ----------------
extern "C" void kernel_launch(void* const* d_in, const int* in_sizes, int n_in,
                              void* d_out, int out_size, void* d_ws, size_t ws_size,
                              hipStream_t stream) {
    (void)in_sizes; (void)n_in; (void)out_size; (void)ws_size;
    const int*   positions = (const int*)d_in[0];
    const float* hs        = (const float*)d_in[1];
    const float* q_c       = (const float*)d_in[2];
    const float* kv_lora   = (const float*)d_in[3];
    const float* W_qb      = (const float*)d_in[4];
    const float* W_kvb     = (const float*)d_in[5];
    const float* W_o       = (const float*)d_in[6];
    const float* kv_ln     = (const float*)d_in[7];
    const float* W_iq      = (const float*)d_in[8];
    const float* W_ik      = (const float*)d_in[9];
    const float* gamma     = (const float*)d_in[10];
    const float* beta      = (const float*)d_in[11];
    const float* W_iw      = (const float*)d_in[12];

    float* ws = (float*)d_ws;
    // workspace (float offsets); high-water 54,595,584 fl = 218.4 MB (< 229 MB proven OK)
    float*   cosT  = ws;                              // 65,536
    float*   sinT  = ws + 65536;                      // 65,536
    int*     tki   = (int*)(ws + 131072);             // 1,048,576 ints
    int*     tkc   = (int*)(ws + 1179648);            // 2,048 ints
    ushortT* kcat  = (ushortT*)(ws + 1181696);        // (T,576) bf16 = 589,824 fl
    float*   kidx  = ws + 1771520;                    // 262,144
    float*   kscale= ws + 2033664;                    // 2,048
    float*   qscale= ws + 2035712;                    // 65,536
    float*   wts   = ws + 2101248;                    // 65,536
    float*   qi    = ws + 2166784;                    // 8,388,608 (phase A)
    float*   score = ws + 10555392;                   // 4,194,304 (phase A)
    float*   qfull = ws + 2166784;                    // 12,582,912 (phase B, aliases qi+score)
    float*   o_lat = ws + 2166784;                    // 33,554,432 (phase C, aliases qfull)
    ushortT* qcat  = (ushortT*)(ws + 35721216);       // (T,32,576) bf16 = 18,874,368 fl
    float*   vbuf  = ws + 35721216;                   // 8,388,608 (phase D, aliases qcat)

    // 1. rope tables
    k_rope_tables<<<T_N, 32, 0, stream>>>(positions, cosT, sinT);
    // 2. indexer k: hs @ W_ik  (2048x128x2048)
    gemm128<false, false><<<dim3(1, 16, 1), 256, 0, stream>>>(
        hs, W_ik, kidx, T_N, 128, HID_N, HID_N, 128, 128, 0, 0, 0, 1.f);
    // 3. LN + neox rope + fp8 quant
    k_ki_post<<<T_N, 128, 0, stream>>>(kidx, gamma, beta, cosT, sinT, kscale);
    // 4. indexer q: q_c @ W_iq  (2048x4096x1536)
    gemm128<false, false><<<dim3(32, 16, 1), 256, 0, stream>>>(
        q_c, W_iq, qi, T_N, 4096, QLORA_N, QLORA_N, 4096, 4096, 0, 0, 0, 1.f);
    // 5. neox rope + fp8 quant per (t,h)
    k_qi_post<<<T_N * IDX_H_N, 128, 0, stream>>>(qi, cosT, sinT, qscale);
    // 6. indexer weights
    k_wiw<<<T_N, 256, 0, stream>>>(hs, W_iw, qscale, wts);
    // 7. indexer score (causal lower-triangular tiles)
    k_score<<<2080, 256, 0, stream>>>(qi, kidx, kscale, wts, score);
    // 8. top-512 per row
    k_topk<<<T_N, 256, 0, stream>>>(score, tki, tkc);
    // 9. kv rms_norm + k_pe rope -> kcat bf16
    k_kv_post2<<<T_N, 256, 0, stream>>>(kv_lora, kv_ln, cosT, sinT, kcat);
    // 10. q = q_c @ W_qb (2048x6144x1536) -- overwrites phase-A scratch (after topk)
    gemm128<false, false><<<dim3(48, 16, 1), 256, 0, stream>>>(
        q_c, W_qb, qfull, T_N, 6144, QLORA_N, QLORA_N, 6144, 6144, 0, 0, 0, 1.f);
    // 11. rope q_pe -> qcat[...,512:576] (bf16, SCALE folded)
    k_rope_q2<<<T_N * H_N / 8, 256, 0, stream>>>(qfull, cosT, sinT, qcat);
    // 12. q_lat = q_nope @ W_UK^T per head -> qcat[...,0:512] (bf16, SCALE folded)
    gemm128<true, true><<<dim3(4, 16, 32), 256, 0, stream>>>(
        qfull, W_kvb, qcat, T_N, 512, 128, 6144, 8192, 18432,
        192, 256, 576, SCALE_F);
    // 13. fused sparse MFMA attention -> o_lat (T,32,512) f32
    k_attn_mfma<<<T_N, 512, 0, stream>>>(qcat, kcat, tki, tkc, o_lat);
    // 14. v = o_lat @ W_UV per head -> vbuf (T, 32*128)
    gemm128<false, false><<<dim3(1, 16, 32), 256, 0, stream>>>(
        o_lat, W_kvb + 128, vbuf, T_N, 128, KVLORA_N, 16384, 8192, 4096,
        512, 256, 128, 1.f);
    // 15. out = vbuf @ W_o -> f32
    gemm128<false, false><<<dim3(16, 16, 1), 256, 0, stream>>>(
        vbuf, W_o, (float*)d_out, T_N, HID_N, H_N * VD_N, H_N * VD_N, HID_N, HID_N,
        0, 0, 0, 1.f);
}

// Round 7
// 1847.409 us; speedup vs baseline: 3.4746x; 1.6237x over previous
//
#include <hip/hip_runtime.h>
#include <hip/hip_bf16.h>

// ---------------- constants ----------------
#define T_N    2048
#define H_N    32
#define NOPE_N 128
#define ROPE_N 64
#define VD_N   128
#define QLORA_N 1536
#define KVLORA_N 512
#define IDX_H_N 32
#define IDX_D_N 128
#define TOPK_N 512
#define HID_N  2048

typedef __attribute__((ext_vector_type(8))) short bf16x8;
typedef __attribute__((ext_vector_type(4))) float f32x4;
typedef unsigned short ushortT;

#define SCALE_F 0.07216878364870323f  // (NOPE+ROPE)^-0.5 = 192^-0.5

static __device__ __forceinline__ ushortT f2bf(float x) {
    __hip_bfloat16 b = __float2bfloat16(x);
    return *(ushortT*)&b;
}
static __device__ __forceinline__ float bf2f(ushortT u) {
    __hip_bfloat16 b = *(__hip_bfloat16*)&u;
    return __bfloat162float(b);
}

// exact RNE float -> e4m3fn grid
static __device__ __forceinline__ float q_e4m3(float x) {
    float ax = fabsf(x);
    unsigned b = __float_as_uint(ax);
    int e = (int)(b >> 23) - 126;
    int ue = (e - 4 > -9) ? (e - 4) : -9;
    float ulp = __int_as_float((ue + 127) << 23);
    float q = rintf(ax / ulp) * ulp;
    return copysignf(q, x);
}

// ---------------- rope tables ----------------
__global__ void k_rope_tables(const int* __restrict__ pos, float* __restrict__ cosT,
                              float* __restrict__ sinT) {
    int t = blockIdx.x, i = threadIdx.x;
    double inv = 1.0 / pow(10000.0, (double)i / 32.0);
    double ang = (double)pos[t] * inv;
    cosT[t * 32 + i] = (float)cos(ang);
    sinT[t * 32 + i] = (float)sin(ang);
}

// ---------------- generic 128x128 f32 GEMM (BK=8) ----------------
template <bool BT>
__global__ __launch_bounds__(256) void gemm128(
    const float* __restrict__ A, const float* __restrict__ B, float* __restrict__ C,
    int M, int N, int K, int lda, int ldb, int ldc,
    long batchOffA, long batchOffB, long batchOffC) {
    const float* Ab = A + (size_t)batchOffA * blockIdx.z;
    const float* Bb = B + (size_t)batchOffB * blockIdx.z;
    int bm = blockIdx.y * 128, bn = blockIdx.x * 128;
    int tid = threadIdx.x;
    __shared__ float As[8][128];
    __shared__ float Bs[8][128];
    float acc[8][8];
#pragma unroll
    for (int i = 0; i < 8; ++i)
#pragma unroll
        for (int j = 0; j < 8; ++j) acc[i][j] = 0.f;
    int tx = tid & 15, ty = tid >> 4;
    int ar = tid >> 1, ak = (tid & 1) * 4;
    for (int k0 = 0; k0 < K; k0 += 8) {
        float4 av = *(const float4*)(Ab + (size_t)(bm + ar) * lda + k0 + ak);
        As[ak + 0][ar] = av.x; As[ak + 1][ar] = av.y;
        As[ak + 2][ar] = av.z; As[ak + 3][ar] = av.w;
        if (BT) {
            int n = tid >> 1, kk = (tid & 1) * 4;
            float4 bv = *(const float4*)(Bb + (size_t)(bn + n) * ldb + k0 + kk);
            Bs[kk + 0][n] = bv.x; Bs[kk + 1][n] = bv.y;
            Bs[kk + 2][n] = bv.z; Bs[kk + 3][n] = bv.w;
        } else {
            int kk = tid >> 5, n = (tid & 31) * 4;
            float4 bv = *(const float4*)(Bb + (size_t)(k0 + kk) * ldb + bn + n);
            Bs[kk][n + 0] = bv.x; Bs[kk][n + 1] = bv.y;
            Bs[kk][n + 2] = bv.z; Bs[kk][n + 3] = bv.w;
        }
        __syncthreads();
#pragma unroll
        for (int kk = 0; kk < 8; ++kk) {
            float4 a0 = *(const float4*)(&As[kk][ty * 8]);
            float4 a1 = *(const float4*)(&As[kk][ty * 8 + 4]);
            float4 b0 = *(const float4*)(&Bs[kk][tx * 8]);
            float4 b1 = *(const float4*)(&Bs[kk][tx * 8 + 4]);
            float a[8] = {a0.x, a0.y, a0.z, a0.w, a1.x, a1.y, a1.z, a1.w};
            float b[8] = {b0.x, b0.y, b0.z, b0.w, b1.x, b1.y, b1.z, b1.w};
#pragma unroll
            for (int i = 0; i < 8; ++i)
#pragma unroll
                for (int j = 0; j < 8; ++j) acc[i][j] = fmaf(a[i], b[j], acc[i][j]);
        }
        __syncthreads();
    }
    size_t cbase = (size_t)batchOffC * blockIdx.z;
#pragma unroll
    for (int i = 0; i < 8; ++i) {
        size_t r = bm + ty * 8 + i;
#pragma unroll
        for (int j = 0; j < 8; ++j) {
            size_t c = bn + tx * 8 + j;
            C[cbase + r * (size_t)ldc + c] = acc[i][j];
        }
    }
}

// ======== bf16 NT MFMA GEMM: A(M,K) bf16, B(N,K) bf16, 128x128 tile, BK=64 =============
// Round-3 hardware-verified pattern: explicit uint4 global loads, XOR-swizzled LDS
// stores (^((row&7)<<4)), ds_read_b128 fragments, 16x16x32 MFMA.
// CB16: C bf16 (scaled); else C f32. M,N multiples of 128; K multiple of 64.
template <bool CB16>
__global__ __launch_bounds__(256) void bgemm(
    const ushortT* __restrict__ A, const ushortT* __restrict__ B, void* __restrict__ Cv,
    int K, int lda, int ldb, int ldc,
    long boffA, long boffB, long boffC, float scaleC) {
    const ushortT* Ab = A + (size_t)boffA * blockIdx.z;
    const ushortT* Bb = B + (size_t)boffB * blockIdx.z;
    int bm = blockIdx.y * 128, bn = blockIdx.x * 128;
    int tid = threadIdx.x, lane = tid & 63, w = tid >> 6;
    int wr = w >> 1, wc = w & 1;
    int lr = lane & 15, lk = lane >> 4;

    __shared__ __align__(16) ushortT As[128 * 64];  // [128 rows][64 elems], 128B rows, swz
    __shared__ __align__(16) ushortT Bs[128 * 64];

    f32x4 acc[4][4];
#pragma unroll
    for (int i = 0; i < 4; ++i)
#pragma unroll
        for (int j = 0; j < 4; ++j) acc[i][j] = (f32x4){0.f, 0.f, 0.f, 0.f};

    for (int kt = 0; kt < K; kt += 64) {
        __syncthreads();  // previous iteration's reads complete before overwrite
#pragma unroll
        for (int q = 0; q < 4; ++q) {
            int ch = tid + q * 256;          // 1024 chunks of 16B per matrix
            int row = ch >> 3, e8 = ch & 7;
            int byteoff = (row * 128 + e8 * 16) ^ ((row & 7) << 4);
            uint4 va = *(const uint4*)(Ab + (size_t)(bm + row) * lda + kt + e8 * 8);
            *(uint4*)((char*)As + byteoff) = va;
            uint4 vb = *(const uint4*)(Bb + (size_t)(bn + row) * ldb + kt + e8 * 8);
            *(uint4*)((char*)Bs + byteoff) = vb;
        }
        __syncthreads();
#pragma unroll
        for (int kk = 0; kk < 2; ++kk) {
            bf16x8 af[4], bfr[4];
#pragma unroll
            for (int i = 0; i < 4; ++i) {
                int arow = wr * 64 + i * 16 + lr;
                af[i] = *(const bf16x8*)((const char*)As +
                         ((arow * 128 + kk * 64 + lk * 16) ^ ((arow & 7) << 4)));
                int brow = wc * 64 + i * 16 + lr;
                bfr[i] = *(const bf16x8*)((const char*)Bs +
                         ((brow * 128 + kk * 64 + lk * 16) ^ ((brow & 7) << 4)));
            }
#pragma unroll
            for (int i = 0; i < 4; ++i)
#pragma unroll
                for (int j = 0; j < 4; ++j)
                    acc[i][j] = __builtin_amdgcn_mfma_f32_16x16x32_bf16(af[i], bfr[j], acc[i][j], 0, 0, 0);
        }
    }
    // epilogue: C row = wr*64+mi*16+lk*4+r, col = wc*64+ni*16+lr (verified mapping)
    size_t cbase = (size_t)boffC * blockIdx.z;
#pragma unroll
    for (int mi = 0; mi < 4; ++mi)
#pragma unroll
        for (int ni = 0; ni < 4; ++ni) {
            int col = bn + wc * 64 + ni * 16 + lr;
#pragma unroll
            for (int r = 0; r < 4; ++r) {
                int row = bm + wr * 64 + mi * 16 + lk * 4 + r;
                if (CB16)
                    ((ushortT*)Cv)[cbase + (size_t)row * ldc + col] = f2bf(acc[mi][ni][r] * scaleC);
                else
                    ((float*)Cv)[cbase + (size_t)row * ldc + col] = acc[mi][ni][r];
            }
        }
}

// ---------------- cast / transpose helpers ----------------
__global__ __launch_bounds__(256) void k_cast4(const float* __restrict__ src,
                                               ushortT* __restrict__ dst, int n4) {
    int i = blockIdx.x * 256 + threadIdx.x;
    if (i < n4) {
        float4 v = ((const float4*)src)[i];
        ushortT o[4] = {f2bf(v.x), f2bf(v.y), f2bf(v.z), f2bf(v.w)};
        *(uint2*)(dst + (size_t)i * 4) = *(uint2*)o;
    }
}

// dst[z][b][a] bf16 = src[a*sa + b + soff + z*sz]  (sb==1), tiles 32x32
__global__ __launch_bounds__(256) void k_tcast(const float* __restrict__ src,
                                               ushortT* __restrict__ dst,
                                               long sa, long soff, long sz,
                                               long da, long dz) {
    __shared__ float tile[32][33];
    int a0 = blockIdx.x * 32, b0 = blockIdx.y * 32;
    int tx = threadIdx.x & 31, ty = threadIdx.x >> 5;
    const float* s = src + (size_t)sz * blockIdx.z + soff;
#pragma unroll
    for (int i = ty; i < 32; i += 8)
        tile[i][tx] = s[(size_t)(a0 + i) * sa + (b0 + tx)];
    __syncthreads();
    ushortT* d = dst + (size_t)dz * blockIdx.z;
#pragma unroll
    for (int i = ty; i < 32; i += 8)
        d[(size_t)(b0 + i) * da + a0 + tx] = f2bf(tile[tx][i]);
}

// wuk_t[h][r][n] = W_kvb[r][h][n]
__global__ __launch_bounds__(256) void k_wuk_cast(const float* __restrict__ wkvb,
                                                  ushortT* __restrict__ wuk) {
    int i = blockIdx.x * 256 + threadIdx.x;  // i = h*65536 + r*128 + n
    int n = i & 127, r = (i >> 7) & 511, h = i >> 16;
    wuk[i] = f2bf(wkvb[(size_t)r * 8192 + h * 256 + n]);
}

// ------- kv postprocess -> kcat bf16 (T,576) ----
__global__ __launch_bounds__(256) void k_kv_post2(const float* __restrict__ kv,
                                                  const float* __restrict__ lnw,
                                                  const float* __restrict__ cosT,
                                                  const float* __restrict__ sinT,
                                                  ushortT* __restrict__ kcat) {
    int t = blockIdx.x, tid = threadIdx.x;
    const float* row = kv + (size_t)t * 576;
    float v0 = row[tid], v1 = row[tid + 256];
    float s = v0 * v0 + v1 * v1;
    for (int o = 32; o > 0; o >>= 1) s += __shfl_down(s, o);
    __shared__ float sm[4];
    if ((tid & 63) == 0) sm[tid >> 6] = s;
    __syncthreads();
    float tot = sm[0] + sm[1] + sm[2] + sm[3];
    float inv = 1.f / sqrtf(tot / 512.f + 1e-6f);
    ushortT* out = kcat + (size_t)t * 576;
    out[tid] = f2bf(v0 * inv * lnw[tid]);
    out[tid + 256] = f2bf(v1 * inv * lnw[tid + 256]);
    if (tid < 32) {
        float c = cosT[t * 32 + tid], sn = sinT[t * 32 + tid];
        float x1 = row[512 + 2 * tid], x2 = row[512 + 2 * tid + 1];
        out[512 + 2 * tid] = f2bf(x1 * c - x2 * sn);
        out[512 + 2 * tid + 1] = f2bf(x2 * c + x1 * sn);
    }
}

// ------- rope on q_pe (bf16 qfull) -> qcat[...,512:576] (SCALE folded) ------------------
__global__ __launch_bounds__(256) void k_rope_q2(const ushortT* __restrict__ qfull,
                                                 const float* __restrict__ cosT,
                                                 const float* __restrict__ sinT,
                                                 ushortT* __restrict__ qcat) {
    int b = blockIdx.x * 8 + (threadIdx.x >> 5);  // b = t*32 + h
    int i = threadIdx.x & 31;
    int t = b >> 5, h = b & 31;
    const ushortT* p = qfull + (size_t)b * 192 + 128;
    float c = cosT[t * 32 + i], s = sinT[t * 32 + i];
    float x1 = bf2f(p[2 * i]), x2 = bf2f(p[2 * i + 1]);
    ushortT* q = qcat + (size_t)t * 18432 + h * 576 + 512;
    q[2 * i] = f2bf((x1 * c - x2 * s) * SCALE_F);
    q[2 * i + 1] = f2bf((x2 * c + x1 * s) * SCALE_F);
}

// ---------------- indexer k: layernorm + neox rope + fp8 quant (in place) ----------------
__global__ __launch_bounds__(128) void k_ki_post(float* __restrict__ kidx,
                                                 const float* __restrict__ g,
                                                 const float* __restrict__ be,
                                                 const float* __restrict__ cosT,
                                                 const float* __restrict__ sinT,
                                                 float* __restrict__ kscale) {
    int t = blockIdx.x, i = threadIdx.x;
    float* row = kidx + (size_t)t * 128;
    float x = row[i];
    float s = x;
    for (int o = 32; o > 0; o >>= 1) s += __shfl_down(s, o);
    __shared__ float sm[2];
    if ((i & 63) == 0) sm[i >> 6] = s;
    __syncthreads();
    float mean = (sm[0] + sm[1]) / 128.f;
    float d = x - mean;
    float s2 = d * d;
    for (int o = 32; o > 0; o >>= 1) s2 += __shfl_down(s2, o);
    __shared__ float sv[2];
    if ((i & 63) == 0) sv[i >> 6] = s2;
    __syncthreads();
    float var = (sv[0] + sv[1]) / 128.f;
    float nrm = d * (1.f / sqrtf(var + 1e-6f)) * g[i] + be[i];
    __shared__ float buf[128];
    buf[i] = nrm;
    __syncthreads();
    float out;
    if (i < 32)      out = buf[i] * cosT[t * 32 + i] - buf[i + 32] * sinT[t * 32 + i];
    else if (i < 64) out = buf[i] * cosT[t * 32 + i - 32] + buf[i - 32] * sinT[t * 32 + i - 32];
    else             out = nrm;
    float a = fabsf(out);
    for (int o = 32; o > 0; o >>= 1) a = fmaxf(a, __shfl_down(a, o));
    __shared__ float am[2];
    if ((i & 63) == 0) am[i >> 6] = a;
    __syncthreads();
    float amax = fmaxf(fmaxf(am[0], am[1]), 1e-10f);
    float scale = __int_as_float((((int)ceilf(log2f(amax / 448.f))) + 127) << 23);
    row[i] = q_e4m3(out / scale);
    if (i == 0) kscale[t] = scale;
}

// ---------------- indexer q: neox rope + fp8 quant per (t,h) row (in place) ----------------
__global__ __launch_bounds__(128) void k_qi_post(float* __restrict__ qi,
                                                 const float* __restrict__ cosT,
                                                 const float* __restrict__ sinT,
                                                 float* __restrict__ qscale) {
    int b = blockIdx.x;
    int t = b >> 5;
    int i = threadIdx.x;
    float* row = qi + (size_t)b * 128;
    float x = row[i];
    __shared__ float buf[128];
    buf[i] = x;
    __syncthreads();
    float out;
    if (i < 32)      out = buf[i] * cosT[t * 32 + i] - buf[i + 32] * sinT[t * 32 + i];
    else if (i < 64) out = buf[i] * cosT[t * 32 + i - 32] + buf[i - 32] * sinT[t * 32 + i - 32];
    else             out = x;
    float a = fabsf(out);
    for (int o = 32; o > 0; o >>= 1) a = fmaxf(a, __shfl_down(a, o));
    __shared__ float am[2];
    if ((i & 63) == 0) am[i >> 6] = a;
    __syncthreads();
    float amax = fmaxf(fmaxf(am[0], am[1]), 1e-10f);
    float scale = __int_as_float((((int)ceilf(log2f(amax / 448.f))) + 127) << 23);
    row[i] = q_e4m3(out / scale);
    if (i == 0) qscale[b] = scale;
}

// ---------------- indexer weights ----------------
__global__ __launch_bounds__(256) void k_wiw(const float* __restrict__ hs,
                                             const float* __restrict__ W_iw,
                                             const float* __restrict__ qscale,
                                             float* __restrict__ wts) {
    int t = blockIdx.x, tid = threadIdx.x;
    __shared__ float hr[2048];
    for (int i = tid; i < 2048; i += 256) hr[i] = hs[(size_t)t * 2048 + i];
    __syncthreads();
    int h = tid & 31, p = tid >> 5;
    float s = 0;
    for (int k = p * 256; k < p * 256 + 256; ++k) s = fmaf(hr[k], W_iw[(size_t)k * 32 + h], s);
    __shared__ float part[8][32];
    part[p][h] = s;
    __syncthreads();
    if (tid < 32) {
        float tot = 0;
#pragma unroll
        for (int pp = 0; pp < 8; ++pp) tot += part[pp][tid];
        const float a = (float)0.08838834764831845;   // 128^-0.5
        const float b = (float)0.1767766952966369;    // 32^-0.5
        wts[t * 32 + tid] = tot * qscale[t * 32 + tid] * a * b;
    }
}

// ---------------- indexer score ----------------
__global__ __launch_bounds__(256) void k_score(const float* __restrict__ q,
                                               const float* __restrict__ k,
                                               const float* __restrict__ kscale,
                                               const float* __restrict__ wts,
                                               float* __restrict__ score) {
    int b = blockIdx.x;
    int ti = (int)((sqrtf(8.f * b + 1.f) - 1.f) * 0.5f);
    while ((ti + 1) * (ti + 2) / 2 <= b) ++ti;
    while (ti * (ti + 1) / 2 > b) --ti;
    int si = b - ti * (ti + 1) / 2;
    int t0 = ti * 32, s0 = si * 32;
    __shared__ float qs[32][132];
    __shared__ float ks_[32][132];
    __shared__ float ksc[32];
    __shared__ float w_s[32];
    int tid = threadIdx.x;
    if (tid < 32) ksc[tid] = kscale[s0 + tid];
#pragma unroll
    for (int i = 0; i < 4; ++i) {
        int fi = tid + i * 256;
        int r = fi >> 5, d4 = (fi & 31) * 4;
        float4 u = *(const float4*)&k[(size_t)(s0 + r) * 128 + d4];
        ks_[r][d4 + 0] = u.x; ks_[r][d4 + 1] = u.y; ks_[r][d4 + 2] = u.z; ks_[r][d4 + 3] = u.w;
    }
    int tt = tid & 31, sg = tid >> 5;
    float acc0 = 0, acc1 = 0, acc2 = 0, acc3 = 0;
    for (int h = 0; h < 32; ++h) {
        __syncthreads();
        if (tid < 32) w_s[tid] = wts[(t0 + tid) * 32 + h];
#pragma unroll
        for (int i = 0; i < 4; ++i) {
            int fi = tid + i * 256;
            int r = fi >> 5, d4 = (fi & 31) * 4;
            float4 v = *(const float4*)&q[((size_t)(t0 + r) * 32 + h) * 128 + d4];
            qs[r][d4 + 0] = v.x; qs[r][d4 + 1] = v.y; qs[r][d4 + 2] = v.z; qs[r][d4 + 3] = v.w;
        }
        __syncthreads();
        float d0 = 0, d1 = 0, d2 = 0, d3 = 0;
#pragma unroll 4
        for (int d4 = 0; d4 < 32; ++d4) {
            float4 qv = *(const float4*)&qs[tt][d4 * 4];
            float4 k0 = *(const float4*)&ks_[sg * 4 + 0][d4 * 4];
            float4 k1 = *(const float4*)&ks_[sg * 4 + 1][d4 * 4];
            float4 k2 = *(const float4*)&ks_[sg * 4 + 2][d4 * 4];
            float4 k3 = *(const float4*)&ks_[sg * 4 + 3][d4 * 4];
            d0 = fmaf(qv.x, k0.x, fmaf(qv.y, k0.y, fmaf(qv.z, k0.z, fmaf(qv.w, k0.w, d0))));
            d1 = fmaf(qv.x, k1.x, fmaf(qv.y, k1.y, fmaf(qv.z, k1.z, fmaf(qv.w, k1.w, d1))));
            d2 = fmaf(qv.x, k2.x, fmaf(qv.y, k2.y, fmaf(qv.z, k2.z, fmaf(qv.w, k2.w, d2))));
            d3 = fmaf(qv.x, k3.x, fmaf(qv.y, k3.y, fmaf(qv.z, k3.z, fmaf(qv.w, k3.w, d3))));
        }
        float w = w_s[tt];
        acc0 += w * fmaxf(d0 * ksc[sg * 4 + 0], 0.f);
        acc1 += w * fmaxf(d1 * ksc[sg * 4 + 1], 0.f);
        acc2 += w * fmaxf(d2 * ksc[sg * 4 + 2], 0.f);
        acc3 += w * fmaxf(d3 * ksc[sg * 4 + 3], 0.f);
    }
    int t = t0 + tt;
    float accs[4] = {acc0, acc1, acc2, acc3};
#pragma unroll
    for (int j = 0; j < 4; ++j) {
        int s = s0 + sg * 4 + j;
        if (s <= t) score[(size_t)t * T_N + s] = accs[j];
    }
}

// ---------------- top-512 per row (stable ties) --------------------------
__global__ __launch_bounds__(256) void k_topk(const float* __restrict__ score,
                                              int* __restrict__ tki, int* __restrict__ tkc) {
    int t = blockIdx.x;
    int n = t + 1;
    int tid = threadIdx.x;
    if (n <= TOPK_N) {
        for (int i = tid; i < n; i += 256) tki[(size_t)t * TOPK_N + i] = i;
        if (tid == 0) tkc[t] = n;
        return;
    }
    __shared__ unsigned keys[2048];
    const float* row = score + (size_t)t * T_N;
    for (int i = tid; i < n; i += 256) {
        float f = row[i] + 0.f;
        unsigned u = __float_as_uint(f);
        u = (u & 0x80000000u) ? ~u : (u | 0x80000000u);
        keys[i] = u;
    }
    __shared__ int hist[256];
    __shared__ unsigned sh_prefix;
    __shared__ int sh_need;
    if (tid == 0) { sh_prefix = 0u; sh_need = TOPK_N; }
    __syncthreads();
    unsigned maskHi = 0;
    for (int level = 3; level >= 0; --level) {
        hist[tid] = 0;
        __syncthreads();
        unsigned prefix = sh_prefix;
        int shift = level * 8;
        for (int i = tid; i < n; i += 256) {
            unsigned kk = keys[i];
            if ((kk & maskHi) == prefix) atomicAdd(&hist[(kk >> shift) & 255], 1);
        }
        __syncthreads();
        if (tid == 0) {
            int need = sh_need, cum = 0, bsel = 255;
            for (int bb = 255; bb >= 0; --bb) {
                if (cum + hist[bb] >= need) { bsel = bb; break; }
                cum += hist[bb];
            }
            sh_need = need - cum;
            sh_prefix = prefix | ((unsigned)bsel << shift);
        }
        __syncthreads();
        maskHi |= (0xFFu << shift);
    }
    unsigned thr = sh_prefix;
    int needEq = sh_need;
    int base = tid * 8;
    int eqcnt = 0;
#pragma unroll
    for (int j = 0; j < 8; ++j) {
        int i = base + j;
        if (i < n && keys[i] == thr) eqcnt++;
    }
    __shared__ int scn[256];
    scn[tid] = eqcnt;
    __syncthreads();
    for (int off = 1; off < 256; off <<= 1) {
        int add = (tid >= off) ? scn[tid - off] : 0;
        __syncthreads();
        scn[tid] += add;
        __syncthreads();
    }
    int eq_excl = scn[tid] - eqcnt;
    int acnt = 0;
    {
        int eqr = eq_excl;
#pragma unroll
        for (int j = 0; j < 8; ++j) {
            int i = base + j;
            if (i < n) {
                unsigned kk = keys[i];
                bool a = (kk > thr) || (kk == thr && eqr < needEq);
                if (kk == thr) eqr++;
                if (a) acnt++;
            }
        }
    }
    __syncthreads();
    scn[tid] = acnt;
    __syncthreads();
    for (int off = 1; off < 256; off <<= 1) {
        int add = (tid >= off) ? scn[tid - off] : 0;
        __syncthreads();
        scn[tid] += add;
        __syncthreads();
    }
    int pos = scn[tid] - acnt;
    {
        int eqr = eq_excl;
#pragma unroll
        for (int j = 0; j < 8; ++j) {
            int i = base + j;
            if (i < n) {
                unsigned kk = keys[i];
                bool a = (kk > thr) || (kk == thr && eqr < needEq);
                if (kk == thr) eqr++;
                if (a) tki[(size_t)t * TOPK_N + (pos++)] = i;
            }
        }
    }
    if (tid == 0) tkc[t] = TOPK_N;
}

// ======== fused sparse MFMA attention; writes o (32x512 bf16) IN PLACE over own qcat row ==
__global__ __launch_bounds__(512) void k_attn_mfma(const ushortT* __restrict__ qcat,
                                                   const ushortT* __restrict__ kcat,
                                                   const int* __restrict__ tki,
                                                   const int* __restrict__ tkc,
                                                   ushortT* __restrict__ olat) {
    int t = blockIdx.x;
    int tid = threadIdx.x;
    int lane = tid & 63;
    int w = tid >> 6;
    int S = tkc[t];

    __shared__ int idx_s[512];
    __shared__ ushortT qs[18432];
    __shared__ ushortT kb[41472];
    __shared__ ushortT ps[16384];
    __shared__ float red[256];

    idx_s[tid] = (tid < S) ? tki[(size_t)t * TOPK_N + tid] : 0;
    {
        const uint4* src = (const uint4*)(qcat + (size_t)t * 18432);
        for (int c = tid; c < 2304; c += 512) {
            int head = c / 72;
            int byteoff = (c * 16) ^ ((head & 7) << 4);
            *(uint4*)((char*)qs + byteoff) = src[c];
        }
    }
    __syncthreads();

    int lr = lane & 15, lk = lane >> 4;
    int mt = w >> 2, nt = w & 3;

    f32x4 acc[8];
#pragma unroll
    for (int p = 0; p < 8; ++p) acc[p] = (f32x4){0.f, 0.f, 0.f, 0.f};

#pragma unroll
    for (int p = 0; p < 8; ++p) {
        if (p * 64 < S) {
            for (int c = tid; c < 4608; c += 512) {
                int keyl = c / 72, dg = c % 72;
                int gk = p * 64 + keyl;
                uint4 v = {0, 0, 0, 0};
                if (gk < S) v = *(const uint4*)(kcat + (size_t)idx_s[gk] * 576 + dg * 8);
                int byteoff = (keyl * 1152 + dg * 16) ^ ((keyl & 7) << 4);
                *(uint4*)((char*)kb + byteoff) = v;
            }
            __syncthreads();
#pragma unroll
            for (int kk = 0; kk < 18; ++kk) {
                int doff = (kk * 32 + lk * 8) * 2;
                bf16x8 a = *(const bf16x8*)((const char*)qs +
                            (((mt * 16 + lr) * 1152 + doff) ^ ((lr & 7) << 4)));
                bf16x8 b = *(const bf16x8*)((const char*)kb +
                            (((nt * 16 + lr) * 1152 + doff) ^ ((lr & 7) << 4)));
                acc[p] = __builtin_amdgcn_mfma_f32_16x16x32_bf16(a, b, acc[p], 0, 0, 0);
            }
            __syncthreads();
        }
    }

    int hb = mt * 16 + (lane >> 4) * 4;
    float mx[4];
#pragma unroll
    for (int r = 0; r < 4; ++r) mx[r] = -1e30f;
#pragma unroll
    for (int p = 0; p < 8; ++p) {
        int key = p * 64 + nt * 16 + lr;
        if (key < S) {
#pragma unroll
            for (int r = 0; r < 4; ++r) mx[r] = fmaxf(mx[r], acc[p][r]);
        }
    }
#pragma unroll
    for (int off = 1; off < 16; off <<= 1)
#pragma unroll
        for (int r = 0; r < 4; ++r) mx[r] = fmaxf(mx[r], __shfl_xor(mx[r], off));
    if (lr == 0)
#pragma unroll
        for (int r = 0; r < 4; ++r) red[(hb + r) * 8 + w] = mx[r];
    __syncthreads();
    float m_[4];
#pragma unroll
    for (int r = 0; r < 4; ++r) {
        const float* rp = &red[(hb + r) * 8 + mt * 4];
        m_[r] = fmaxf(fmaxf(rp[0], rp[1]), fmaxf(rp[2], rp[3]));
    }
    __syncthreads();
    float sm_[4] = {0.f, 0.f, 0.f, 0.f};
#pragma unroll
    for (int p = 0; p < 8; ++p) {
        int key = p * 64 + nt * 16 + lr;
        if (key < S) {
#pragma unroll
            for (int r = 0; r < 4; ++r) sm_[r] += expf(acc[p][r] - m_[r]);
        }
    }
#pragma unroll
    for (int off = 1; off < 16; off <<= 1)
#pragma unroll
        for (int r = 0; r < 4; ++r) sm_[r] += __shfl_xor(sm_[r], off);
    if (lr == 0)
#pragma unroll
        for (int r = 0; r < 4; ++r) red[(hb + r) * 8 + w] = sm_[r];
    __syncthreads();
    float dv[4];
#pragma unroll
    for (int r = 0; r < 4; ++r) {
        const float* rp = &red[(hb + r) * 8 + mt * 4];
        dv[r] = 1.f / (rp[0] + rp[1] + rp[2] + rp[3]);
    }
#pragma unroll
    for (int p = 0; p < 8; ++p) {
        int key = p * 64 + nt * 16 + lr;
#pragma unroll
        for (int r = 0; r < 4; ++r) {
            float val = (key < S) ? expf(acc[p][r] - m_[r]) * dv[r] : 0.f;
            int head = hb + r;
            int byteoff = (head * 1024 + key * 2) ^ ((head & 7) << 4);
            *(ushortT*)((char*)ps + byteoff) = f2bf(val);
        }
    }
    __syncthreads();

    f32x4 oa[2][4];
#pragma unroll
    for (int i = 0; i < 2; ++i)
#pragma unroll
        for (int j = 0; j < 4; ++j) oa[i][j] = (f32x4){0.f, 0.f, 0.f, 0.f};

#pragma unroll
    for (int p = 0; p < 8; ++p) {
        if (p * 64 < S) {
            for (int c = tid; c < 4608; c += 512) {
                int dg = c >> 6, keyl = c & 63;
                int gk = p * 64 + keyl;
                uint4 v = {0, 0, 0, 0};
                if (gk < S) v = *(const uint4*)(kcat + (size_t)idx_s[gk] * 576 + dg * 8);
                ushortT* pv = (ushortT*)&v;
#pragma unroll
                for (int j = 0; j < 8; ++j) kb[(dg * 8 + j) * 72 + keyl] = pv[j];
            }
            __syncthreads();
#pragma unroll
            for (int kk = 0; kk < 2; ++kk) {
#pragma unroll
                for (int m2 = 0; m2 < 2; ++m2) {
                    bf16x8 a = *(const bf16x8*)((const char*)ps +
                        (((m2 * 16 + lr) * 1024 + (p * 64 + kk * 32 + lk * 8) * 2) ^ ((lr & 7) << 4)));
#pragma unroll
                    for (int n2 = 0; n2 < 4; ++n2) {
                        bf16x8 b = *(const bf16x8*)((const char*)kb +
                            ((w * 64 + n2 * 16 + lr) * 144 + (kk * 32 + lk * 8) * 2));
                        oa[m2][n2] = __builtin_amdgcn_mfma_f32_16x16x32_bf16(a, b, oa[m2][n2], 0, 0, 0);
                    }
                }
            }
            __syncthreads();
        }
    }
    // in-place write over this block's own qcat row (layout: t*18432 + head*512 + dim)
#pragma unroll
    for (int m2 = 0; m2 < 2; ++m2)
#pragma unroll
        for (int n2 = 0; n2 < 4; ++n2) {
            int dim = w * 64 + n2 * 16 + lr;
#pragma unroll
            for (int r = 0; r < 4; ++r) {
                int head = m2 * 16 + (lane >> 4) * 4 + r;
                olat[(size_t)t * 18432 + head * 512 + dim] = f2bf(oa[m2][n2][r]);
            }
        }
}

// ---------------- launch ----------------
extern "C" void kernel_launch(void* const* d_in, const int* in_sizes, int n_in,
                              void* d_out, int out_size, void* d_ws, size_t ws_size,
                              hipStream_t stream) {
    (void)in_sizes; (void)n_in; (void)out_size; (void)ws_size;
    const int*   positions = (const int*)d_in[0];
    const float* hs        = (const float*)d_in[1];
    const float* q_c       = (const float*)d_in[2];
    const float* kv_lora   = (const float*)d_in[3];
    const float* W_qb      = (const float*)d_in[4];
    const float* W_kvb     = (const float*)d_in[5];
    const float* W_o       = (const float*)d_in[6];
    const float* kv_ln     = (const float*)d_in[7];
    const float* W_iq      = (const float*)d_in[8];
    const float* W_ik      = (const float*)d_in[9];
    const float* gamma     = (const float*)d_in[10];
    const float* beta      = (const float*)d_in[11];
    const float* W_iw      = (const float*)d_in[12];

    float* ws = (float*)d_ws;
    // workspace (float offsets); high-water 39,915,520 fl = 159.7 MB (< 218.4 proven)
    float*   cosT   = ws;                          // 65,536
    float*   sinT   = ws + 65536;                  // 65,536
    int*     tki    = (int*)(ws + 131072);         // 1,048,576
    int*     tkc    = (int*)(ws + 1179648);        // 2,048
    ushortT* kcat   = (ushortT*)(ws + 1181696);    // 589,824 fl
    float*   kidx   = ws + 1771520;                // 262,144
    float*   kscale = ws + 2033664;                // 2,048
    float*   qscale = ws + 2035712;                // 65,536
    float*   wts    = ws + 2101248;                // 65,536
    // phase A (indexer):
    float*   qi     = ws + 2166784;                // 8,388,608
    float*   score  = ws + 10555392;               // 4,194,304  (A ends 14,749,696)
    // phase B (aliases phase A, after topk):
    ushortT* wqb_t  = (ushortT*)(ws + 2166784);    // 4,718,592 fl [dead after 11]
    ushortT* qc_bf  = (ushortT*)(ws + 6885376);    // 1,572,864 fl [dead after 11]
    ushortT* wuk_t  = (ushortT*)(ws + 8458240);    // 1,048,576 fl [dead after 13]
    ushortT* wuv_t  = (ushortT*)(ws + 9506816);    // 1,048,576 fl [read at 15]
    ushortT* vbuf   = (ushortT*)(ws + 10555392);   // 4,194,304 fl in score slot [15->16]
    ushortT* wo_t   = (ushortT*)(ws + 2166784);    // 4,194,304 fl [created 13b over wqb_t]
    // persistent tail:
    ushortT* qfull_bf = (ushortT*)(ws + 14749696); // 6,291,456 fl [written 11; read 12,13]
    ushortT* qcat   = (ushortT*)(ws + 21041152);   // 18,874,368 fl (T,32,576); o reuses rows

    // 1. rope tables
    k_rope_tables<<<T_N, 32, 0, stream>>>(positions, cosT, sinT);
    // 2. indexer k: hs @ W_ik (2048x128x2048) f32 — bit-identical to round-3 path
    gemm128<false><<<dim3(1, 16, 1), 256, 0, stream>>>(
        hs, W_ik, kidx, T_N, 128, HID_N, HID_N, 128, 128, 0, 0, 0);
    // 3. LN + neox rope + fp8 quant
    k_ki_post<<<T_N, 128, 0, stream>>>(kidx, gamma, beta, cosT, sinT, kscale);
    // 4. indexer q: q_c @ W_iq (2048x4096x1536) f32
    gemm128<false><<<dim3(32, 16, 1), 256, 0, stream>>>(
        q_c, W_iq, qi, T_N, 4096, QLORA_N, QLORA_N, 4096, 4096, 0, 0, 0);
    // 5. neox rope + fp8 quant
    k_qi_post<<<T_N * IDX_H_N, 128, 0, stream>>>(qi, cosT, sinT, qscale);
    // 6. indexer weights
    k_wiw<<<T_N, 256, 0, stream>>>(hs, W_iw, qscale, wts);
    // 7. indexer score
    k_score<<<2080, 256, 0, stream>>>(qi, kidx, kscale, wts, score);
    // 8. top-512
    k_topk<<<T_N, 256, 0, stream>>>(score, tki, tkc);
    // 9. kv rms_norm + k_pe rope -> kcat bf16
    k_kv_post2<<<T_N, 256, 0, stream>>>(kv_lora, kv_ln, cosT, sinT, kcat);
    // 10. casts / transposes (phase-A scratch now free)
    // FIX (round 7): grid 768 -> 3072; previous grid left qc_bf rows 512..2047 unwritten.
    k_cast4<<<3072, 256, 0, stream>>>(q_c, qc_bf, T_N * QLORA_N / 4);
    k_tcast<<<dim3(48, 192, 1), 256, 0, stream>>>(W_qb, wqb_t, 6144, 0, 0, 1536, 0);
    k_wuk_cast<<<8192, 256, 0, stream>>>(W_kvb, wuk_t);
    k_tcast<<<dim3(16, 4, 32), 256, 0, stream>>>(W_kvb, wuv_t, 8192, 128, 256, 512, 65536);
    // 11. qfull = q_c @ W_qb (bf16 MFMA) -> bf16 (T,32,192)
    bgemm<true><<<dim3(48, 16, 1), 256, 0, stream>>>(
        qc_bf, wqb_t, qfull_bf, QLORA_N, QLORA_N, QLORA_N, 6144, 0, 0, 0, 1.f);
    // 12. rope q_pe -> qcat[...,512:576]
    k_rope_q2<<<T_N * H_N / 8, 256, 0, stream>>>(qfull_bf, cosT, sinT, qcat);
    // 13. q_lat = q_nope @ W_UK^T per head -> qcat[...,0:512] (SCALE folded)
    bgemm<true><<<dim3(4, 16, 32), 256, 0, stream>>>(
        qfull_bf, wuk_t, qcat, NOPE_N, 6144, 128, 18432, 192, 65536, 576, SCALE_F);
    // 13b. wo_t transpose (over dead wqb_t)
    k_tcast<<<dim3(128, 64, 1), 256, 0, stream>>>(W_o, wo_t, 2048, 0, 0, 4096, 0);
    // 14. fused sparse MFMA attention -> o written in place into qcat rows
    k_attn_mfma<<<T_N, 512, 0, stream>>>(qcat, kcat, tki, tkc, qcat);
    // 15. v = o @ W_UV per head -> vbuf bf16 (T,4096); A rows stride 18432, head off 512
    bgemm<true><<<dim3(1, 16, 32), 256, 0, stream>>>(
        qcat, wuv_t, vbuf, KVLORA_N, 18432, 512, 4096, 512, 65536, 128, 1.f);
    // 16. out = vbuf @ W_o -> f32
    bgemm<false><<<dim3(16, 16, 1), 256, 0, stream>>>(
        vbuf, wo_t, (float*)d_out, H_N * VD_N, 4096, 4096, HID_N, 0, 0, 0, 1.f);
}

// Round 8
// 1114.153 us; speedup vs baseline: 5.7613x; 1.6581x over previous
//
#include <hip/hip_runtime.h>
#include <hip/hip_bf16.h>

// ---------------- constants ----------------
#define T_N    2048
#define H_N    32
#define NOPE_N 128
#define ROPE_N 64
#define VD_N   128
#define QLORA_N 1536
#define KVLORA_N 512
#define IDX_H_N 32
#define IDX_D_N 128
#define TOPK_N 512
#define HID_N  2048

typedef __attribute__((ext_vector_type(8))) short bf16x8;
typedef __attribute__((ext_vector_type(4))) float f32x4;
typedef unsigned short ushortT;
typedef unsigned char uchar;

#define SCALE_F 0.07216878364870323f  // (NOPE+ROPE)^-0.5 = 192^-0.5

static __device__ __forceinline__ ushortT f2bf(float x) {
    __hip_bfloat16 b = __float2bfloat16(x);
    return *(ushortT*)&b;
}
static __device__ __forceinline__ float bf2f(ushortT u) {
    __hip_bfloat16 b = *(__hip_bfloat16*)&u;
    return __bfloat162float(b);
}

// exact RNE float -> e4m3fn grid
static __device__ __forceinline__ float q_e4m3(float x) {
    float ax = fabsf(x);
    unsigned b = __float_as_uint(ax);
    int e = (int)(b >> 23) - 126;
    int ue = (e - 4 > -9) ? (e - 4) : -9;
    float ulp = __int_as_float((ue + 127) << 23);
    float q = rintf(ax / ulp) * ulp;
    return copysignf(q, x);
}

// encode a value ALREADY on the e4m3fn grid (|q|<=448) to its fp8 byte
static __device__ __forceinline__ uchar enc_e4m3(float q) {
    unsigned b = __float_as_uint(q);
    unsigned s = (b >> 31) << 7;
    float ax = fabsf(q);
    if (ax == 0.f) return (uchar)s;
    int e = (int)((b >> 23) & 255) - 127;   // q = 1.m * 2^e
    if (e >= -6) {
        unsigned m = (b >> 20) & 7;         // exact: grid value has 3 mantissa bits
        return (uchar)(s | ((unsigned)(e + 7) << 3) | m);
    }
    unsigned M = (unsigned)rintf(ax * 512.f);  // subnormal: M * 2^-9, M in 1..7
    return (uchar)(s | M);
}

// ---------------- rope tables ----------------
__global__ void k_rope_tables(const int* __restrict__ pos, float* __restrict__ cosT,
                              float* __restrict__ sinT) {
    int t = blockIdx.x, i = threadIdx.x;
    double inv = 1.0 / pow(10000.0, (double)i / 32.0);
    double ang = (double)pos[t] * inv;
    cosT[t * 32 + i] = (float)cos(ang);
    sinT[t * 32 + i] = (float)sin(ang);
}

// ---------------- generic 128x128 f32 GEMM (BK=8), batched/split-K via blockIdx.z -------
template <bool BT>
__global__ __launch_bounds__(256) void gemm128(
    const float* __restrict__ A, const float* __restrict__ B, float* __restrict__ C,
    int M, int N, int K, int lda, int ldb, int ldc,
    long batchOffA, long batchOffB, long batchOffC) {
    const float* Ab = A + (size_t)batchOffA * blockIdx.z;
    const float* Bb = B + (size_t)batchOffB * blockIdx.z;
    int bm = blockIdx.y * 128, bn = blockIdx.x * 128;
    int tid = threadIdx.x;
    __shared__ float As[8][128];
    __shared__ float Bs[8][128];
    float acc[8][8];
#pragma unroll
    for (int i = 0; i < 8; ++i)
#pragma unroll
        for (int j = 0; j < 8; ++j) acc[i][j] = 0.f;
    int tx = tid & 15, ty = tid >> 4;
    int ar = tid >> 1, ak = (tid & 1) * 4;
    for (int k0 = 0; k0 < K; k0 += 8) {
        float4 av = *(const float4*)(Ab + (size_t)(bm + ar) * lda + k0 + ak);
        As[ak + 0][ar] = av.x; As[ak + 1][ar] = av.y;
        As[ak + 2][ar] = av.z; As[ak + 3][ar] = av.w;
        if (BT) {
            int n = tid >> 1, kk = (tid & 1) * 4;
            float4 bv = *(const float4*)(Bb + (size_t)(bn + n) * ldb + k0 + kk);
            Bs[kk + 0][n] = bv.x; Bs[kk + 1][n] = bv.y;
            Bs[kk + 2][n] = bv.z; Bs[kk + 3][n] = bv.w;
        } else {
            int kk = tid >> 5, n = (tid & 31) * 4;
            float4 bv = *(const float4*)(Bb + (size_t)(k0 + kk) * ldb + bn + n);
            Bs[kk][n + 0] = bv.x; Bs[kk][n + 1] = bv.y;
            Bs[kk][n + 2] = bv.z; Bs[kk][n + 3] = bv.w;
        }
        __syncthreads();
#pragma unroll
        for (int kk = 0; kk < 8; ++kk) {
            float4 a0 = *(const float4*)(&As[kk][ty * 8]);
            float4 a1 = *(const float4*)(&As[kk][ty * 8 + 4]);
            float4 b0 = *(const float4*)(&Bs[kk][tx * 8]);
            float4 b1 = *(const float4*)(&Bs[kk][tx * 8 + 4]);
            float a[8] = {a0.x, a0.y, a0.z, a0.w, a1.x, a1.y, a1.z, a1.w};
            float b[8] = {b0.x, b0.y, b0.z, b0.w, b1.x, b1.y, b1.z, b1.w};
#pragma unroll
            for (int i = 0; i < 8; ++i)
#pragma unroll
                for (int j = 0; j < 8; ++j) acc[i][j] = fmaf(a[i], b[j], acc[i][j]);
        }
        __syncthreads();
    }
    size_t cbase = (size_t)batchOffC * blockIdx.z;
#pragma unroll
    for (int i = 0; i < 8; ++i) {
        size_t r = bm + ty * 8 + i;
#pragma unroll
        for (int j = 0; j < 8; ++j) {
            size_t c = bn + tx * 8 + j;
            C[cbase + r * (size_t)ldc + c] = acc[i][j];
        }
    }
}

// ======== bf16 NT MFMA GEMM: A(M,K) bf16, B(N,K) bf16, 128x128 tile, BK=64 =============
template <bool CB16>
__global__ __launch_bounds__(256) void bgemm(
    const ushortT* __restrict__ A, const ushortT* __restrict__ B, void* __restrict__ Cv,
    int K, int lda, int ldb, int ldc,
    long boffA, long boffB, long boffC, float scaleC) {
    const ushortT* Ab = A + (size_t)boffA * blockIdx.z;
    const ushortT* Bb = B + (size_t)boffB * blockIdx.z;
    int bm = blockIdx.y * 128, bn = blockIdx.x * 128;
    int tid = threadIdx.x, lane = tid & 63, w = tid >> 6;
    int wr = w >> 1, wc = w & 1;
    int lr = lane & 15, lk = lane >> 4;

    __shared__ __align__(16) ushortT As[128 * 64];
    __shared__ __align__(16) ushortT Bs[128 * 64];

    f32x4 acc[4][4];
#pragma unroll
    for (int i = 0; i < 4; ++i)
#pragma unroll
        for (int j = 0; j < 4; ++j) acc[i][j] = (f32x4){0.f, 0.f, 0.f, 0.f};

    for (int kt = 0; kt < K; kt += 64) {
        __syncthreads();
#pragma unroll
        for (int q = 0; q < 4; ++q) {
            int ch = tid + q * 256;
            int row = ch >> 3, e8 = ch & 7;
            int byteoff = (row * 128 + e8 * 16) ^ ((row & 7) << 4);
            uint4 va = *(const uint4*)(Ab + (size_t)(bm + row) * lda + kt + e8 * 8);
            *(uint4*)((char*)As + byteoff) = va;
            uint4 vb = *(const uint4*)(Bb + (size_t)(bn + row) * ldb + kt + e8 * 8);
            *(uint4*)((char*)Bs + byteoff) = vb;
        }
        __syncthreads();
#pragma unroll
        for (int kk = 0; kk < 2; ++kk) {
            bf16x8 af[4], bfr[4];
#pragma unroll
            for (int i = 0; i < 4; ++i) {
                int arow = wr * 64 + i * 16 + lr;
                af[i] = *(const bf16x8*)((const char*)As +
                         ((arow * 128 + kk * 64 + lk * 16) ^ ((arow & 7) << 4)));
                int brow = wc * 64 + i * 16 + lr;
                bfr[i] = *(const bf16x8*)((const char*)Bs +
                         ((brow * 128 + kk * 64 + lk * 16) ^ ((brow & 7) << 4)));
            }
#pragma unroll
            for (int i = 0; i < 4; ++i)
#pragma unroll
                for (int j = 0; j < 4; ++j)
                    acc[i][j] = __builtin_amdgcn_mfma_f32_16x16x32_bf16(af[i], bfr[j], acc[i][j], 0, 0, 0);
        }
    }
    size_t cbase = (size_t)boffC * blockIdx.z;
#pragma unroll
    for (int mi = 0; mi < 4; ++mi)
#pragma unroll
        for (int ni = 0; ni < 4; ++ni) {
            int col = bn + wc * 64 + ni * 16 + lr;
#pragma unroll
            for (int r = 0; r < 4; ++r) {
                int row = bm + wr * 64 + mi * 16 + lk * 4 + r;
                if (CB16)
                    ((ushortT*)Cv)[cbase + (size_t)row * ldc + col] = f2bf(acc[mi][ni][r] * scaleC);
                else
                    ((float*)Cv)[cbase + (size_t)row * ldc + col] = acc[mi][ni][r];
            }
        }
}

// ---------------- cast / transpose helpers ----------------
__global__ __launch_bounds__(256) void k_cast4(const float* __restrict__ src,
                                               ushortT* __restrict__ dst, int n4) {
    int i = blockIdx.x * 256 + threadIdx.x;
    if (i < n4) {
        float4 v = ((const float4*)src)[i];
        ushortT o[4] = {f2bf(v.x), f2bf(v.y), f2bf(v.z), f2bf(v.w)};
        *(uint2*)(dst + (size_t)i * 4) = *(uint2*)o;
    }
}

// dst[z][b][a] bf16 = src[a*sa + b + soff + z*sz]  (sb==1), tiles 32x32
__global__ __launch_bounds__(256) void k_tcast(const float* __restrict__ src,
                                               ushortT* __restrict__ dst,
                                               long sa, long soff, long sz,
                                               long da, long dz) {
    __shared__ float tile[32][33];
    int a0 = blockIdx.x * 32, b0 = blockIdx.y * 32;
    int tx = threadIdx.x & 31, ty = threadIdx.x >> 5;
    const float* s = src + (size_t)sz * blockIdx.z + soff;
#pragma unroll
    for (int i = ty; i < 32; i += 8)
        tile[i][tx] = s[(size_t)(a0 + i) * sa + (b0 + tx)];
    __syncthreads();
    ushortT* d = dst + (size_t)dz * blockIdx.z;
#pragma unroll
    for (int i = ty; i < 32; i += 8)
        d[(size_t)(b0 + i) * da + a0 + tx] = f2bf(tile[tx][i]);
}

// wuk_t[h][r][n] = W_kvb[r][h][n]
__global__ __launch_bounds__(256) void k_wuk_cast(const float* __restrict__ wkvb,
                                                  ushortT* __restrict__ wuk) {
    int i = blockIdx.x * 256 + threadIdx.x;
    int n = i & 127, r = (i >> 7) & 511, h = i >> 16;
    wuk[i] = f2bf(wkvb[(size_t)r * 8192 + h * 256 + n]);
}

// ------- kv postprocess -> kcat bf16 (T,576) ----
__global__ __launch_bounds__(256) void k_kv_post2(const float* __restrict__ kv,
                                                  const float* __restrict__ lnw,
                                                  const float* __restrict__ cosT,
                                                  const float* __restrict__ sinT,
                                                  ushortT* __restrict__ kcat) {
    int t = blockIdx.x, tid = threadIdx.x;
    const float* row = kv + (size_t)t * 576;
    float v0 = row[tid], v1 = row[tid + 256];
    float s = v0 * v0 + v1 * v1;
    for (int o = 32; o > 0; o >>= 1) s += __shfl_down(s, o);
    __shared__ float sm[4];
    if ((tid & 63) == 0) sm[tid >> 6] = s;
    __syncthreads();
    float tot = sm[0] + sm[1] + sm[2] + sm[3];
    float inv = 1.f / sqrtf(tot / 512.f + 1e-6f);
    ushortT* out = kcat + (size_t)t * 576;
    out[tid] = f2bf(v0 * inv * lnw[tid]);
    out[tid + 256] = f2bf(v1 * inv * lnw[tid + 256]);
    if (tid < 32) {
        float c = cosT[t * 32 + tid], sn = sinT[t * 32 + tid];
        float x1 = row[512 + 2 * tid], x2 = row[512 + 2 * tid + 1];
        out[512 + 2 * tid] = f2bf(x1 * c - x2 * sn);
        out[512 + 2 * tid + 1] = f2bf(x2 * c + x1 * sn);
    }
}

// ------- rope on q_pe (bf16 qfull) -> qcat[...,512:576] (SCALE folded) ------------------
__global__ __launch_bounds__(256) void k_rope_q2(const ushortT* __restrict__ qfull,
                                                 const float* __restrict__ cosT,
                                                 const float* __restrict__ sinT,
                                                 ushortT* __restrict__ qcat) {
    int b = blockIdx.x * 8 + (threadIdx.x >> 5);
    int i = threadIdx.x & 31;
    int t = b >> 5, h = b & 31;
    const ushortT* p = qfull + (size_t)b * 192 + 128;
    float c = cosT[t * 32 + i], s = sinT[t * 32 + i];
    float x1 = bf2f(p[2 * i]), x2 = bf2f(p[2 * i + 1]);
    ushortT* q = qcat + (size_t)t * 18432 + h * 576 + 512;
    q[2 * i] = f2bf((x1 * c - x2 * s) * SCALE_F);
    q[2 * i + 1] = f2bf((x2 * c + x1 * s) * SCALE_F);
}

// ---- indexer k: sum 16 split-K partials + layernorm + neox rope + fp8 quant -> bytes ----
__global__ __launch_bounds__(128) void k_ki_post16(const float* __restrict__ kp,
                                                   const float* __restrict__ g,
                                                   const float* __restrict__ be,
                                                   const float* __restrict__ cosT,
                                                   const float* __restrict__ sinT,
                                                   uchar* __restrict__ ki8,
                                                   float* __restrict__ kscale) {
    int t = blockIdx.x, i = threadIdx.x;
    float x = 0.f;
#pragma unroll
    for (int z = 0; z < 16; ++z) x += kp[(size_t)z * 262144 + (size_t)t * 128 + i];
    float s = x;
    for (int o = 32; o > 0; o >>= 1) s += __shfl_down(s, o);
    __shared__ float sm[2];
    if ((i & 63) == 0) sm[i >> 6] = s;
    __syncthreads();
    float mean = (sm[0] + sm[1]) / 128.f;
    float d = x - mean;
    float s2 = d * d;
    for (int o = 32; o > 0; o >>= 1) s2 += __shfl_down(s2, o);
    __shared__ float sv[2];
    if ((i & 63) == 0) sv[i >> 6] = s2;
    __syncthreads();
    float var = (sv[0] + sv[1]) / 128.f;
    float nrm = d * (1.f / sqrtf(var + 1e-6f)) * g[i] + be[i];
    __shared__ float buf[128];
    buf[i] = nrm;
    __syncthreads();
    float out;
    if (i < 32)      out = buf[i] * cosT[t * 32 + i] - buf[i + 32] * sinT[t * 32 + i];
    else if (i < 64) out = buf[i] * cosT[t * 32 + i - 32] + buf[i - 32] * sinT[t * 32 + i - 32];
    else             out = nrm;
    float a = fabsf(out);
    for (int o = 32; o > 0; o >>= 1) a = fmaxf(a, __shfl_down(a, o));
    __shared__ float am[2];
    if ((i & 63) == 0) am[i >> 6] = a;
    __syncthreads();
    float amax = fmaxf(fmaxf(am[0], am[1]), 1e-10f);
    float scale = __int_as_float((((int)ceilf(log2f(amax / 448.f))) + 127) << 23);
    ki8[(size_t)t * 128 + i] = enc_e4m3(q_e4m3(out / scale));
    if (i == 0) kscale[t] = scale;
}

// ---- indexer q: sum 2 split-K partials + neox rope + fp8 quant -> bytes -----------------
__global__ __launch_bounds__(128) void k_qi_post2(const float* __restrict__ p0,
                                                  const float* __restrict__ p1,
                                                  const float* __restrict__ cosT,
                                                  const float* __restrict__ sinT,
                                                  uchar* __restrict__ qi8,
                                                  float* __restrict__ qscale) {
    int b = blockIdx.x;
    int t = b >> 5;
    int i = threadIdx.x;
    float x = p0[(size_t)b * 128 + i] + p1[(size_t)b * 128 + i];
    __shared__ float buf[128];
    buf[i] = x;
    __syncthreads();
    float out;
    if (i < 32)      out = buf[i] * cosT[t * 32 + i] - buf[i + 32] * sinT[t * 32 + i];
    else if (i < 64) out = buf[i] * cosT[t * 32 + i - 32] + buf[i - 32] * sinT[t * 32 + i - 32];
    else             out = x;
    float a = fabsf(out);
    for (int o = 32; o > 0; o >>= 1) a = fmaxf(a, __shfl_down(a, o));
    __shared__ float am[2];
    if ((i & 63) == 0) am[i >> 6] = a;
    __syncthreads();
    float amax = fmaxf(fmaxf(am[0], am[1]), 1e-10f);
    float scale = __int_as_float((((int)ceilf(log2f(amax / 448.f))) + 127) << 23);
    qi8[(size_t)b * 128 + i] = enc_e4m3(q_e4m3(out / scale));
    if (i == 0) qscale[b] = scale;
}

// ---------------- indexer weights ----------------
__global__ __launch_bounds__(256) void k_wiw(const float* __restrict__ hs,
                                             const float* __restrict__ W_iw,
                                             const float* __restrict__ qscale,
                                             float* __restrict__ wts) {
    int t = blockIdx.x, tid = threadIdx.x;
    __shared__ float hr[2048];
    for (int i = tid; i < 2048; i += 256) hr[i] = hs[(size_t)t * 2048 + i];
    __syncthreads();
    int h = tid & 31, p = tid >> 5;
    float s = 0;
    for (int k = p * 256; k < p * 256 + 256; ++k) s = fmaf(hr[k], W_iw[(size_t)k * 32 + h], s);
    __shared__ float part[8][32];
    part[p][h] = s;
    __syncthreads();
    if (tid < 32) {
        float tot = 0;
#pragma unroll
        for (int pp = 0; pp < 8; ++pp) tot += part[pp][tid];
        const float a = (float)0.08838834764831845;   // 128^-0.5
        const float b = (float)0.1767766952966369;    // 32^-0.5
        wts[t * 32 + tid] = tot * qscale[t * 32 + tid] * a * b;
    }
}

// ======== indexer score via fp8 MFMA: score[t,s] = sum_h w[t,h]*relu((q.k)*kscale[s]) ====
__global__ __launch_bounds__(256) void k_score8(const uchar* __restrict__ qi8,
                                                const uchar* __restrict__ ki8,
                                                const float* __restrict__ kscale,
                                                const float* __restrict__ wts,
                                                float* __restrict__ score) {
    int b = blockIdx.x;
    int ti = (int)((sqrtf(8.f * b + 1.f) - 1.f) * 0.5f);
    while ((ti + 1) * (ti + 2) / 2 <= b) ++ti;
    while (ti * (ti + 1) / 2 > b) --ti;
    int si = b - ti * (ti + 1) / 2;
    int t0 = ti * 32, s0 = si * 32;
    int tid = threadIdx.x, lane = tid & 63, w = tid >> 6;
    int qt = w >> 1, qs = w & 1;         // wave's 16x16 quadrant
    int col = lane & 15, g = lane >> 4;

    __shared__ __align__(16) uchar k8s[4096];    // [32 s][128B] swz
    __shared__ __align__(16) uchar q8s[32768];   // [8 heads][32 t][128B] swz
    __shared__ float wts_s[32][33];

    {   // stage k tile once
        int row = tid >> 3, inner = tid & 7;
        uint4 v = *(const uint4*)(ki8 + (size_t)(s0 + row) * 128 + inner * 16);
        *(uint4*)(k8s + ((row * 128 + inner * 16) ^ ((row & 7) << 4))) = v;
    }
    for (int c = tid; c < 1024; c += 256) {
        int tl = c >> 5, h = c & 31;
        wts_s[tl][h] = wts[(size_t)(t0 + tl) * 32 + h];
    }

    float ksc = kscale[s0 + qs * 16 + col];
    int arow = qt * 16 + col;
    int brow = qs * 16 + col;
    float sacc[4] = {0.f, 0.f, 0.f, 0.f};

    for (int h0 = 0; h0 < 32; h0 += 8) {
        __syncthreads();   // previous consumers done (also covers k8s/wts first time)
        for (int c = tid; c < 2048; c += 256) {
            int hh = c >> 8, row = (c >> 3) & 31, inner = c & 7;
            uint4 v = *(const uint4*)(qi8 + ((size_t)(t0 + row) * 32 + h0 + hh) * 128 + inner * 16);
            *(uint4*)(q8s + hh * 4096 + ((row * 128 + inner * 16) ^ ((row & 7) << 4))) = v;
        }
        __syncthreads();
#pragma unroll
        for (int hh = 0; hh < 8; ++hh) {
            f32x4 c4 = (f32x4){0.f, 0.f, 0.f, 0.f};
#pragma unroll
            for (int kk = 0; kk < 4; ++kk) {
                long long a = *(const long long*)(q8s + hh * 4096 +
                              ((arow * 128 + kk * 32 + g * 8) ^ ((arow & 7) << 4)));
                long long bb = *(const long long*)(k8s +
                              ((brow * 128 + kk * 32 + g * 8) ^ ((brow & 7) << 4)));
                c4 = __builtin_amdgcn_mfma_f32_16x16x32_fp8_fp8(a, bb, c4, 0, 0, 0);
            }
            int h = h0 + hh;
#pragma unroll
            for (int r = 0; r < 4; ++r)
                sacc[r] = fmaf(fmaxf(c4[r] * ksc, 0.f), wts_s[qt * 16 + g * 4 + r][h], sacc[r]);
        }
    }
    int t = t0 + qt * 16 + g * 4;
    int s = s0 + qs * 16 + col;
#pragma unroll
    for (int r = 0; r < 4; ++r)
        if (s <= t + r) score[(size_t)(t + r) * T_N + s] = sacc[r];
}

// ---------------- top-512 per row (stable ties) --------------------------
__global__ __launch_bounds__(256) void k_topk(const float* __restrict__ score,
                                              int* __restrict__ tki, int* __restrict__ tkc) {
    int t = blockIdx.x;
    int n = t + 1;
    int tid = threadIdx.x;
    if (n <= TOPK_N) {
        for (int i = tid; i < n; i += 256) tki[(size_t)t * TOPK_N + i] = i;
        if (tid == 0) tkc[t] = n;
        return;
    }
    __shared__ unsigned keys[2048];
    const float* row = score + (size_t)t * T_N;
    for (int i = tid; i < n; i += 256) {
        float f = row[i] + 0.f;
        unsigned u = __float_as_uint(f);
        u = (u & 0x80000000u) ? ~u : (u | 0x80000000u);
        keys[i] = u;
    }
    __shared__ int hist[256];
    __shared__ unsigned sh_prefix;
    __shared__ int sh_need;
    if (tid == 0) { sh_prefix = 0u; sh_need = TOPK_N; }
    __syncthreads();
    unsigned maskHi = 0;
    for (int level = 3; level >= 0; --level) {
        hist[tid] = 0;
        __syncthreads();
        unsigned prefix = sh_prefix;
        int shift = level * 8;
        for (int i = tid; i < n; i += 256) {
            unsigned kk = keys[i];
            if ((kk & maskHi) == prefix) atomicAdd(&hist[(kk >> shift) & 255], 1);
        }
        __syncthreads();
        if (tid == 0) {
            int need = sh_need, cum = 0, bsel = 255;
            for (int bb = 255; bb >= 0; --bb) {
                if (cum + hist[bb] >= need) { bsel = bb; break; }
                cum += hist[bb];
            }
            sh_need = need - cum;
            sh_prefix = prefix | ((unsigned)bsel << shift);
        }
        __syncthreads();
        maskHi |= (0xFFu << shift);
    }
    unsigned thr = sh_prefix;
    int needEq = sh_need;
    int base = tid * 8;
    int eqcnt = 0;
#pragma unroll
    for (int j = 0; j < 8; ++j) {
        int i = base + j;
        if (i < n && keys[i] == thr) eqcnt++;
    }
    __shared__ int scn[256];
    scn[tid] = eqcnt;
    __syncthreads();
    for (int off = 1; off < 256; off <<= 1) {
        int add = (tid >= off) ? scn[tid - off] : 0;
        __syncthreads();
        scn[tid] += add;
        __syncthreads();
    }
    int eq_excl = scn[tid] - eqcnt;
    int acnt = 0;
    {
        int eqr = eq_excl;
#pragma unroll
        for (int j = 0; j < 8; ++j) {
            int i = base + j;
            if (i < n) {
                unsigned kk = keys[i];
                bool a = (kk > thr) || (kk == thr && eqr < needEq);
                if (kk == thr) eqr++;
                if (a) acnt++;
            }
        }
    }
    __syncthreads();
    scn[tid] = acnt;
    __syncthreads();
    for (int off = 1; off < 256; off <<= 1) {
        int add = (tid >= off) ? scn[tid - off] : 0;
        __syncthreads();
        scn[tid] += add;
        __syncthreads();
    }
    int pos = scn[tid] - acnt;
    {
        int eqr = eq_excl;
#pragma unroll
        for (int j = 0; j < 8; ++j) {
            int i = base + j;
            if (i < n) {
                unsigned kk = keys[i];
                bool a = (kk > thr) || (kk == thr && eqr < needEq);
                if (kk == thr) eqr++;
                if (a) tki[(size_t)t * TOPK_N + (pos++)] = i;
            }
        }
    }
    if (tid == 0) tkc[t] = TOPK_N;
}

// ======== fused sparse MFMA attention; writes o (32x512 bf16) IN PLACE over own qcat row ==
__global__ __launch_bounds__(512) void k_attn_mfma(const ushortT* __restrict__ qcat,
                                                   const ushortT* __restrict__ kcat,
                                                   const int* __restrict__ tki,
                                                   const int* __restrict__ tkc,
                                                   ushortT* __restrict__ olat) {
    int t = blockIdx.x;
    int tid = threadIdx.x;
    int lane = tid & 63;
    int w = tid >> 6;
    int S = tkc[t];

    __shared__ int idx_s[512];
    __shared__ ushortT qs[18432];
    __shared__ ushortT kb[41472];
    __shared__ ushortT ps[16384];
    __shared__ float red[256];

    idx_s[tid] = (tid < S) ? tki[(size_t)t * TOPK_N + tid] : 0;
    {
        const uint4* src = (const uint4*)(qcat + (size_t)t * 18432);
        for (int c = tid; c < 2304; c += 512) {
            int head = c / 72;
            int byteoff = (c * 16) ^ ((head & 7) << 4);
            *(uint4*)((char*)qs + byteoff) = src[c];
        }
    }
    __syncthreads();

    int lr = lane & 15, lk = lane >> 4;
    int mt = w >> 2, nt = w & 3;

    f32x4 acc[8];
#pragma unroll
    for (int p = 0; p < 8; ++p) acc[p] = (f32x4){0.f, 0.f, 0.f, 0.f};

#pragma unroll
    for (int p = 0; p < 8; ++p) {
        if (p * 64 < S) {
            for (int c = tid; c < 4608; c += 512) {
                int keyl = c / 72, dg = c % 72;
                int gk = p * 64 + keyl;
                uint4 v = {0, 0, 0, 0};
                if (gk < S) v = *(const uint4*)(kcat + (size_t)idx_s[gk] * 576 + dg * 8);
                int byteoff = (keyl * 1152 + dg * 16) ^ ((keyl & 7) << 4);
                *(uint4*)((char*)kb + byteoff) = v;
            }
            __syncthreads();
#pragma unroll
            for (int kk = 0; kk < 18; ++kk) {
                int doff = (kk * 32 + lk * 8) * 2;
                bf16x8 a = *(const bf16x8*)((const char*)qs +
                            (((mt * 16 + lr) * 1152 + doff) ^ ((lr & 7) << 4)));
                bf16x8 b = *(const bf16x8*)((const char*)kb +
                            (((nt * 16 + lr) * 1152 + doff) ^ ((lr & 7) << 4)));
                acc[p] = __builtin_amdgcn_mfma_f32_16x16x32_bf16(a, b, acc[p], 0, 0, 0);
            }
            __syncthreads();
        }
    }

    int hb = mt * 16 + (lane >> 4) * 4;
    float mx[4];
#pragma unroll
    for (int r = 0; r < 4; ++r) mx[r] = -1e30f;
#pragma unroll
    for (int p = 0; p < 8; ++p) {
        int key = p * 64 + nt * 16 + lr;
        if (key < S) {
#pragma unroll
            for (int r = 0; r < 4; ++r) mx[r] = fmaxf(mx[r], acc[p][r]);
        }
    }
#pragma unroll
    for (int off = 1; off < 16; off <<= 1)
#pragma unroll
        for (int r = 0; r < 4; ++r) mx[r] = fmaxf(mx[r], __shfl_xor(mx[r], off));
    if (lr == 0)
#pragma unroll
        for (int r = 0; r < 4; ++r) red[(hb + r) * 8 + w] = mx[r];
    __syncthreads();
    float m_[4];
#pragma unroll
    for (int r = 0; r < 4; ++r) {
        const float* rp = &red[(hb + r) * 8 + mt * 4];
        m_[r] = fmaxf(fmaxf(rp[0], rp[1]), fmaxf(rp[2], rp[3]));
    }
    __syncthreads();
    float sm_[4] = {0.f, 0.f, 0.f, 0.f};
#pragma unroll
    for (int p = 0; p < 8; ++p) {
        int key = p * 64 + nt * 16 + lr;
        if (key < S) {
#pragma unroll
            for (int r = 0; r < 4; ++r) sm_[r] += expf(acc[p][r] - m_[r]);
        }
    }
#pragma unroll
    for (int off = 1; off < 16; off <<= 1)
#pragma unroll
        for (int r = 0; r < 4; ++r) sm_[r] += __shfl_xor(sm_[r], off);
    if (lr == 0)
#pragma unroll
        for (int r = 0; r < 4; ++r) red[(hb + r) * 8 + w] = sm_[r];
    __syncthreads();
    float dv[4];
#pragma unroll
    for (int r = 0; r < 4; ++r) {
        const float* rp = &red[(hb + r) * 8 + mt * 4];
        dv[r] = 1.f / (rp[0] + rp[1] + rp[2] + rp[3]);
    }
#pragma unroll
    for (int p = 0; p < 8; ++p) {
        int key = p * 64 + nt * 16 + lr;
#pragma unroll
        for (int r = 0; r < 4; ++r) {
            float val = (key < S) ? expf(acc[p][r] - m_[r]) * dv[r] : 0.f;
            int head = hb + r;
            int byteoff = (head * 1024 + key * 2) ^ ((head & 7) << 4);
            *(ushortT*)((char*)ps + byteoff) = f2bf(val);
        }
    }
    __syncthreads();

    f32x4 oa[2][4];
#pragma unroll
    for (int i = 0; i < 2; ++i)
#pragma unroll
        for (int j = 0; j < 4; ++j) oa[i][j] = (f32x4){0.f, 0.f, 0.f, 0.f};

#pragma unroll
    for (int p = 0; p < 8; ++p) {
        if (p * 64 < S) {
            for (int c = tid; c < 4608; c += 512) {
                int dg = c >> 6, keyl = c & 63;
                int gk = p * 64 + keyl;
                uint4 v = {0, 0, 0, 0};
                if (gk < S) v = *(const uint4*)(kcat + (size_t)idx_s[gk] * 576 + dg * 8);
                ushortT* pv = (ushortT*)&v;
#pragma unroll
                for (int j = 0; j < 8; ++j) kb[(dg * 8 + j) * 72 + keyl] = pv[j];
            }
            __syncthreads();
#pragma unroll
            for (int kk = 0; kk < 2; ++kk) {
#pragma unroll
                for (int m2 = 0; m2 < 2; ++m2) {
                    bf16x8 a = *(const bf16x8*)((const char*)ps +
                        (((m2 * 16 + lr) * 1024 + (p * 64 + kk * 32 + lk * 8) * 2) ^ ((lr & 7) << 4)));
#pragma unroll
                    for (int n2 = 0; n2 < 4; ++n2) {
                        bf16x8 b = *(const bf16x8*)((const char*)kb +
                            ((w * 64 + n2 * 16 + lr) * 144 + (kk * 32 + lk * 8) * 2));
                        oa[m2][n2] = __builtin_amdgcn_mfma_f32_16x16x32_bf16(a, b, oa[m2][n2], 0, 0, 0);
                    }
                }
            }
            __syncthreads();
        }
    }
#pragma unroll
    for (int m2 = 0; m2 < 2; ++m2)
#pragma unroll
        for (int n2 = 0; n2 < 4; ++n2) {
            int dim = w * 64 + n2 * 16 + lr;
#pragma unroll
            for (int r = 0; r < 4; ++r) {
                int head = m2 * 16 + (lane >> 4) * 4 + r;
                olat[(size_t)t * 18432 + head * 512 + dim] = f2bf(oa[m2][n2][r]);
            }
        }
}

// ---------------- launch ----------------
extern "C" void kernel_launch(void* const* d_in, const int* in_sizes, int n_in,
                              void* d_out, int out_size, void* d_ws, size_t ws_size,
                              hipStream_t stream) {
    (void)in_sizes; (void)n_in; (void)out_size; (void)ws_size;
    const int*   positions = (const int*)d_in[0];
    const float* hs        = (const float*)d_in[1];
    const float* q_c       = (const float*)d_in[2];
    const float* kv_lora   = (const float*)d_in[3];
    const float* W_qb      = (const float*)d_in[4];
    const float* W_kvb     = (const float*)d_in[5];
    const float* W_o       = (const float*)d_in[6];
    const float* kv_ln     = (const float*)d_in[7];
    const float* W_iq      = (const float*)d_in[8];
    const float* W_ik      = (const float*)d_in[9];
    const float* gamma     = (const float*)d_in[10];
    const float* beta      = (const float*)d_in[11];
    const float* W_iw      = (const float*)d_in[12];

    float* ws = (float*)d_ws;
    // workspace (float offsets); high-water 50,204,672 fl = 200.8 MB (< 218.4 proven)
    float*   cosT   = ws;                          // 65,536
    float*   sinT   = ws + 65536;                  // 65,536
    int*     tki    = (int*)(ws + 131072);         // 1,048,576
    int*     tkc    = (int*)(ws + 1179648);        // 2,048
    ushortT* kcat   = (ushortT*)(ws + 1181696);    // 589,824 fl
    float*   kscale = ws + 1771520;                // 2,048
    float*   qscale = ws + 1773568;                // 65,536
    float*   wts    = ws + 1839104;                // 65,536
    uchar*   qi8    = (uchar*)(ws + 1904640);      // 2,097,152 fl (8 MB bytes)
    uchar*   ki8    = (uchar*)(ws + 4001792);      // 65,536 fl
    // REGION R1 4067328..20844544, time-multiplexed:
    float*   kip    = ws + 4067328;                // 16 x 262,144 [step2 -> dead after 3]
    float*   qip0   = ws + 4067328;                // 8,388,608   [step4 -> dead after 5]
    float*   qip1   = ws + 12455936;               // 8,388,608   [step4 -> dead after 5]
    ushortT* wqb_t  = (ushortT*)(ws + 4067328);    // 4,718,592 fl [10 -> dead after 11]
    ushortT* qc_bf  = (ushortT*)(ws + 8785920);    // 1,572,864 fl [10 -> dead after 11]
    ushortT* wuk_t  = (ushortT*)(ws + 10358784);   // 1,048,576 fl [10 -> dead after 13]
    ushortT* wuv_t  = (ushortT*)(ws + 11407360);   // 1,048,576 fl [10 -> read at 15]
    ushortT* wo_t   = (ushortT*)(ws + 4067328);    // 4,194,304 fl [13b over dead wqb_t]
    // score / vbuf slot:
    float*   score  = ws + 20844544;               // 4,194,304 [7 -> dead after 8]
    ushortT* vbuf   = (ushortT*)(ws + 20844544);   // 4,194,304 fl [15 -> 16]
    // persistent tail:
    ushortT* qfull_bf = (ushortT*)(ws + 25038848); // 6,291,456 fl [11 -> 12,13]
    ushortT* qcat   = (ushortT*)(ws + 31330304);   // 18,874,368 fl; o written in place (14)

    // 1. rope tables
    k_rope_tables<<<T_N, 32, 0, stream>>>(positions, cosT, sinT);
    // 2. indexer k: hs @ W_ik (2048x128x2048), split-K x16 -> partials
    gemm128<false><<<dim3(1, 16, 16), 256, 0, stream>>>(
        hs, W_ik, kip, T_N, 128, 128, HID_N, 128, 128, 128, 16384, 262144);
    // 3. sum partials + LN + neox rope + fp8 quant -> ki8 bytes
    k_ki_post16<<<T_N, 128, 0, stream>>>(kip, gamma, beta, cosT, sinT, ki8, kscale);
    // 4. indexer q: q_c @ W_iq (2048x4096x1536), split-K x2 -> partials
    gemm128<false><<<dim3(32, 16, 2), 256, 0, stream>>>(
        q_c, W_iq, qip0, T_N, 4096, 768, QLORA_N, 4096, 4096, 768, 3145728, 8388608);
    // 5. sum partials + neox rope + fp8 quant -> qi8 bytes
    k_qi_post2<<<T_N * IDX_H_N, 128, 0, stream>>>(qip0, qip1, cosT, sinT, qi8, qscale);
    // 6. indexer weights
    k_wiw<<<T_N, 256, 0, stream>>>(hs, W_iw, qscale, wts);
    // 7. indexer score via fp8 MFMA
    k_score8<<<2080, 256, 0, stream>>>(qi8, ki8, kscale, wts, score);
    // 8. top-512
    k_topk<<<T_N, 256, 0, stream>>>(score, tki, tkc);
    // 9. kv rms_norm + k_pe rope -> kcat bf16
    k_kv_post2<<<T_N, 256, 0, stream>>>(kv_lora, kv_ln, cosT, sinT, kcat);
    // 10. casts / transposes (R1 free again)
    k_cast4<<<3072, 256, 0, stream>>>(q_c, qc_bf, T_N * QLORA_N / 4);
    k_tcast<<<dim3(48, 192, 1), 256, 0, stream>>>(W_qb, wqb_t, 6144, 0, 0, 1536, 0);
    k_wuk_cast<<<8192, 256, 0, stream>>>(W_kvb, wuk_t);
    k_tcast<<<dim3(16, 4, 32), 256, 0, stream>>>(W_kvb, wuv_t, 8192, 128, 256, 512, 65536);
    // 11. qfull = q_c @ W_qb (bf16 MFMA) -> bf16 (T,32,192)
    bgemm<true><<<dim3(48, 16, 1), 256, 0, stream>>>(
        qc_bf, wqb_t, qfull_bf, QLORA_N, QLORA_N, QLORA_N, 6144, 0, 0, 0, 1.f);
    // 12. rope q_pe -> qcat[...,512:576]
    k_rope_q2<<<T_N * H_N / 8, 256, 0, stream>>>(qfull_bf, cosT, sinT, qcat);
    // 13. q_lat = q_nope @ W_UK^T per head -> qcat[...,0:512] (SCALE folded)
    bgemm<true><<<dim3(4, 16, 32), 256, 0, stream>>>(
        qfull_bf, wuk_t, qcat, NOPE_N, 6144, 128, 18432, 192, 65536, 576, SCALE_F);
    // 13b. wo_t transpose (over dead wqb_t)
    k_tcast<<<dim3(128, 64, 1), 256, 0, stream>>>(W_o, wo_t, 2048, 0, 0, 4096, 0);
    // 14. fused sparse MFMA attention -> o written in place into qcat rows
    k_attn_mfma<<<T_N, 512, 0, stream>>>(qcat, kcat, tki, tkc, qcat);
    // 15. v = o @ W_UV per head -> vbuf bf16 (T,4096)
    bgemm<true><<<dim3(1, 16, 32), 256, 0, stream>>>(
        qcat, wuv_t, vbuf, KVLORA_N, 18432, 512, 4096, 512, 65536, 128, 1.f);
    // 16. out = vbuf @ W_o -> f32
    bgemm<false><<<dim3(16, 16, 1), 256, 0, stream>>>(
        vbuf, wo_t, (float*)d_out, H_N * VD_N, 4096, 4096, HID_N, 0, 0, 0, 1.f);
}

// Round 9
// 1084.101 us; speedup vs baseline: 5.9210x; 1.0277x over previous
//
#include <hip/hip_runtime.h>
#include <hip/hip_bf16.h>

// ---------------- constants ----------------
#define T_N    2048
#define H_N    32
#define NOPE_N 128
#define ROPE_N 64
#define VD_N   128
#define QLORA_N 1536
#define KVLORA_N 512
#define IDX_H_N 32
#define IDX_D_N 128
#define TOPK_N 512
#define HID_N  2048

typedef __attribute__((ext_vector_type(8))) short bf16x8;
typedef __attribute__((ext_vector_type(4))) float f32x4;
typedef unsigned short ushortT;
typedef unsigned char uchar;

#define SCALE_F 0.07216878364870323f  // (NOPE+ROPE)^-0.5 = 192^-0.5

static __device__ __forceinline__ ushortT f2bf(float x) {
    __hip_bfloat16 b = __float2bfloat16(x);
    return *(ushortT*)&b;
}
static __device__ __forceinline__ float bf2f(ushortT u) {
    __hip_bfloat16 b = *(__hip_bfloat16*)&u;
    return __bfloat162float(b);
}

// exact RNE float -> e4m3fn grid
static __device__ __forceinline__ float q_e4m3(float x) {
    float ax = fabsf(x);
    unsigned b = __float_as_uint(ax);
    int e = (int)(b >> 23) - 126;
    int ue = (e - 4 > -9) ? (e - 4) : -9;
    float ulp = __int_as_float((ue + 127) << 23);
    float q = rintf(ax / ulp) * ulp;
    return copysignf(q, x);
}

// encode a value ALREADY on the e4m3fn grid (|q|<=448) to its fp8 byte
static __device__ __forceinline__ uchar enc_e4m3(float q) {
    unsigned b = __float_as_uint(q);
    unsigned s = (b >> 31) << 7;
    float ax = fabsf(q);
    if (ax == 0.f) return (uchar)s;
    int e = (int)((b >> 23) & 255) - 127;   // q = 1.m * 2^e
    if (e >= -6) {
        unsigned m = (b >> 20) & 7;         // exact: grid value has 3 mantissa bits
        return (uchar)(s | ((unsigned)(e + 7) << 3) | m);
    }
    unsigned M = (unsigned)rintf(ax * 512.f);  // subnormal: M * 2^-9, M in 1..7
    return (uchar)(s | M);
}

// ---------------- rope tables ----------------
__global__ void k_rope_tables(const int* __restrict__ pos, float* __restrict__ cosT,
                              float* __restrict__ sinT) {
    int t = blockIdx.x, i = threadIdx.x;
    double inv = 1.0 / pow(10000.0, (double)i / 32.0);
    double ang = (double)pos[t] * inv;
    cosT[t * 32 + i] = (float)cos(ang);
    sinT[t * 32 + i] = (float)sin(ang);
}

// ---------------- generic 128x128 f32 GEMM (BK=8), batched/split-K via blockIdx.z -------
template <bool BT>
__global__ __launch_bounds__(256) void gemm128(
    const float* __restrict__ A, const float* __restrict__ B, float* __restrict__ C,
    int M, int N, int K, int lda, int ldb, int ldc,
    long batchOffA, long batchOffB, long batchOffC) {
    const float* Ab = A + (size_t)batchOffA * blockIdx.z;
    const float* Bb = B + (size_t)batchOffB * blockIdx.z;
    int bm = blockIdx.y * 128, bn = blockIdx.x * 128;
    int tid = threadIdx.x;
    __shared__ float As[8][128];
    __shared__ float Bs[8][128];
    float acc[8][8];
#pragma unroll
    for (int i = 0; i < 8; ++i)
#pragma unroll
        for (int j = 0; j < 8; ++j) acc[i][j] = 0.f;
    int tx = tid & 15, ty = tid >> 4;
    int ar = tid >> 1, ak = (tid & 1) * 4;
    for (int k0 = 0; k0 < K; k0 += 8) {
        float4 av = *(const float4*)(Ab + (size_t)(bm + ar) * lda + k0 + ak);
        As[ak + 0][ar] = av.x; As[ak + 1][ar] = av.y;
        As[ak + 2][ar] = av.z; As[ak + 3][ar] = av.w;
        if (BT) {
            int n = tid >> 1, kk = (tid & 1) * 4;
            float4 bv = *(const float4*)(Bb + (size_t)(bn + n) * ldb + k0 + kk);
            Bs[kk + 0][n] = bv.x; Bs[kk + 1][n] = bv.y;
            Bs[kk + 2][n] = bv.z; Bs[kk + 3][n] = bv.w;
        } else {
            int kk = tid >> 5, n = (tid & 31) * 4;
            float4 bv = *(const float4*)(Bb + (size_t)(k0 + kk) * ldb + bn + n);
            Bs[kk][n + 0] = bv.x; Bs[kk][n + 1] = bv.y;
            Bs[kk][n + 2] = bv.z; Bs[kk][n + 3] = bv.w;
        }
        __syncthreads();
#pragma unroll
        for (int kk = 0; kk < 8; ++kk) {
            float4 a0 = *(const float4*)(&As[kk][ty * 8]);
            float4 a1 = *(const float4*)(&As[kk][ty * 8 + 4]);
            float4 b0 = *(const float4*)(&Bs[kk][tx * 8]);
            float4 b1 = *(const float4*)(&Bs[kk][tx * 8 + 4]);
            float a[8] = {a0.x, a0.y, a0.z, a0.w, a1.x, a1.y, a1.z, a1.w};
            float b[8] = {b0.x, b0.y, b0.z, b0.w, b1.x, b1.y, b1.z, b1.w};
#pragma unroll
            for (int i = 0; i < 8; ++i)
#pragma unroll
                for (int j = 0; j < 8; ++j) acc[i][j] = fmaf(a[i], b[j], acc[i][j]);
        }
        __syncthreads();
    }
    size_t cbase = (size_t)batchOffC * blockIdx.z;
#pragma unroll
    for (int i = 0; i < 8; ++i) {
        size_t r = bm + ty * 8 + i;
#pragma unroll
        for (int j = 0; j < 8; ++j) {
            size_t c = bn + tx * 8 + j;
            C[cbase + r * (size_t)ldc + c] = acc[i][j];
        }
    }
}

// ======== bf16 NT MFMA GEMM: A(M,K) bf16, B(N,K) bf16, 128x128 tile, BK=64 =============
template <bool CB16>
__global__ __launch_bounds__(256) void bgemm(
    const ushortT* __restrict__ A, const ushortT* __restrict__ B, void* __restrict__ Cv,
    int K, int lda, int ldb, int ldc,
    long boffA, long boffB, long boffC, float scaleC) {
    const ushortT* Ab = A + (size_t)boffA * blockIdx.z;
    const ushortT* Bb = B + (size_t)boffB * blockIdx.z;
    int bm = blockIdx.y * 128, bn = blockIdx.x * 128;
    int tid = threadIdx.x, lane = tid & 63, w = tid >> 6;
    int wr = w >> 1, wc = w & 1;
    int lr = lane & 15, lk = lane >> 4;

    __shared__ __align__(16) ushortT As[128 * 64];
    __shared__ __align__(16) ushortT Bs[128 * 64];

    f32x4 acc[4][4];
#pragma unroll
    for (int i = 0; i < 4; ++i)
#pragma unroll
        for (int j = 0; j < 4; ++j) acc[i][j] = (f32x4){0.f, 0.f, 0.f, 0.f};

    for (int kt = 0; kt < K; kt += 64) {
        __syncthreads();
#pragma unroll
        for (int q = 0; q < 4; ++q) {
            int ch = tid + q * 256;
            int row = ch >> 3, e8 = ch & 7;
            int byteoff = (row * 128 + e8 * 16) ^ ((row & 7) << 4);
            uint4 va = *(const uint4*)(Ab + (size_t)(bm + row) * lda + kt + e8 * 8);
            *(uint4*)((char*)As + byteoff) = va;
            uint4 vb = *(const uint4*)(Bb + (size_t)(bn + row) * ldb + kt + e8 * 8);
            *(uint4*)((char*)Bs + byteoff) = vb;
        }
        __syncthreads();
#pragma unroll
        for (int kk = 0; kk < 2; ++kk) {
            bf16x8 af[4], bfr[4];
#pragma unroll
            for (int i = 0; i < 4; ++i) {
                int arow = wr * 64 + i * 16 + lr;
                af[i] = *(const bf16x8*)((const char*)As +
                         ((arow * 128 + kk * 64 + lk * 16) ^ ((arow & 7) << 4)));
                int brow = wc * 64 + i * 16 + lr;
                bfr[i] = *(const bf16x8*)((const char*)Bs +
                         ((brow * 128 + kk * 64 + lk * 16) ^ ((brow & 7) << 4)));
            }
#pragma unroll
            for (int i = 0; i < 4; ++i)
#pragma unroll
                for (int j = 0; j < 4; ++j)
                    acc[i][j] = __builtin_amdgcn_mfma_f32_16x16x32_bf16(af[i], bfr[j], acc[i][j], 0, 0, 0);
        }
    }
    size_t cbase = (size_t)boffC * blockIdx.z;
#pragma unroll
    for (int mi = 0; mi < 4; ++mi)
#pragma unroll
        for (int ni = 0; ni < 4; ++ni) {
            int col = bn + wc * 64 + ni * 16 + lr;
#pragma unroll
            for (int r = 0; r < 4; ++r) {
                int row = bm + wr * 64 + mi * 16 + lk * 4 + r;
                if (CB16)
                    ((ushortT*)Cv)[cbase + (size_t)row * ldc + col] = f2bf(acc[mi][ni][r] * scaleC);
                else
                    ((float*)Cv)[cbase + (size_t)row * ldc + col] = acc[mi][ni][r];
            }
        }
}

// ---------------- cast / transpose helpers ----------------
__global__ __launch_bounds__(256) void k_cast4(const float* __restrict__ src,
                                               ushortT* __restrict__ dst, int n4) {
    int i = blockIdx.x * 256 + threadIdx.x;
    if (i < n4) {
        float4 v = ((const float4*)src)[i];
        ushortT o[4] = {f2bf(v.x), f2bf(v.y), f2bf(v.z), f2bf(v.w)};
        *(uint2*)(dst + (size_t)i * 4) = *(uint2*)o;
    }
}

// dst[z][b][a] bf16 = src[a*sa + b + soff + z*sz]  (sb==1), tiles 32x32
__global__ __launch_bounds__(256) void k_tcast(const float* __restrict__ src,
                                               ushortT* __restrict__ dst,
                                               long sa, long soff, long sz,
                                               long da, long dz) {
    __shared__ float tile[32][33];
    int a0 = blockIdx.x * 32, b0 = blockIdx.y * 32;
    int tx = threadIdx.x & 31, ty = threadIdx.x >> 5;
    const float* s = src + (size_t)sz * blockIdx.z + soff;
#pragma unroll
    for (int i = ty; i < 32; i += 8)
        tile[i][tx] = s[(size_t)(a0 + i) * sa + (b0 + tx)];
    __syncthreads();
    ushortT* d = dst + (size_t)dz * blockIdx.z;
#pragma unroll
    for (int i = ty; i < 32; i += 8)
        d[(size_t)(b0 + i) * da + a0 + tx] = f2bf(tile[tx][i]);
}

// wuk_t[h][r][n] = W_kvb[r][h][n]
__global__ __launch_bounds__(256) void k_wuk_cast(const float* __restrict__ wkvb,
                                                  ushortT* __restrict__ wuk) {
    int i = blockIdx.x * 256 + threadIdx.x;
    int n = i & 127, r = (i >> 7) & 511, h = i >> 16;
    wuk[i] = f2bf(wkvb[(size_t)r * 8192 + h * 256 + n]);
}

// ------- kv postprocess -> kcat bf16 (T,576) ----
__global__ __launch_bounds__(256) void k_kv_post2(const float* __restrict__ kv,
                                                  const float* __restrict__ lnw,
                                                  const float* __restrict__ cosT,
                                                  const float* __restrict__ sinT,
                                                  ushortT* __restrict__ kcat) {
    int t = blockIdx.x, tid = threadIdx.x;
    const float* row = kv + (size_t)t * 576;
    float v0 = row[tid], v1 = row[tid + 256];
    float s = v0 * v0 + v1 * v1;
    for (int o = 32; o > 0; o >>= 1) s += __shfl_down(s, o);
    __shared__ float sm[4];
    if ((tid & 63) == 0) sm[tid >> 6] = s;
    __syncthreads();
    float tot = sm[0] + sm[1] + sm[2] + sm[3];
    float inv = 1.f / sqrtf(tot / 512.f + 1e-6f);
    ushortT* out = kcat + (size_t)t * 576;
    out[tid] = f2bf(v0 * inv * lnw[tid]);
    out[tid + 256] = f2bf(v1 * inv * lnw[tid + 256]);
    if (tid < 32) {
        float c = cosT[t * 32 + tid], sn = sinT[t * 32 + tid];
        float x1 = row[512 + 2 * tid], x2 = row[512 + 2 * tid + 1];
        out[512 + 2 * tid] = f2bf(x1 * c - x2 * sn);
        out[512 + 2 * tid + 1] = f2bf(x2 * c + x1 * sn);
    }
}

// ------- rope on q_pe (bf16 qfull) -> qcat[...,512:576] (SCALE folded) ------------------
__global__ __launch_bounds__(256) void k_rope_q2(const ushortT* __restrict__ qfull,
                                                 const float* __restrict__ cosT,
                                                 const float* __restrict__ sinT,
                                                 ushortT* __restrict__ qcat) {
    int b = blockIdx.x * 8 + (threadIdx.x >> 5);
    int i = threadIdx.x & 31;
    int t = b >> 5, h = b & 31;
    const ushortT* p = qfull + (size_t)b * 192 + 128;
    float c = cosT[t * 32 + i], s = sinT[t * 32 + i];
    float x1 = bf2f(p[2 * i]), x2 = bf2f(p[2 * i + 1]);
    ushortT* q = qcat + (size_t)t * 18432 + h * 576 + 512;
    q[2 * i] = f2bf((x1 * c - x2 * s) * SCALE_F);
    q[2 * i + 1] = f2bf((x2 * c + x1 * s) * SCALE_F);
}

// ---- indexer k: sum 16 split-K partials + layernorm + neox rope + fp8 quant -> bytes ----
__global__ __launch_bounds__(128) void k_ki_post16(const float* __restrict__ kp,
                                                   const float* __restrict__ g,
                                                   const float* __restrict__ be,
                                                   const float* __restrict__ cosT,
                                                   const float* __restrict__ sinT,
                                                   uchar* __restrict__ ki8,
                                                   float* __restrict__ kscale) {
    int t = blockIdx.x, i = threadIdx.x;
    float x = 0.f;
#pragma unroll
    for (int z = 0; z < 16; ++z) x += kp[(size_t)z * 262144 + (size_t)t * 128 + i];
    float s = x;
    for (int o = 32; o > 0; o >>= 1) s += __shfl_down(s, o);
    __shared__ float sm[2];
    if ((i & 63) == 0) sm[i >> 6] = s;
    __syncthreads();
    float mean = (sm[0] + sm[1]) / 128.f;
    float d = x - mean;
    float s2 = d * d;
    for (int o = 32; o > 0; o >>= 1) s2 += __shfl_down(s2, o);
    __shared__ float sv[2];
    if ((i & 63) == 0) sv[i >> 6] = s2;
    __syncthreads();
    float var = (sv[0] + sv[1]) / 128.f;
    float nrm = d * (1.f / sqrtf(var + 1e-6f)) * g[i] + be[i];
    __shared__ float buf[128];
    buf[i] = nrm;
    __syncthreads();
    float out;
    if (i < 32)      out = buf[i] * cosT[t * 32 + i] - buf[i + 32] * sinT[t * 32 + i];
    else if (i < 64) out = buf[i] * cosT[t * 32 + i - 32] + buf[i - 32] * sinT[t * 32 + i - 32];
    else             out = nrm;
    float a = fabsf(out);
    for (int o = 32; o > 0; o >>= 1) a = fmaxf(a, __shfl_down(a, o));
    __shared__ float am[2];
    if ((i & 63) == 0) am[i >> 6] = a;
    __syncthreads();
    float amax = fmaxf(fmaxf(am[0], am[1]), 1e-10f);
    float scale = __int_as_float((((int)ceilf(log2f(amax / 448.f))) + 127) << 23);
    ki8[(size_t)t * 128 + i] = enc_e4m3(q_e4m3(out / scale));
    if (i == 0) kscale[t] = scale;
}

// ---- indexer q: sum 2 split-K partials + neox rope + fp8 quant -> bytes -----------------
__global__ __launch_bounds__(128) void k_qi_post2(const float* __restrict__ p0,
                                                  const float* __restrict__ p1,
                                                  const float* __restrict__ cosT,
                                                  const float* __restrict__ sinT,
                                                  uchar* __restrict__ qi8,
                                                  float* __restrict__ qscale) {
    int b = blockIdx.x;
    int t = b >> 5;
    int i = threadIdx.x;
    float x = p0[(size_t)b * 128 + i] + p1[(size_t)b * 128 + i];
    __shared__ float buf[128];
    buf[i] = x;
    __syncthreads();
    float out;
    if (i < 32)      out = buf[i] * cosT[t * 32 + i] - buf[i + 32] * sinT[t * 32 + i];
    else if (i < 64) out = buf[i] * cosT[t * 32 + i - 32] + buf[i - 32] * sinT[t * 32 + i - 32];
    else             out = x;
    float a = fabsf(out);
    for (int o = 32; o > 0; o >>= 1) a = fmaxf(a, __shfl_down(a, o));
    __shared__ float am[2];
    if ((i & 63) == 0) am[i >> 6] = a;
    __syncthreads();
    float amax = fmaxf(fmaxf(am[0], am[1]), 1e-10f);
    float scale = __int_as_float((((int)ceilf(log2f(amax / 448.f))) + 127) << 23);
    qi8[(size_t)b * 128 + i] = enc_e4m3(q_e4m3(out / scale));
    if (i == 0) qscale[b] = scale;
}

// ---------------- indexer weights ----------------
__global__ __launch_bounds__(256) void k_wiw(const float* __restrict__ hs,
                                             const float* __restrict__ W_iw,
                                             const float* __restrict__ qscale,
                                             float* __restrict__ wts) {
    int t = blockIdx.x, tid = threadIdx.x;
    __shared__ float hr[2048];
    for (int i = tid; i < 2048; i += 256) hr[i] = hs[(size_t)t * 2048 + i];
    __syncthreads();
    int h = tid & 31, p = tid >> 5;
    float s = 0;
    for (int k = p * 256; k < p * 256 + 256; ++k) s = fmaf(hr[k], W_iw[(size_t)k * 32 + h], s);
    __shared__ float part[8][32];
    part[p][h] = s;
    __syncthreads();
    if (tid < 32) {
        float tot = 0;
#pragma unroll
        for (int pp = 0; pp < 8; ++pp) tot += part[pp][tid];
        const float a = (float)0.08838834764831845;   // 128^-0.5
        const float b = (float)0.1767766952966369;    // 32^-0.5
        wts[t * 32 + tid] = tot * qscale[t * 32 + tid] * a * b;
    }
}

// ======== indexer score via fp8 MFMA ====
__global__ __launch_bounds__(256) void k_score8(const uchar* __restrict__ qi8,
                                                const uchar* __restrict__ ki8,
                                                const float* __restrict__ kscale,
                                                const float* __restrict__ wts,
                                                float* __restrict__ score) {
    int b = blockIdx.x;
    int ti = (int)((sqrtf(8.f * b + 1.f) - 1.f) * 0.5f);
    while ((ti + 1) * (ti + 2) / 2 <= b) ++ti;
    while (ti * (ti + 1) / 2 > b) --ti;
    int si = b - ti * (ti + 1) / 2;
    int t0 = ti * 32, s0 = si * 32;
    int tid = threadIdx.x, lane = tid & 63, w = tid >> 6;
    int qt = w >> 1, qs = w & 1;
    int col = lane & 15, g = lane >> 4;

    __shared__ __align__(16) uchar k8s[4096];
    __shared__ __align__(16) uchar q8s[32768];
    __shared__ float wts_s[32][33];

    {
        int row = tid >> 3, inner = tid & 7;
        uint4 v = *(const uint4*)(ki8 + (size_t)(s0 + row) * 128 + inner * 16);
        *(uint4*)(k8s + ((row * 128 + inner * 16) ^ ((row & 7) << 4))) = v;
    }
    for (int c = tid; c < 1024; c += 256) {
        int tl = c >> 5, h = c & 31;
        wts_s[tl][h] = wts[(size_t)(t0 + tl) * 32 + h];
    }

    float ksc = kscale[s0 + qs * 16 + col];
    int arow = qt * 16 + col;
    int brow = qs * 16 + col;
    float sacc[4] = {0.f, 0.f, 0.f, 0.f};

    for (int h0 = 0; h0 < 32; h0 += 8) {
        __syncthreads();
        for (int c = tid; c < 2048; c += 256) {
            int hh = c >> 8, row = (c >> 3) & 31, inner = c & 7;
            uint4 v = *(const uint4*)(qi8 + ((size_t)(t0 + row) * 32 + h0 + hh) * 128 + inner * 16);
            *(uint4*)(q8s + hh * 4096 + ((row * 128 + inner * 16) ^ ((row & 7) << 4))) = v;
        }
        __syncthreads();
#pragma unroll
        for (int hh = 0; hh < 8; ++hh) {
            f32x4 c4 = (f32x4){0.f, 0.f, 0.f, 0.f};
#pragma unroll
            for (int kk = 0; kk < 4; ++kk) {
                long long a = *(const long long*)(q8s + hh * 4096 +
                              ((arow * 128 + kk * 32 + g * 8) ^ ((arow & 7) << 4)));
                long long bb = *(const long long*)(k8s +
                              ((brow * 128 + kk * 32 + g * 8) ^ ((brow & 7) << 4)));
                c4 = __builtin_amdgcn_mfma_f32_16x16x32_fp8_fp8(a, bb, c4, 0, 0, 0);
            }
            int h = h0 + hh;
#pragma unroll
            for (int r = 0; r < 4; ++r)
                sacc[r] = fmaf(fmaxf(c4[r] * ksc, 0.f), wts_s[qt * 16 + g * 4 + r][h], sacc[r]);
        }
    }
    int t = t0 + qt * 16 + g * 4;
    int s = s0 + qs * 16 + col;
#pragma unroll
    for (int r = 0; r < 4; ++r)
        if (s <= t + r) score[(size_t)(t + r) * T_N + s] = sacc[r];
}

// ---------------- top-512 per row (stable ties) --------------------------
__global__ __launch_bounds__(256) void k_topk(const float* __restrict__ score,
                                              int* __restrict__ tki, int* __restrict__ tkc) {
    int t = blockIdx.x;
    int n = t + 1;
    int tid = threadIdx.x;
    if (n <= TOPK_N) {
        for (int i = tid; i < n; i += 256) tki[(size_t)t * TOPK_N + i] = i;
        if (tid == 0) tkc[t] = n;
        return;
    }
    __shared__ unsigned keys[2048];
    const float* row = score + (size_t)t * T_N;
    for (int i = tid; i < n; i += 256) {
        float f = row[i] + 0.f;
        unsigned u = __float_as_uint(f);
        u = (u & 0x80000000u) ? ~u : (u | 0x80000000u);
        keys[i] = u;
    }
    __shared__ int hist[256];
    __shared__ unsigned sh_prefix;
    __shared__ int sh_need;
    if (tid == 0) { sh_prefix = 0u; sh_need = TOPK_N; }
    __syncthreads();
    unsigned maskHi = 0;
    for (int level = 3; level >= 0; --level) {
        hist[tid] = 0;
        __syncthreads();
        unsigned prefix = sh_prefix;
        int shift = level * 8;
        for (int i = tid; i < n; i += 256) {
            unsigned kk = keys[i];
            if ((kk & maskHi) == prefix) atomicAdd(&hist[(kk >> shift) & 255], 1);
        }
        __syncthreads();
        if (tid == 0) {
            int need = sh_need, cum = 0, bsel = 255;
            for (int bb = 255; bb >= 0; --bb) {
                if (cum + hist[bb] >= need) { bsel = bb; break; }
                cum += hist[bb];
            }
            sh_need = need - cum;
            sh_prefix = prefix | ((unsigned)bsel << shift);
        }
        __syncthreads();
        maskHi |= (0xFFu << shift);
    }
    unsigned thr = sh_prefix;
    int needEq = sh_need;
    int base = tid * 8;
    int eqcnt = 0;
#pragma unroll
    for (int j = 0; j < 8; ++j) {
        int i = base + j;
        if (i < n && keys[i] == thr) eqcnt++;
    }
    __shared__ int scn[256];
    scn[tid] = eqcnt;
    __syncthreads();
    for (int off = 1; off < 256; off <<= 1) {
        int add = (tid >= off) ? scn[tid - off] : 0;
        __syncthreads();
        scn[tid] += add;
        __syncthreads();
    }
    int eq_excl = scn[tid] - eqcnt;
    int acnt = 0;
    {
        int eqr = eq_excl;
#pragma unroll
        for (int j = 0; j < 8; ++j) {
            int i = base + j;
            if (i < n) {
                unsigned kk = keys[i];
                bool a = (kk > thr) || (kk == thr && eqr < needEq);
                if (kk == thr) eqr++;
                if (a) acnt++;
            }
        }
    }
    __syncthreads();
    scn[tid] = acnt;
    __syncthreads();
    for (int off = 1; off < 256; off <<= 1) {
        int add = (tid >= off) ? scn[tid - off] : 0;
        __syncthreads();
        scn[tid] += add;
        __syncthreads();
    }
    int pos = scn[tid] - acnt;
    {
        int eqr = eq_excl;
#pragma unroll
        for (int j = 0; j < 8; ++j) {
            int i = base + j;
            if (i < n) {
                unsigned kk = keys[i];
                bool a = (kk > thr) || (kk == thr && eqr < needEq);
                if (kk == thr) eqr++;
                if (a) tki[(size_t)t * TOPK_N + (pos++)] = i;
            }
        }
    }
    if (tid == 0) tkc[t] = TOPK_N;
}

// ======== fused sparse MFMA attention (latency-optimized staging, round 9) ==============
// Slice layouts (pow2-aligned, swizzle ^((row&7)<<4)):
//   qs: [kk 0..17][32 heads][32 dims]  (2048B slices)
//   kb score: [kk 0..17][64 keys][32 dims] (4096B slices) | kb PV: [512 dims][72 keys]
// Register prefetch of next chunk's gathers hides L2 latency under barrier+MFMA.
__global__ __launch_bounds__(512) void k_attn_mfma(const ushortT* __restrict__ qcat,
                                                   const ushortT* __restrict__ kcat,
                                                   const int* __restrict__ tki,
                                                   const int* __restrict__ tkc,
                                                   ushortT* __restrict__ olat) {
    int t = blockIdx.x;
    int tid = threadIdx.x;
    int lane = tid & 63;
    int w = tid >> 6;
    int S = tkc[t];
    int nchunk = (S + 63) >> 6;

    __shared__ int idx_s[512];
    __shared__ __align__(16) ushortT qs[18432];   // 36864 B
    __shared__ __align__(16) ushortT kb[36864];   // 73728 B (score slices / PV transposed)
    __shared__ __align__(16) ushortT ps[16384];   // 32768 B
    __shared__ float red[256];

    idx_s[tid] = (tid < S) ? tki[(size_t)t * TOPK_N + tid] : 0;
    // stage q into slice layout: thread: head = tid&31, dg = (tid>>5) + i*16
    {
        const ushortT* qrow = qcat + (size_t)t * 18432;
        int head = tid & 31, dg0 = tid >> 5;
        int inner = ((head * 64 + (dg0 & 3) * 16) ^ ((head & 7) << 4));
        int kk0 = dg0 >> 2;
#pragma unroll
        for (int i = 0; i < 5; ++i) {
            int dg = dg0 + i * 16;
            if (dg < 72) {
                uint4 v = *(const uint4*)(qrow + head * 576 + dg * 8);
                *(uint4*)((char*)qs + (kk0 + 4 * i) * 2048 + inner) = v;
            }
        }
    }
    __syncthreads();

    int lr = lane & 15, lk = lane >> 4;
    int mt = w >> 2, nt = w & 3;
    int arow = mt * 16 + lr;
    int a_base = (arow * 64 + lk * 16) ^ ((arow & 7) << 4);
    int brow = nt * 16 + lr;
    int b_base = (brow * 64 + lk * 16) ^ ((brow & 7) << 4);

    // ---- score pass: per-chunk stage (prefetched) + 18 MFMA ----
    int keyl = tid & 63;
    int sdg0 = tid >> 6;                           // dg = sdg0 + i*8
    int s_inner = ((keyl * 64 + (sdg0 & 3) * 16) ^ ((keyl & 7) << 4));
    int s_kk0 = sdg0 >> 2;

    f32x4 acc[8];
#pragma unroll
    for (int p = 0; p < 8; ++p) acc[p] = (f32x4){0.f, 0.f, 0.f, 0.f};

    uint4 sv[9];
    {   // prefetch chunk 0
        bool ok = keyl < S;
        const ushortT* g = kcat + (size_t)idx_s[keyl] * 576;
#pragma unroll
        for (int i = 0; i < 9; ++i) {
            uint4 v = {0, 0, 0, 0};
            if (ok) v = *(const uint4*)(g + (sdg0 + i * 8) * 8);
            sv[i] = v;
        }
    }
    for (int p = 0; p < nchunk; ++p) {
        // write staged regs to LDS
#pragma unroll
        for (int i = 0; i < 9; ++i)
            *(uint4*)((char*)kb + (s_kk0 + 2 * i) * 4096 + s_inner) = sv[i];
        // prefetch next chunk
        if (p + 1 < nchunk) {
            int gk = (p + 1) * 64 + keyl;
            bool ok = gk < S;
            const ushortT* g = kcat + (size_t)idx_s[gk] * 576;
#pragma unroll
            for (int i = 0; i < 9; ++i) {
                uint4 v = {0, 0, 0, 0};
                if (ok) v = *(const uint4*)(g + (sdg0 + i * 8) * 8);
                sv[i] = v;
            }
        }
        __syncthreads();
#pragma unroll
        for (int kk = 0; kk < 18; ++kk) {
            bf16x8 a = *(const bf16x8*)((const char*)qs + kk * 2048 + a_base);
            bf16x8 b = *(const bf16x8*)((const char*)kb + kk * 4096 + b_base);
            acc[p] = __builtin_amdgcn_mfma_f32_16x16x32_bf16(a, b, acc[p], 0, 0, 0);
        }
        __syncthreads();
    }

    // ---- softmax (C layout: key = lr within tile, head = hb + reg) ----
    int hb = mt * 16 + lk * 4;
    float mx[4];
#pragma unroll
    for (int r = 0; r < 4; ++r) mx[r] = -1e30f;
#pragma unroll
    for (int p = 0; p < 8; ++p) {
        int key = p * 64 + nt * 16 + lr;
        if (key < S) {
#pragma unroll
            for (int r = 0; r < 4; ++r) mx[r] = fmaxf(mx[r], acc[p][r]);
        }
    }
#pragma unroll
    for (int off = 1; off < 16; off <<= 1)
#pragma unroll
        for (int r = 0; r < 4; ++r) mx[r] = fmaxf(mx[r], __shfl_xor(mx[r], off));
    if (lr == 0)
#pragma unroll
        for (int r = 0; r < 4; ++r) red[(hb + r) * 8 + w] = mx[r];
    __syncthreads();
    float m_[4];
#pragma unroll
    for (int r = 0; r < 4; ++r) {
        const float* rp = &red[(hb + r) * 8 + mt * 4];
        m_[r] = fmaxf(fmaxf(rp[0], rp[1]), fmaxf(rp[2], rp[3]));
    }
    __syncthreads();
    float sm_[4] = {0.f, 0.f, 0.f, 0.f};
#pragma unroll
    for (int p = 0; p < 8; ++p) {
        int key = p * 64 + nt * 16 + lr;
#pragma unroll
        for (int r = 0; r < 4; ++r) {
            float e = (key < S) ? expf(acc[p][r] - m_[r]) : 0.f;
            acc[p][r] = e;      // fuse: reuse acc as exp storage
            sm_[r] += e;
        }
    }
#pragma unroll
    for (int off = 1; off < 16; off <<= 1)
#pragma unroll
        for (int r = 0; r < 4; ++r) sm_[r] += __shfl_xor(sm_[r], off);
    if (lr == 0)
#pragma unroll
        for (int r = 0; r < 4; ++r) red[(hb + r) * 8 + w] = sm_[r];
    __syncthreads();
    float dv[4];
#pragma unroll
    for (int r = 0; r < 4; ++r) {
        const float* rp = &red[(hb + r) * 8 + mt * 4];
        dv[r] = 1.f / (rp[0] + rp[1] + rp[2] + rp[3]);
    }
#pragma unroll
    for (int p = 0; p < 8; ++p) {
        int key = p * 64 + nt * 16 + lr;
#pragma unroll
        for (int r = 0; r < 4; ++r) {
            int head = hb + r;
            int byteoff = (head * 1024 + key * 2) ^ ((head & 7) << 4);
            *(ushortT*)((char*)ps + byteoff) = f2bf(acc[p][r] * dv[r]);
        }
    }
    __syncthreads();

    // ---- PV pass: transposed stage (key-pair uint writes, prefetched) + MFMA ----
    f32x4 oa[2][4];
#pragma unroll
    for (int i = 0; i < 2; ++i)
#pragma unroll
        for (int j = 0; j < 4; ++j) oa[i][j] = (f32x4){0.f, 0.f, 0.f, 0.f};

    int kp = tid & 31, dgp0 = tid >> 5;            // keys 2kp,2kp+1; dg = dgp0 + i*16
    uint4 pv0[5], pv1[5];
    {   // prefetch chunk 0
        int k0i = kp * 2;
        const ushortT* g0 = kcat + (size_t)idx_s[k0i] * 576;
        const ushortT* g1 = kcat + (size_t)idx_s[k0i + 1] * 576;
        bool ok0 = k0i < S, ok1 = k0i + 1 < S;
#pragma unroll
        for (int i = 0; i < 5; ++i) {
            int dg = dgp0 + i * 16;
            uint4 v0 = {0, 0, 0, 0}, v1 = {0, 0, 0, 0};
            if (dg < 72) {
                if (ok0) v0 = *(const uint4*)(g0 + dg * 8);
                if (ok1) v1 = *(const uint4*)(g1 + dg * 8);
            }
            pv0[i] = v0; pv1[i] = v1;
        }
    }
    for (int p = 0; p < nchunk; ++p) {
        // write transposed: kb as [dim][72 keys]; uint = (key 2kp, 2kp+1) at one dim
        unsigned* dst = (unsigned*)kb;
#pragma unroll
        for (int i = 0; i < 5; ++i) {
            int dg = dgp0 + i * 16;
            if (dg < 72) {
                const ushortT* p0 = (const ushortT*)&pv0[i];
                const ushortT* p1 = (const ushortT*)&pv1[i];
#pragma unroll
                for (int j = 0; j < 8; ++j)
                    dst[(dg * 8 + j) * 36 + kp] = (unsigned)p0[j] | ((unsigned)p1[j] << 16);
            }
        }
        // prefetch next chunk
        if (p + 1 < nchunk) {
            int k0i = (p + 1) * 64 + kp * 2;
            const ushortT* g0 = kcat + (size_t)idx_s[k0i] * 576;
            const ushortT* g1 = kcat + (size_t)idx_s[k0i + 1] * 576;
            bool ok0 = k0i < S, ok1 = k0i + 1 < S;
#pragma unroll
            for (int i = 0; i < 5; ++i) {
                int dg = dgp0 + i * 16;
                uint4 v0 = {0, 0, 0, 0}, v1 = {0, 0, 0, 0};
                if (dg < 72) {
                    if (ok0) v0 = *(const uint4*)(g0 + dg * 8);
                    if (ok1) v1 = *(const uint4*)(g1 + dg * 8);
                }
                pv0[i] = v0; pv1[i] = v1;
            }
        }
        __syncthreads();
#pragma unroll
        for (int kk = 0; kk < 2; ++kk) {
#pragma unroll
            for (int m2 = 0; m2 < 2; ++m2) {
                bf16x8 a = *(const bf16x8*)((const char*)ps +
                    (((m2 * 16 + lr) * 1024 + (p * 64 + kk * 32 + lk * 8) * 2) ^ ((lr & 7) << 4)));
#pragma unroll
                for (int n2 = 0; n2 < 4; ++n2) {
                    bf16x8 b = *(const bf16x8*)((const char*)kb +
                        ((w * 64 + n2 * 16 + lr) * 144 + (kk * 32 + lk * 8) * 2));
                    oa[m2][n2] = __builtin_amdgcn_mfma_f32_16x16x32_bf16(a, b, oa[m2][n2], 0, 0, 0);
                }
            }
        }
        __syncthreads();
    }
    // in-place write over this block's own qcat row (layout: t*18432 + head*512 + dim)
#pragma unroll
    for (int m2 = 0; m2 < 2; ++m2)
#pragma unroll
        for (int n2 = 0; n2 < 4; ++n2) {
            int dim = w * 64 + n2 * 16 + lr;
#pragma unroll
            for (int r = 0; r < 4; ++r) {
                int head = m2 * 16 + lk * 4 + r;
                olat[(size_t)t * 18432 + head * 512 + dim] = f2bf(oa[m2][n2][r]);
            }
        }
}

// ---------------- launch ----------------
extern "C" void kernel_launch(void* const* d_in, const int* in_sizes, int n_in,
                              void* d_out, int out_size, void* d_ws, size_t ws_size,
                              hipStream_t stream) {
    (void)in_sizes; (void)n_in; (void)out_size; (void)ws_size;
    const int*   positions = (const int*)d_in[0];
    const float* hs        = (const float*)d_in[1];
    const float* q_c       = (const float*)d_in[2];
    const float* kv_lora   = (const float*)d_in[3];
    const float* W_qb      = (const float*)d_in[4];
    const float* W_kvb     = (const float*)d_in[5];
    const float* W_o       = (const float*)d_in[6];
    const float* kv_ln     = (const float*)d_in[7];
    const float* W_iq      = (const float*)d_in[8];
    const float* W_ik      = (const float*)d_in[9];
    const float* gamma     = (const float*)d_in[10];
    const float* beta      = (const float*)d_in[11];
    const float* W_iw      = (const float*)d_in[12];

    float* ws = (float*)d_ws;
    // workspace (float offsets); high-water 50,204,672 fl = 200.8 MB (< 218.4 proven)
    float*   cosT   = ws;                          // 65,536
    float*   sinT   = ws + 65536;                  // 65,536
    int*     tki    = (int*)(ws + 131072);         // 1,048,576
    int*     tkc    = (int*)(ws + 1179648);        // 2,048
    ushortT* kcat   = (ushortT*)(ws + 1181696);    // 589,824 fl
    float*   kscale = ws + 1771520;                // 2,048
    float*   qscale = ws + 1773568;                // 65,536
    float*   wts    = ws + 1839104;                // 65,536
    uchar*   qi8    = (uchar*)(ws + 1904640);      // 2,097,152 fl (8 MB bytes)
    uchar*   ki8    = (uchar*)(ws + 4001792);      // 65,536 fl
    // REGION R1 4067328..20844544, time-multiplexed:
    float*   kip    = ws + 4067328;                // 16 x 262,144 [step2 -> dead after 3]
    float*   qip0   = ws + 4067328;                // 8,388,608   [step4 -> dead after 5]
    float*   qip1   = ws + 12455936;               // 8,388,608   [step4 -> dead after 5]
    ushortT* wqb_t  = (ushortT*)(ws + 4067328);    // 4,718,592 fl [10 -> dead after 11]
    ushortT* qc_bf  = (ushortT*)(ws + 8785920);    // 1,572,864 fl [10 -> dead after 11]
    ushortT* wuk_t  = (ushortT*)(ws + 10358784);   // 1,048,576 fl [10 -> dead after 13]
    ushortT* wuv_t  = (ushortT*)(ws + 11407360);   // 1,048,576 fl [10 -> read at 15]
    ushortT* wo_t   = (ushortT*)(ws + 4067328);    // 4,194,304 fl [13b over dead wqb_t]
    // score / vbuf slot:
    float*   score  = ws + 20844544;               // 4,194,304 [7 -> dead after 8]
    ushortT* vbuf   = (ushortT*)(ws + 20844544);   // 4,194,304 fl [15 -> 16]
    // persistent tail:
    ushortT* qfull_bf = (ushortT*)(ws + 25038848); // 6,291,456 fl [11 -> 12,13]
    ushortT* qcat   = (ushortT*)(ws + 31330304);   // 18,874,368 fl; o written in place (14)

    // 1. rope tables
    k_rope_tables<<<T_N, 32, 0, stream>>>(positions, cosT, sinT);
    // 2. indexer k: hs @ W_ik (2048x128x2048), split-K x16 -> partials
    gemm128<false><<<dim3(1, 16, 16), 256, 0, stream>>>(
        hs, W_ik, kip, T_N, 128, 128, HID_N, 128, 128, 128, 16384, 262144);
    // 3. sum partials + LN + neox rope + fp8 quant -> ki8 bytes
    k_ki_post16<<<T_N, 128, 0, stream>>>(kip, gamma, beta, cosT, sinT, ki8, kscale);
    // 4. indexer q: q_c @ W_iq (2048x4096x1536), split-K x2 -> partials
    gemm128<false><<<dim3(32, 16, 2), 256, 0, stream>>>(
        q_c, W_iq, qip0, T_N, 4096, 768, QLORA_N, 4096, 4096, 768, 3145728, 8388608);
    // 5. sum partials + neox rope + fp8 quant -> qi8 bytes
    k_qi_post2<<<T_N * IDX_H_N, 128, 0, stream>>>(qip0, qip1, cosT, sinT, qi8, qscale);
    // 6. indexer weights
    k_wiw<<<T_N, 256, 0, stream>>>(hs, W_iw, qscale, wts);
    // 7. indexer score via fp8 MFMA
    k_score8<<<2080, 256, 0, stream>>>(qi8, ki8, kscale, wts, score);
    // 8. top-512
    k_topk<<<T_N, 256, 0, stream>>>(score, tki, tkc);
    // 9. kv rms_norm + k_pe rope -> kcat bf16
    k_kv_post2<<<T_N, 256, 0, stream>>>(kv_lora, kv_ln, cosT, sinT, kcat);
    // 10. casts / transposes (R1 free again)
    k_cast4<<<3072, 256, 0, stream>>>(q_c, qc_bf, T_N * QLORA_N / 4);
    k_tcast<<<dim3(48, 192, 1), 256, 0, stream>>>(W_qb, wqb_t, 6144, 0, 0, 1536, 0);
    k_wuk_cast<<<8192, 256, 0, stream>>>(W_kvb, wuk_t);
    k_tcast<<<dim3(16, 4, 32), 256, 0, stream>>>(W_kvb, wuv_t, 8192, 128, 256, 512, 65536);
    // 11. qfull = q_c @ W_qb (bf16 MFMA) -> bf16 (T,32,192)
    bgemm<true><<<dim3(48, 16, 1), 256, 0, stream>>>(
        qc_bf, wqb_t, qfull_bf, QLORA_N, QLORA_N, QLORA_N, 6144, 0, 0, 0, 1.f);
    // 12. rope q_pe -> qcat[...,512:576]
    k_rope_q2<<<T_N * H_N / 8, 256, 0, stream>>>(qfull_bf, cosT, sinT, qcat);
    // 13. q_lat = q_nope @ W_UK^T per head -> qcat[...,0:512] (SCALE folded)
    bgemm<true><<<dim3(4, 16, 32), 256, 0, stream>>>(
        qfull_bf, wuk_t, qcat, NOPE_N, 6144, 128, 18432, 192, 65536, 576, SCALE_F);
    // 13b. wo_t transpose (over dead wqb_t)
    k_tcast<<<dim3(128, 64, 1), 256, 0, stream>>>(W_o, wo_t, 2048, 0, 0, 4096, 0);
    // 14. fused sparse MFMA attention -> o written in place into qcat rows
    k_attn_mfma<<<T_N, 512, 0, stream>>>(qcat, kcat, tki, tkc, qcat);
    // 15. v = o @ W_UV per head -> vbuf bf16 (T,4096)
    bgemm<true><<<dim3(1, 16, 32), 256, 0, stream>>>(
        qcat, wuv_t, vbuf, KVLORA_N, 18432, 512, 4096, 512, 65536, 128, 1.f);
    // 16. out = vbuf @ W_o -> f32
    bgemm<false><<<dim3(16, 16, 1), 256, 0, stream>>>(
        vbuf, wo_t, (float*)d_out, H_N * VD_N, 4096, 4096, HID_N, 0, 0, 0, 1.f);
}

// Round 10
// 1043.558 us; speedup vs baseline: 6.1510x; 1.0389x over previous
//
#include <hip/hip_runtime.h>
#include <hip/hip_bf16.h>

// ---------------- constants ----------------
#define T_N    2048
#define H_N    32
#define NOPE_N 128
#define ROPE_N 64
#define VD_N   128
#define QLORA_N 1536
#define KVLORA_N 512
#define IDX_H_N 32
#define IDX_D_N 128
#define TOPK_N 512
#define HID_N  2048

typedef __attribute__((ext_vector_type(8))) short bf16x8;
typedef __attribute__((ext_vector_type(4))) float f32x4;
typedef unsigned short ushortT;
typedef unsigned char uchar;

#define SCALE_F 0.07216878364870323f  // (NOPE+ROPE)^-0.5 = 192^-0.5

static __device__ __forceinline__ ushortT f2bf(float x) {
    __hip_bfloat16 b = __float2bfloat16(x);
    return *(ushortT*)&b;
}
static __device__ __forceinline__ float bf2f(ushortT u) {
    __hip_bfloat16 b = *(__hip_bfloat16*)&u;
    return __bfloat162float(b);
}

// exact RNE float -> e4m3fn grid
static __device__ __forceinline__ float q_e4m3(float x) {
    float ax = fabsf(x);
    unsigned b = __float_as_uint(ax);
    int e = (int)(b >> 23) - 126;
    int ue = (e - 4 > -9) ? (e - 4) : -9;
    float ulp = __int_as_float((ue + 127) << 23);
    float q = rintf(ax / ulp) * ulp;
    return copysignf(q, x);
}

// encode a value ALREADY on the e4m3fn grid (|q|<=448) to its fp8 byte
static __device__ __forceinline__ uchar enc_e4m3(float q) {
    unsigned b = __float_as_uint(q);
    unsigned s = (b >> 31) << 7;
    float ax = fabsf(q);
    if (ax == 0.f) return (uchar)s;
    int e = (int)((b >> 23) & 255) - 127;   // q = 1.m * 2^e
    if (e >= -6) {
        unsigned m = (b >> 20) & 7;         // exact: grid value has 3 mantissa bits
        return (uchar)(s | ((unsigned)(e + 7) << 3) | m);
    }
    unsigned M = (unsigned)rintf(ax * 512.f);  // subnormal: M * 2^-9, M in 1..7
    return (uchar)(s | M);
}

// ---------------- rope tables ----------------
__global__ void k_rope_tables(const int* __restrict__ pos, float* __restrict__ cosT,
                              float* __restrict__ sinT) {
    int t = blockIdx.x, i = threadIdx.x;
    double inv = 1.0 / pow(10000.0, (double)i / 32.0);
    double ang = (double)pos[t] * inv;
    cosT[t * 32 + i] = (float)cos(ang);
    sinT[t * 32 + i] = (float)sin(ang);
}

// ---------------- generic 128x128 f32 GEMM (BK=8), batched/split-K via blockIdx.z -------
template <bool BT>
__global__ __launch_bounds__(256) void gemm128(
    const float* __restrict__ A, const float* __restrict__ B, float* __restrict__ C,
    int M, int N, int K, int lda, int ldb, int ldc,
    long batchOffA, long batchOffB, long batchOffC) {
    const float* Ab = A + (size_t)batchOffA * blockIdx.z;
    const float* Bb = B + (size_t)batchOffB * blockIdx.z;
    int bm = blockIdx.y * 128, bn = blockIdx.x * 128;
    int tid = threadIdx.x;
    __shared__ float As[8][128];
    __shared__ float Bs[8][128];
    float acc[8][8];
#pragma unroll
    for (int i = 0; i < 8; ++i)
#pragma unroll
        for (int j = 0; j < 8; ++j) acc[i][j] = 0.f;
    int tx = tid & 15, ty = tid >> 4;
    int ar = tid >> 1, ak = (tid & 1) * 4;
    for (int k0 = 0; k0 < K; k0 += 8) {
        float4 av = *(const float4*)(Ab + (size_t)(bm + ar) * lda + k0 + ak);
        As[ak + 0][ar] = av.x; As[ak + 1][ar] = av.y;
        As[ak + 2][ar] = av.z; As[ak + 3][ar] = av.w;
        if (BT) {
            int n = tid >> 1, kk = (tid & 1) * 4;
            float4 bv = *(const float4*)(Bb + (size_t)(bn + n) * ldb + k0 + kk);
            Bs[kk + 0][n] = bv.x; Bs[kk + 1][n] = bv.y;
            Bs[kk + 2][n] = bv.z; Bs[kk + 3][n] = bv.w;
        } else {
            int kk = tid >> 5, n = (tid & 31) * 4;
            float4 bv = *(const float4*)(Bb + (size_t)(k0 + kk) * ldb + bn + n);
            Bs[kk][n + 0] = bv.x; Bs[kk][n + 1] = bv.y;
            Bs[kk][n + 2] = bv.z; Bs[kk][n + 3] = bv.w;
        }
        __syncthreads();
#pragma unroll
        for (int kk = 0; kk < 8; ++kk) {
            float4 a0 = *(const float4*)(&As[kk][ty * 8]);
            float4 a1 = *(const float4*)(&As[kk][ty * 8 + 4]);
            float4 b0 = *(const float4*)(&Bs[kk][tx * 8]);
            float4 b1 = *(const float4*)(&Bs[kk][tx * 8 + 4]);
            float a[8] = {a0.x, a0.y, a0.z, a0.w, a1.x, a1.y, a1.z, a1.w};
            float b[8] = {b0.x, b0.y, b0.z, b0.w, b1.x, b1.y, b1.z, b1.w};
#pragma unroll
            for (int i = 0; i < 8; ++i)
#pragma unroll
                for (int j = 0; j < 8; ++j) acc[i][j] = fmaf(a[i], b[j], acc[i][j]);
        }
        __syncthreads();
    }
    size_t cbase = (size_t)batchOffC * blockIdx.z;
#pragma unroll
    for (int i = 0; i < 8; ++i) {
        size_t r = bm + ty * 8 + i;
#pragma unroll
        for (int j = 0; j < 8; ++j) {
            size_t c = bn + tx * 8 + j;
            C[cbase + r * (size_t)ldc + c] = acc[i][j];
        }
    }
}

// ======== bf16 NT MFMA GEMM: A(M,K) bf16, B(N,K) bf16, 128x128 tile, BK=64 =============
template <bool CB16>
__global__ __launch_bounds__(256) void bgemm(
    const ushortT* __restrict__ A, const ushortT* __restrict__ B, void* __restrict__ Cv,
    int K, int lda, int ldb, int ldc,
    long boffA, long boffB, long boffC, float scaleC) {
    const ushortT* Ab = A + (size_t)boffA * blockIdx.z;
    const ushortT* Bb = B + (size_t)boffB * blockIdx.z;
    int bm = blockIdx.y * 128, bn = blockIdx.x * 128;
    int tid = threadIdx.x, lane = tid & 63, w = tid >> 6;
    int wr = w >> 1, wc = w & 1;
    int lr = lane & 15, lk = lane >> 4;

    __shared__ __align__(16) ushortT As[128 * 64];
    __shared__ __align__(16) ushortT Bs[128 * 64];

    f32x4 acc[4][4];
#pragma unroll
    for (int i = 0; i < 4; ++i)
#pragma unroll
        for (int j = 0; j < 4; ++j) acc[i][j] = (f32x4){0.f, 0.f, 0.f, 0.f};

    for (int kt = 0; kt < K; kt += 64) {
        __syncthreads();
#pragma unroll
        for (int q = 0; q < 4; ++q) {
            int ch = tid + q * 256;
            int row = ch >> 3, e8 = ch & 7;
            int byteoff = (row * 128 + e8 * 16) ^ ((row & 7) << 4);
            uint4 va = *(const uint4*)(Ab + (size_t)(bm + row) * lda + kt + e8 * 8);
            *(uint4*)((char*)As + byteoff) = va;
            uint4 vb = *(const uint4*)(Bb + (size_t)(bn + row) * ldb + kt + e8 * 8);
            *(uint4*)((char*)Bs + byteoff) = vb;
        }
        __syncthreads();
#pragma unroll
        for (int kk = 0; kk < 2; ++kk) {
            bf16x8 af[4], bfr[4];
#pragma unroll
            for (int i = 0; i < 4; ++i) {
                int arow = wr * 64 + i * 16 + lr;
                af[i] = *(const bf16x8*)((const char*)As +
                         ((arow * 128 + kk * 64 + lk * 16) ^ ((arow & 7) << 4)));
                int brow = wc * 64 + i * 16 + lr;
                bfr[i] = *(const bf16x8*)((const char*)Bs +
                         ((brow * 128 + kk * 64 + lk * 16) ^ ((brow & 7) << 4)));
            }
#pragma unroll
            for (int i = 0; i < 4; ++i)
#pragma unroll
                for (int j = 0; j < 4; ++j)
                    acc[i][j] = __builtin_amdgcn_mfma_f32_16x16x32_bf16(af[i], bfr[j], acc[i][j], 0, 0, 0);
        }
    }
    size_t cbase = (size_t)boffC * blockIdx.z;
#pragma unroll
    for (int mi = 0; mi < 4; ++mi)
#pragma unroll
        for (int ni = 0; ni < 4; ++ni) {
            int col = bn + wc * 64 + ni * 16 + lr;
#pragma unroll
            for (int r = 0; r < 4; ++r) {
                int row = bm + wr * 64 + mi * 16 + lk * 4 + r;
                if (CB16)
                    ((ushortT*)Cv)[cbase + (size_t)row * ldc + col] = f2bf(acc[mi][ni][r] * scaleC);
                else
                    ((float*)Cv)[cbase + (size_t)row * ldc + col] = acc[mi][ni][r];
            }
        }
}

// ---------------- cast / transpose helpers ----------------
__global__ __launch_bounds__(256) void k_cast4(const float* __restrict__ src,
                                               ushortT* __restrict__ dst, int n4) {
    int i = blockIdx.x * 256 + threadIdx.x;
    if (i < n4) {
        float4 v = ((const float4*)src)[i];
        ushortT o[4] = {f2bf(v.x), f2bf(v.y), f2bf(v.z), f2bf(v.w)};
        *(uint2*)(dst + (size_t)i * 4) = *(uint2*)o;
    }
}

// dst[z][b][a] bf16 = src[a*sa + b + soff + z*sz]  (sb==1), tiles 32x32
__global__ __launch_bounds__(256) void k_tcast(const float* __restrict__ src,
                                               ushortT* __restrict__ dst,
                                               long sa, long soff, long sz,
                                               long da, long dz) {
    __shared__ float tile[32][33];
    int a0 = blockIdx.x * 32, b0 = blockIdx.y * 32;
    int tx = threadIdx.x & 31, ty = threadIdx.x >> 5;
    const float* s = src + (size_t)sz * blockIdx.z + soff;
#pragma unroll
    for (int i = ty; i < 32; i += 8)
        tile[i][tx] = s[(size_t)(a0 + i) * sa + (b0 + tx)];
    __syncthreads();
    ushortT* d = dst + (size_t)dz * blockIdx.z;
#pragma unroll
    for (int i = ty; i < 32; i += 8)
        d[(size_t)(b0 + i) * da + a0 + tx] = f2bf(tile[tx][i]);
}

// wuk_t[h][r][n] = W_kvb[r][h][n]
__global__ __launch_bounds__(256) void k_wuk_cast(const float* __restrict__ wkvb,
                                                  ushortT* __restrict__ wuk) {
    int i = blockIdx.x * 256 + threadIdx.x;
    int n = i & 127, r = (i >> 7) & 511, h = i >> 16;
    wuk[i] = f2bf(wkvb[(size_t)r * 8192 + h * 256 + n]);
}

// ------- kv postprocess -> kcat bf16 (T,576) ----
__global__ __launch_bounds__(256) void k_kv_post2(const float* __restrict__ kv,
                                                  const float* __restrict__ lnw,
                                                  const float* __restrict__ cosT,
                                                  const float* __restrict__ sinT,
                                                  ushortT* __restrict__ kcat) {
    int t = blockIdx.x, tid = threadIdx.x;
    const float* row = kv + (size_t)t * 576;
    float v0 = row[tid], v1 = row[tid + 256];
    float s = v0 * v0 + v1 * v1;
    for (int o = 32; o > 0; o >>= 1) s += __shfl_down(s, o);
    __shared__ float sm[4];
    if ((tid & 63) == 0) sm[tid >> 6] = s;
    __syncthreads();
    float tot = sm[0] + sm[1] + sm[2] + sm[3];
    float inv = 1.f / sqrtf(tot / 512.f + 1e-6f);
    ushortT* out = kcat + (size_t)t * 576;
    out[tid] = f2bf(v0 * inv * lnw[tid]);
    out[tid + 256] = f2bf(v1 * inv * lnw[tid + 256]);
    if (tid < 32) {
        float c = cosT[t * 32 + tid], sn = sinT[t * 32 + tid];
        float x1 = row[512 + 2 * tid], x2 = row[512 + 2 * tid + 1];
        out[512 + 2 * tid] = f2bf(x1 * c - x2 * sn);
        out[512 + 2 * tid + 1] = f2bf(x2 * c + x1 * sn);
    }
}

// ------- rope on q_pe (bf16 qfull) -> qcat[...,512:576] (SCALE folded) ------------------
__global__ __launch_bounds__(256) void k_rope_q2(const ushortT* __restrict__ qfull,
                                                 const float* __restrict__ cosT,
                                                 const float* __restrict__ sinT,
                                                 ushortT* __restrict__ qcat) {
    int b = blockIdx.x * 8 + (threadIdx.x >> 5);
    int i = threadIdx.x & 31;
    int t = b >> 5, h = b & 31;
    const ushortT* p = qfull + (size_t)b * 192 + 128;
    float c = cosT[t * 32 + i], s = sinT[t * 32 + i];
    float x1 = bf2f(p[2 * i]), x2 = bf2f(p[2 * i + 1]);
    ushortT* q = qcat + (size_t)t * 18432 + h * 576 + 512;
    q[2 * i] = f2bf((x1 * c - x2 * s) * SCALE_F);
    q[2 * i + 1] = f2bf((x2 * c + x1 * s) * SCALE_F);
}

// ---- indexer k: sum 16 split-K partials + layernorm + neox rope + fp8 quant -> bytes ----
__global__ __launch_bounds__(128) void k_ki_post16(const float* __restrict__ kp,
                                                   const float* __restrict__ g,
                                                   const float* __restrict__ be,
                                                   const float* __restrict__ cosT,
                                                   const float* __restrict__ sinT,
                                                   uchar* __restrict__ ki8,
                                                   float* __restrict__ kscale) {
    int t = blockIdx.x, i = threadIdx.x;
    float x = 0.f;
#pragma unroll
    for (int z = 0; z < 16; ++z) x += kp[(size_t)z * 262144 + (size_t)t * 128 + i];
    float s = x;
    for (int o = 32; o > 0; o >>= 1) s += __shfl_down(s, o);
    __shared__ float sm[2];
    if ((i & 63) == 0) sm[i >> 6] = s;
    __syncthreads();
    float mean = (sm[0] + sm[1]) / 128.f;
    float d = x - mean;
    float s2 = d * d;
    for (int o = 32; o > 0; o >>= 1) s2 += __shfl_down(s2, o);
    __shared__ float sv[2];
    if ((i & 63) == 0) sv[i >> 6] = s2;
    __syncthreads();
    float var = (sv[0] + sv[1]) / 128.f;
    float nrm = d * (1.f / sqrtf(var + 1e-6f)) * g[i] + be[i];
    __shared__ float buf[128];
    buf[i] = nrm;
    __syncthreads();
    float out;
    if (i < 32)      out = buf[i] * cosT[t * 32 + i] - buf[i + 32] * sinT[t * 32 + i];
    else if (i < 64) out = buf[i] * cosT[t * 32 + i - 32] + buf[i - 32] * sinT[t * 32 + i - 32];
    else             out = nrm;
    float a = fabsf(out);
    for (int o = 32; o > 0; o >>= 1) a = fmaxf(a, __shfl_down(a, o));
    __shared__ float am[2];
    if ((i & 63) == 0) am[i >> 6] = a;
    __syncthreads();
    float amax = fmaxf(fmaxf(am[0], am[1]), 1e-10f);
    float scale = __int_as_float((((int)ceilf(log2f(amax / 448.f))) + 127) << 23);
    ki8[(size_t)t * 128 + i] = enc_e4m3(q_e4m3(out / scale));
    if (i == 0) kscale[t] = scale;
}

// ---- indexer q: sum 2 split-K partials + neox rope + fp8 quant -> bytes -----------------
__global__ __launch_bounds__(128) void k_qi_post2(const float* __restrict__ p0,
                                                  const float* __restrict__ p1,
                                                  const float* __restrict__ cosT,
                                                  const float* __restrict__ sinT,
                                                  uchar* __restrict__ qi8,
                                                  float* __restrict__ qscale) {
    int b = blockIdx.x;
    int t = b >> 5;
    int i = threadIdx.x;
    float x = p0[(size_t)b * 128 + i] + p1[(size_t)b * 128 + i];
    __shared__ float buf[128];
    buf[i] = x;
    __syncthreads();
    float out;
    if (i < 32)      out = buf[i] * cosT[t * 32 + i] - buf[i + 32] * sinT[t * 32 + i];
    else if (i < 64) out = buf[i] * cosT[t * 32 + i - 32] + buf[i - 32] * sinT[t * 32 + i - 32];
    else             out = x;
    float a = fabsf(out);
    for (int o = 32; o > 0; o >>= 1) a = fmaxf(a, __shfl_down(a, o));
    __shared__ float am[2];
    if ((i & 63) == 0) am[i >> 6] = a;
    __syncthreads();
    float amax = fmaxf(fmaxf(am[0], am[1]), 1e-10f);
    float scale = __int_as_float((((int)ceilf(log2f(amax / 448.f))) + 127) << 23);
    qi8[(size_t)b * 128 + i] = enc_e4m3(q_e4m3(out / scale));
    if (i == 0) qscale[b] = scale;
}

// ---------------- indexer weights ----------------
__global__ __launch_bounds__(256) void k_wiw(const float* __restrict__ hs,
                                             const float* __restrict__ W_iw,
                                             const float* __restrict__ qscale,
                                             float* __restrict__ wts) {
    int t = blockIdx.x, tid = threadIdx.x;
    __shared__ float hr[2048];
    for (int i = tid; i < 2048; i += 256) hr[i] = hs[(size_t)t * 2048 + i];
    __syncthreads();
    int h = tid & 31, p = tid >> 5;
    float s = 0;
    for (int k = p * 256; k < p * 256 + 256; ++k) s = fmaf(hr[k], W_iw[(size_t)k * 32 + h], s);
    __shared__ float part[8][32];
    part[p][h] = s;
    __syncthreads();
    if (tid < 32) {
        float tot = 0;
#pragma unroll
        for (int pp = 0; pp < 8; ++pp) tot += part[pp][tid];
        const float a = (float)0.08838834764831845;   // 128^-0.5
        const float b = (float)0.1767766952966369;    // 32^-0.5
        wts[t * 32 + tid] = tot * qscale[t * 32 + tid] * a * b;
    }
}

// ======== indexer score via fp8 MFMA ====
__global__ __launch_bounds__(256) void k_score8(const uchar* __restrict__ qi8,
                                                const uchar* __restrict__ ki8,
                                                const float* __restrict__ kscale,
                                                const float* __restrict__ wts,
                                                float* __restrict__ score) {
    int b = blockIdx.x;
    int ti = (int)((sqrtf(8.f * b + 1.f) - 1.f) * 0.5f);
    while ((ti + 1) * (ti + 2) / 2 <= b) ++ti;
    while (ti * (ti + 1) / 2 > b) --ti;
    int si = b - ti * (ti + 1) / 2;
    int t0 = ti * 32, s0 = si * 32;
    int tid = threadIdx.x, lane = tid & 63, w = tid >> 6;
    int qt = w >> 1, qs = w & 1;
    int col = lane & 15, g = lane >> 4;

    __shared__ __align__(16) uchar k8s[4096];
    __shared__ __align__(16) uchar q8s[32768];
    __shared__ float wts_s[32][33];

    {
        int row = tid >> 3, inner = tid & 7;
        uint4 v = *(const uint4*)(ki8 + (size_t)(s0 + row) * 128 + inner * 16);
        *(uint4*)(k8s + ((row * 128 + inner * 16) ^ ((row & 7) << 4))) = v;
    }
    for (int c = tid; c < 1024; c += 256) {
        int tl = c >> 5, h = c & 31;
        wts_s[tl][h] = wts[(size_t)(t0 + tl) * 32 + h];
    }

    float ksc = kscale[s0 + qs * 16 + col];
    int arow = qt * 16 + col;
    int brow = qs * 16 + col;
    float sacc[4] = {0.f, 0.f, 0.f, 0.f};

    for (int h0 = 0; h0 < 32; h0 += 8) {
        __syncthreads();
        for (int c = tid; c < 2048; c += 256) {
            int hh = c >> 8, row = (c >> 3) & 31, inner = c & 7;
            uint4 v = *(const uint4*)(qi8 + ((size_t)(t0 + row) * 32 + h0 + hh) * 128 + inner * 16);
            *(uint4*)(q8s + hh * 4096 + ((row * 128 + inner * 16) ^ ((row & 7) << 4))) = v;
        }
        __syncthreads();
#pragma unroll
        for (int hh = 0; hh < 8; ++hh) {
            f32x4 c4 = (f32x4){0.f, 0.f, 0.f, 0.f};
#pragma unroll
            for (int kk = 0; kk < 4; ++kk) {
                long long a = *(const long long*)(q8s + hh * 4096 +
                              ((arow * 128 + kk * 32 + g * 8) ^ ((arow & 7) << 4)));
                long long bb = *(const long long*)(k8s +
                              ((brow * 128 + kk * 32 + g * 8) ^ ((brow & 7) << 4)));
                c4 = __builtin_amdgcn_mfma_f32_16x16x32_fp8_fp8(a, bb, c4, 0, 0, 0);
            }
            int h = h0 + hh;
#pragma unroll
            for (int r = 0; r < 4; ++r)
                sacc[r] = fmaf(fmaxf(c4[r] * ksc, 0.f), wts_s[qt * 16 + g * 4 + r][h], sacc[r]);
        }
    }
    int t = t0 + qt * 16 + g * 4;
    int s = s0 + qs * 16 + col;
#pragma unroll
    for (int r = 0; r < 4; ++r)
        if (s <= t + r) score[(size_t)(t + r) * T_N + s] = sacc[r];
}

// ---------------- top-512 per row (stable ties) --------------------------
__global__ __launch_bounds__(256) void k_topk(const float* __restrict__ score,
                                              int* __restrict__ tki, int* __restrict__ tkc) {
    int t = blockIdx.x;
    int n = t + 1;
    int tid = threadIdx.x;
    if (n <= TOPK_N) {
        for (int i = tid; i < n; i += 256) tki[(size_t)t * TOPK_N + i] = i;
        if (tid == 0) tkc[t] = n;
        return;
    }
    __shared__ unsigned keys[2048];
    const float* row = score + (size_t)t * T_N;
    for (int i = tid; i < n; i += 256) {
        float f = row[i] + 0.f;
        unsigned u = __float_as_uint(f);
        u = (u & 0x80000000u) ? ~u : (u | 0x80000000u);
        keys[i] = u;
    }
    __shared__ int hist[256];
    __shared__ unsigned sh_prefix;
    __shared__ int sh_need;
    if (tid == 0) { sh_prefix = 0u; sh_need = TOPK_N; }
    __syncthreads();
    unsigned maskHi = 0;
    for (int level = 3; level >= 0; --level) {
        hist[tid] = 0;
        __syncthreads();
        unsigned prefix = sh_prefix;
        int shift = level * 8;
        for (int i = tid; i < n; i += 256) {
            unsigned kk = keys[i];
            if ((kk & maskHi) == prefix) atomicAdd(&hist[(kk >> shift) & 255], 1);
        }
        __syncthreads();
        if (tid == 0) {
            int need = sh_need, cum = 0, bsel = 255;
            for (int bb = 255; bb >= 0; --bb) {
                if (cum + hist[bb] >= need) { bsel = bb; break; }
                cum += hist[bb];
            }
            sh_need = need - cum;
            sh_prefix = prefix | ((unsigned)bsel << shift);
        }
        __syncthreads();
        maskHi |= (0xFFu << shift);
    }
    unsigned thr = sh_prefix;
    int needEq = sh_need;
    int base = tid * 8;
    int eqcnt = 0;
#pragma unroll
    for (int j = 0; j < 8; ++j) {
        int i = base + j;
        if (i < n && keys[i] == thr) eqcnt++;
    }
    __shared__ int scn[256];
    scn[tid] = eqcnt;
    __syncthreads();
    for (int off = 1; off < 256; off <<= 1) {
        int add = (tid >= off) ? scn[tid - off] : 0;
        __syncthreads();
        scn[tid] += add;
        __syncthreads();
    }
    int eq_excl = scn[tid] - eqcnt;
    int acnt = 0;
    {
        int eqr = eq_excl;
#pragma unroll
        for (int j = 0; j < 8; ++j) {
            int i = base + j;
            if (i < n) {
                unsigned kk = keys[i];
                bool a = (kk > thr) || (kk == thr && eqr < needEq);
                if (kk == thr) eqr++;
                if (a) acnt++;
            }
        }
    }
    __syncthreads();
    scn[tid] = acnt;
    __syncthreads();
    for (int off = 1; off < 256; off <<= 1) {
        int add = (tid >= off) ? scn[tid - off] : 0;
        __syncthreads();
        scn[tid] += add;
        __syncthreads();
    }
    int pos = scn[tid] - acnt;
    {
        int eqr = eq_excl;
#pragma unroll
        for (int j = 0; j < 8; ++j) {
            int i = base + j;
            if (i < n) {
                unsigned kk = keys[i];
                bool a = (kk > thr) || (kk == thr && eqr < needEq);
                if (kk == thr) eqr++;
                if (a) tki[(size_t)t * TOPK_N + (pos++)] = i;
            }
        }
    }
    if (tid == 0) tkc[t] = TOPK_N;
}

// ======== fused sparse MFMA attention, single-pass flash-style (round 10) ===============
// 4 waves (256 thr), 2 blocks/CU (74KB LDS). 16 chunks of 32 keys, each gathered ONCE.
// m=0 softmax (exp(s) direct; |s| << 88 so no overflow; identical math to max-shifted).
// Swizzles: (full_byte_offset) ^ ((row&7)<<4) applied AFTER the full offset (bijective).
__global__ __launch_bounds__(256, 2) void k_attn_mfma(const ushortT* __restrict__ qcat,
                                                      const ushortT* __restrict__ kcat,
                                                      const int* __restrict__ tki,
                                                      const int* __restrict__ tkc,
                                                      ushortT* __restrict__ olat) {
    int t = blockIdx.x;
    int tid = threadIdx.x;
    int lane = tid & 63;
    int w = tid >> 6;                 // 4 waves
    int S = tkc[t];
    int nchunk = (S + 31) >> 5;

    __shared__ int idx_s[512];
    __shared__ __align__(16) ushortT kbK[18 * 1024];  // [kk][32 keys][32 dims] 36864B
    __shared__ __align__(16) ushortT kbV[512 * 32];   // [512 dims][32 keys]    32768B
    __shared__ __align__(16) ushortT psc[32 * 32];    // [32 heads][32 keys]     2048B
    __shared__ float red[64];                         // [head][nt] partial sums

    idx_s[tid] = (tid < S) ? tki[(size_t)t * TOPK_N + tid] : 0;
    idx_s[tid + 256] = (tid + 256 < S) ? tki[(size_t)t * TOPK_N + tid + 256] : 0;

    int lr = lane & 15, lk = lane >> 4;
    int mt = w >> 1, nt = w & 1;      // score quadrant: heads mt*16, keys nt*16

    // q fragments in registers: head = mt*16+lr, dims kk*32 + lk*8 .. +8
    bf16x8 qf[18];
    {
        const ushortT* qrow = qcat + (size_t)t * 18432 + (size_t)(mt * 16 + lr) * 576 + lk * 8;
#pragma unroll
        for (int kk = 0; kk < 18; ++kk) qf[kk] = *(const bf16x8*)(qrow + kk * 32);
    }
    __syncthreads();

    // staging: key = tid&31, part = tid>>5 (0..7), dg = part + i*8 (16B units of 1152B row)
    int skey = tid & 31, part = tid >> 5;

    f32x4 oa[2][8];
#pragma unroll
    for (int i = 0; i < 2; ++i)
#pragma unroll
        for (int j = 0; j < 8; ++j) oa[i][j] = (f32x4){0.f, 0.f, 0.f, 0.f};
    float sm_[4] = {0.f, 0.f, 0.f, 0.f};

    uint4 sv[9];
    {   // prefetch chunk 0
        bool ok = skey < S;
        const ushortT* g = kcat + (size_t)idx_s[skey] * 576 + part * 8;
#pragma unroll
        for (int i = 0; i < 9; ++i) {
            uint4 v = {0, 0, 0, 0};
            if (ok) v = *(const uint4*)(g + i * 64);
            sv[i] = v;
        }
    }

    for (int p = 0; p < nchunk; ++p) {
        // ---- stage chunk p: K-layout + V-transposed ----
#pragma unroll
        for (int i = 0; i < 9; ++i) {
            int dg = part + i * 8;
            int off = ((skey * 64 + (dg & 3) * 16) ^ ((skey & 7) << 4)) + (dg >> 2) * 2048;
            *(uint4*)((char*)kbK + off) = sv[i];
        }
#pragma unroll
        for (int i = 0; i < 8; ++i) {           // dg < 64: V dims only
            int dg = part + i * 8;
            const ushortT* pv = (const ushortT*)&sv[i];
#pragma unroll
            for (int j = 0; j < 8; ++j) {       // dim = dg*8+j, dim&7 == j
                int off = ((dg * 8 + j) * 64 + skey * 2) ^ (j << 4);
                *(ushortT*)((char*)kbV + off) = pv[j];
            }
        }
        // prefetch chunk p+1
        if (p + 1 < nchunk) {
            int gk = (p + 1) * 32 + skey;
            bool ok = gk < S;
            const ushortT* g = kcat + (size_t)idx_s[gk] * 576 + part * 8;
#pragma unroll
            for (int i = 0; i < 9; ++i) {
                uint4 v = {0, 0, 0, 0};
                if (ok) v = *(const uint4*)(g + i * 64);
                sv[i] = v;
            }
        }
        __syncthreads();
        // ---- score: C[16h][16k] for quadrant (mt, nt) ----
        f32x4 acc = (f32x4){0.f, 0.f, 0.f, 0.f};
        int brow = nt * 16 + lr;
#pragma unroll
        for (int kk = 0; kk < 18; ++kk) {
            bf16x8 b = *(const bf16x8*)((const char*)kbK + kk * 2048 +
                        ((brow * 64 + lk * 16) ^ ((brow & 7) << 4)));
            acc = __builtin_amdgcn_mfma_f32_16x16x32_bf16(qf[kk], b, acc, 0, 0, 0);
        }
        // ---- exp (m=0), accumulate sums, write P chunk ----
        int key_g = p * 32 + nt * 16 + lr;
        int hb = mt * 16 + lk * 4;
#pragma unroll
        for (int r = 0; r < 4; ++r) {
            float e = (key_g < S) ? expf(acc[r]) : 0.f;
            sm_[r] += e;
            int head = hb + r;
            int off = (head * 64 + (nt * 16 + lr) * 2) ^ ((head & 7) << 4);
            *(ushortT*)((char*)psc + off) = f2bf(e);
        }
        __syncthreads();
        // ---- PV: all 32 heads x this wave's 128 dims, K = 32 chunk keys ----
#pragma unroll
        for (int m2 = 0; m2 < 2; ++m2) {
            int arow = m2 * 16 + lr;
            bf16x8 a = *(const bf16x8*)((const char*)psc +
                        ((arow * 64 + lk * 16) ^ ((arow & 7) << 4)));
#pragma unroll
            for (int n2 = 0; n2 < 8; ++n2) {
                int dim = w * 128 + n2 * 16 + lr;
                bf16x8 b = *(const bf16x8*)((const char*)kbV +
                            ((dim * 64 + lk * 16) ^ ((dim & 7) << 4)));
                oa[m2][n2] = __builtin_amdgcn_mfma_f32_16x16x32_bf16(a, b, oa[m2][n2], 0, 0, 0);
            }
        }
        __syncthreads();
    }
    // ---- reduce per-head sums: over lr lanes, then across nt waves via LDS ----
#pragma unroll
    for (int off = 1; off < 16; off <<= 1)
#pragma unroll
        for (int r = 0; r < 4; ++r) sm_[r] += __shfl_xor(sm_[r], off);
    if (lr == 0) {
#pragma unroll
        for (int r = 0; r < 4; ++r) red[(mt * 16 + lk * 4 + r) * 2 + nt] = sm_[r];
    }
    __syncthreads();
    // ---- normalize + in-place write over this block's own qcat row ----
#pragma unroll
    for (int m2 = 0; m2 < 2; ++m2)
#pragma unroll
        for (int r = 0; r < 4; ++r) {
            int head = m2 * 16 + lk * 4 + r;
            float dvv = 1.f / (red[head * 2] + red[head * 2 + 1]);
#pragma unroll
            for (int n2 = 0; n2 < 8; ++n2) {
                int dim = w * 128 + n2 * 16 + lr;
                olat[(size_t)t * 18432 + head * 512 + dim] = f2bf(oa[m2][n2][r] * dvv);
            }
        }
}

// ---------------- launch ----------------
extern "C" void kernel_launch(void* const* d_in, const int* in_sizes, int n_in,
                              void* d_out, int out_size, void* d_ws, size_t ws_size,
                              hipStream_t stream) {
    (void)in_sizes; (void)n_in; (void)out_size; (void)ws_size;
    const int*   positions = (const int*)d_in[0];
    const float* hs        = (const float*)d_in[1];
    const float* q_c       = (const float*)d_in[2];
    const float* kv_lora   = (const float*)d_in[3];
    const float* W_qb      = (const float*)d_in[4];
    const float* W_kvb     = (const float*)d_in[5];
    const float* W_o       = (const float*)d_in[6];
    const float* kv_ln     = (const float*)d_in[7];
    const float* W_iq      = (const float*)d_in[8];
    const float* W_ik      = (const float*)d_in[9];
    const float* gamma     = (const float*)d_in[10];
    const float* beta      = (const float*)d_in[11];
    const float* W_iw      = (const float*)d_in[12];

    float* ws = (float*)d_ws;
    // workspace (float offsets); high-water 50,204,672 fl = 200.8 MB (< 218.4 proven)
    float*   cosT   = ws;                          // 65,536
    float*   sinT   = ws + 65536;                  // 65,536
    int*     tki    = (int*)(ws + 131072);         // 1,048,576
    int*     tkc    = (int*)(ws + 1179648);        // 2,048
    ushortT* kcat   = (ushortT*)(ws + 1181696);    // 589,824 fl
    float*   kscale = ws + 1771520;                // 2,048
    float*   qscale = ws + 1773568;                // 65,536
    float*   wts    = ws + 1839104;                // 65,536
    uchar*   qi8    = (uchar*)(ws + 1904640);      // 2,097,152 fl (8 MB bytes)
    uchar*   ki8    = (uchar*)(ws + 4001792);      // 65,536 fl
    // REGION R1 4067328..20844544, time-multiplexed:
    float*   kip    = ws + 4067328;                // 16 x 262,144 [step2 -> dead after 3]
    float*   qip0   = ws + 4067328;                // 8,388,608   [step4 -> dead after 5]
    float*   qip1   = ws + 12455936;               // 8,388,608   [step4 -> dead after 5]
    ushortT* wqb_t  = (ushortT*)(ws + 4067328);    // 4,718,592 fl [10 -> dead after 11]
    ushortT* qc_bf  = (ushortT*)(ws + 8785920);    // 1,572,864 fl [10 -> dead after 11]
    ushortT* wuk_t  = (ushortT*)(ws + 10358784);   // 1,048,576 fl [10 -> dead after 13]
    ushortT* wuv_t  = (ushortT*)(ws + 11407360);   // 1,048,576 fl [10 -> read at 15]
    ushortT* wo_t   = (ushortT*)(ws + 4067328);    // 4,194,304 fl [13b over dead wqb_t]
    // score / vbuf slot:
    float*   score  = ws + 20844544;               // 4,194,304 [7 -> dead after 8]
    ushortT* vbuf   = (ushortT*)(ws + 20844544);   // 4,194,304 fl [15 -> 16]
    // persistent tail:
    ushortT* qfull_bf = (ushortT*)(ws + 25038848); // 6,291,456 fl [11 -> 12,13]
    ushortT* qcat   = (ushortT*)(ws + 31330304);   // 18,874,368 fl; o written in place (14)

    // 1. rope tables
    k_rope_tables<<<T_N, 32, 0, stream>>>(positions, cosT, sinT);
    // 2. indexer k: hs @ W_ik (2048x128x2048), split-K x16 -> partials
    gemm128<false><<<dim3(1, 16, 16), 256, 0, stream>>>(
        hs, W_ik, kip, T_N, 128, 128, HID_N, 128, 128, 128, 16384, 262144);
    // 3. sum partials + LN + neox rope + fp8 quant -> ki8 bytes
    k_ki_post16<<<T_N, 128, 0, stream>>>(kip, gamma, beta, cosT, sinT, ki8, kscale);
    // 4. indexer q: q_c @ W_iq (2048x4096x1536), split-K x2 -> partials
    gemm128<false><<<dim3(32, 16, 2), 256, 0, stream>>>(
        q_c, W_iq, qip0, T_N, 4096, 768, QLORA_N, 4096, 4096, 768, 3145728, 8388608);
    // 5. sum partials + neox rope + fp8 quant -> qi8 bytes
    k_qi_post2<<<T_N * IDX_H_N, 128, 0, stream>>>(qip0, qip1, cosT, sinT, qi8, qscale);
    // 6. indexer weights
    k_wiw<<<T_N, 256, 0, stream>>>(hs, W_iw, qscale, wts);
    // 7. indexer score via fp8 MFMA
    k_score8<<<2080, 256, 0, stream>>>(qi8, ki8, kscale, wts, score);
    // 8. top-512
    k_topk<<<T_N, 256, 0, stream>>>(score, tki, tkc);
    // 9. kv rms_norm + k_pe rope -> kcat bf16
    k_kv_post2<<<T_N, 256, 0, stream>>>(kv_lora, kv_ln, cosT, sinT, kcat);
    // 10. casts / transposes (R1 free again)
    k_cast4<<<3072, 256, 0, stream>>>(q_c, qc_bf, T_N * QLORA_N / 4);
    k_tcast<<<dim3(48, 192, 1), 256, 0, stream>>>(W_qb, wqb_t, 6144, 0, 0, 1536, 0);
    k_wuk_cast<<<8192, 256, 0, stream>>>(W_kvb, wuk_t);
    k_tcast<<<dim3(16, 4, 32), 256, 0, stream>>>(W_kvb, wuv_t, 8192, 128, 256, 512, 65536);
    // 11. qfull = q_c @ W_qb (bf16 MFMA) -> bf16 (T,32,192)
    bgemm<true><<<dim3(48, 16, 1), 256, 0, stream>>>(
        qc_bf, wqb_t, qfull_bf, QLORA_N, QLORA_N, QLORA_N, 6144, 0, 0, 0, 1.f);
    // 12. rope q_pe -> qcat[...,512:576]
    k_rope_q2<<<T_N * H_N / 8, 256, 0, stream>>>(qfull_bf, cosT, sinT, qcat);
    // 13. q_lat = q_nope @ W_UK^T per head -> qcat[...,0:512] (SCALE folded)
    bgemm<true><<<dim3(4, 16, 32), 256, 0, stream>>>(
        qfull_bf, wuk_t, qcat, NOPE_N, 6144, 128, 18432, 192, 65536, 576, SCALE_F);
    // 13b. wo_t transpose (over dead wqb_t)
    k_tcast<<<dim3(128, 64, 1), 256, 0, stream>>>(W_o, wo_t, 2048, 0, 0, 4096, 0);
    // 14. fused sparse MFMA attention (single-pass) -> o written in place into qcat rows
    k_attn_mfma<<<T_N, 256, 0, stream>>>(qcat, kcat, tki, tkc, qcat);
    // 15. v = o @ W_UV per head -> vbuf bf16 (T,4096)
    bgemm<true><<<dim3(1, 16, 32), 256, 0, stream>>>(
        qcat, wuv_t, vbuf, KVLORA_N, 18432, 512, 4096, 512, 65536, 128, 1.f);
    // 16. out = vbuf @ W_o -> f32
    bgemm<false><<<dim3(16, 16, 1), 256, 0, stream>>>(
        vbuf, wo_t, (float*)d_out, H_N * VD_N, 4096, 4096, HID_N, 0, 0, 0, 1.f);
}

// Round 11
// 1043.356 us; speedup vs baseline: 6.1522x; 1.0002x over previous
//
#include <hip/hip_runtime.h>
#include <hip/hip_bf16.h>

// ---------------- constants ----------------
#define T_N    2048
#define H_N    32
#define NOPE_N 128
#define ROPE_N 64
#define VD_N   128
#define QLORA_N 1536
#define KVLORA_N 512
#define IDX_H_N 32
#define IDX_D_N 128
#define TOPK_N 512
#define HID_N  2048

typedef __attribute__((ext_vector_type(8))) short bf16x8;
typedef __attribute__((ext_vector_type(4))) float f32x4;
typedef unsigned short ushortT;
typedef unsigned char uchar;

#define SCALE_F 0.07216878364870323f  // (NOPE+ROPE)^-0.5 = 192^-0.5

static __device__ __forceinline__ ushortT f2bf(float x) {
    __hip_bfloat16 b = __float2bfloat16(x);
    return *(ushortT*)&b;
}
static __device__ __forceinline__ float bf2f(ushortT u) {
    __hip_bfloat16 b = *(__hip_bfloat16*)&u;
    return __bfloat162float(b);
}

// exact RNE float -> e4m3fn grid
static __device__ __forceinline__ float q_e4m3(float x) {
    float ax = fabsf(x);
    unsigned b = __float_as_uint(ax);
    int e = (int)(b >> 23) - 126;
    int ue = (e - 4 > -9) ? (e - 4) : -9;
    float ulp = __int_as_float((ue + 127) << 23);
    float q = rintf(ax / ulp) * ulp;
    return copysignf(q, x);
}

// encode a value ALREADY on the e4m3fn grid (|q|<=448) to its fp8 byte
static __device__ __forceinline__ uchar enc_e4m3(float q) {
    unsigned b = __float_as_uint(q);
    unsigned s = (b >> 31) << 7;
    float ax = fabsf(q);
    if (ax == 0.f) return (uchar)s;
    int e = (int)((b >> 23) & 255) - 127;   // q = 1.m * 2^e
    if (e >= -6) {
        unsigned m = (b >> 20) & 7;         // exact: grid value has 3 mantissa bits
        return (uchar)(s | ((unsigned)(e + 7) << 3) | m);
    }
    unsigned M = (unsigned)rintf(ax * 512.f);  // subnormal: M * 2^-9, M in 1..7
    return (uchar)(s | M);
}

// ---------------- rope tables ----------------
__global__ void k_rope_tables(const int* __restrict__ pos, float* __restrict__ cosT,
                              float* __restrict__ sinT) {
    int t = blockIdx.x, i = threadIdx.x;
    double inv = 1.0 / pow(10000.0, (double)i / 32.0);
    double ang = (double)pos[t] * inv;
    cosT[t * 32 + i] = (float)cos(ang);
    sinT[t * 32 + i] = (float)sin(ang);
}

// ---------------- generic 128x128 f32 GEMM (BK=8), batched/split-K via blockIdx.z -------
template <bool BT>
__global__ __launch_bounds__(256) void gemm128(
    const float* __restrict__ A, const float* __restrict__ B, float* __restrict__ C,
    int M, int N, int K, int lda, int ldb, int ldc,
    long batchOffA, long batchOffB, long batchOffC) {
    const float* Ab = A + (size_t)batchOffA * blockIdx.z;
    const float* Bb = B + (size_t)batchOffB * blockIdx.z;
    int bm = blockIdx.y * 128, bn = blockIdx.x * 128;
    int tid = threadIdx.x;
    __shared__ float As[8][128];
    __shared__ float Bs[8][128];
    float acc[8][8];
#pragma unroll
    for (int i = 0; i < 8; ++i)
#pragma unroll
        for (int j = 0; j < 8; ++j) acc[i][j] = 0.f;
    int tx = tid & 15, ty = tid >> 4;
    int ar = tid >> 1, ak = (tid & 1) * 4;
    for (int k0 = 0; k0 < K; k0 += 8) {
        float4 av = *(const float4*)(Ab + (size_t)(bm + ar) * lda + k0 + ak);
        As[ak + 0][ar] = av.x; As[ak + 1][ar] = av.y;
        As[ak + 2][ar] = av.z; As[ak + 3][ar] = av.w;
        if (BT) {
            int n = tid >> 1, kk = (tid & 1) * 4;
            float4 bv = *(const float4*)(Bb + (size_t)(bn + n) * ldb + k0 + kk);
            Bs[kk + 0][n] = bv.x; Bs[kk + 1][n] = bv.y;
            Bs[kk + 2][n] = bv.z; Bs[kk + 3][n] = bv.w;
        } else {
            int kk = tid >> 5, n = (tid & 31) * 4;
            float4 bv = *(const float4*)(Bb + (size_t)(k0 + kk) * ldb + bn + n);
            Bs[kk][n + 0] = bv.x; Bs[kk][n + 1] = bv.y;
            Bs[kk][n + 2] = bv.z; Bs[kk][n + 3] = bv.w;
        }
        __syncthreads();
#pragma unroll
        for (int kk = 0; kk < 8; ++kk) {
            float4 a0 = *(const float4*)(&As[kk][ty * 8]);
            float4 a1 = *(const float4*)(&As[kk][ty * 8 + 4]);
            float4 b0 = *(const float4*)(&Bs[kk][tx * 8]);
            float4 b1 = *(const float4*)(&Bs[kk][tx * 8 + 4]);
            float a[8] = {a0.x, a0.y, a0.z, a0.w, a1.x, a1.y, a1.z, a1.w};
            float b[8] = {b0.x, b0.y, b0.z, b0.w, b1.x, b1.y, b1.z, b1.w};
#pragma unroll
            for (int i = 0; i < 8; ++i)
#pragma unroll
                for (int j = 0; j < 8; ++j) acc[i][j] = fmaf(a[i], b[j], acc[i][j]);
        }
        __syncthreads();
    }
    size_t cbase = (size_t)batchOffC * blockIdx.z;
#pragma unroll
    for (int i = 0; i < 8; ++i) {
        size_t r = bm + ty * 8 + i;
#pragma unroll
        for (int j = 0; j < 8; ++j) {
            size_t c = bn + tx * 8 + j;
            C[cbase + r * (size_t)ldc + c] = acc[i][j];
        }
    }
}

// ======== bf16 NT MFMA GEMM: A(M,K) bf16, B(N,K) bf16, 128x128 tile, BK=64 =============
// CB16 epilogue: LDS bounce -> full-64B-line coalesced uint4 stores (kills RMW traffic).
template <bool CB16>
__global__ __launch_bounds__(256) void bgemm(
    const ushortT* __restrict__ A, const ushortT* __restrict__ B, void* __restrict__ Cv,
    int K, int lda, int ldb, int ldc,
    long boffA, long boffB, long boffC, float scaleC) {
    const ushortT* Ab = A + (size_t)boffA * blockIdx.z;
    const ushortT* Bb = B + (size_t)boffB * blockIdx.z;
    int bm = blockIdx.y * 128, bn = blockIdx.x * 128;
    int tid = threadIdx.x, lane = tid & 63, w = tid >> 6;
    int wr = w >> 1, wc = w & 1;
    int lr = lane & 15, lk = lane >> 4;

    __shared__ __align__(16) ushortT sbuf[16384];   // 32KB: As=sbuf, Bs=sbuf+8192
    ushortT* As = sbuf;
    ushortT* Bs = sbuf + 8192;

    f32x4 acc[4][4];
#pragma unroll
    for (int i = 0; i < 4; ++i)
#pragma unroll
        for (int j = 0; j < 4; ++j) acc[i][j] = (f32x4){0.f, 0.f, 0.f, 0.f};

    for (int kt = 0; kt < K; kt += 64) {
        __syncthreads();
#pragma unroll
        for (int q = 0; q < 4; ++q) {
            int ch = tid + q * 256;
            int row = ch >> 3, e8 = ch & 7;
            int byteoff = (row * 128 + e8 * 16) ^ ((row & 7) << 4);
            uint4 va = *(const uint4*)(Ab + (size_t)(bm + row) * lda + kt + e8 * 8);
            *(uint4*)((char*)As + byteoff) = va;
            uint4 vb = *(const uint4*)(Bb + (size_t)(bn + row) * ldb + kt + e8 * 8);
            *(uint4*)((char*)Bs + byteoff) = vb;
        }
        __syncthreads();
#pragma unroll
        for (int kk = 0; kk < 2; ++kk) {
            bf16x8 af[4], bfr[4];
#pragma unroll
            for (int i = 0; i < 4; ++i) {
                int arow = wr * 64 + i * 16 + lr;
                af[i] = *(const bf16x8*)((const char*)As +
                         ((arow * 128 + kk * 64 + lk * 16) ^ ((arow & 7) << 4)));
                int brow = wc * 64 + i * 16 + lr;
                bfr[i] = *(const bf16x8*)((const char*)Bs +
                         ((brow * 128 + kk * 64 + lk * 16) ^ ((brow & 7) << 4)));
            }
#pragma unroll
            for (int i = 0; i < 4; ++i)
#pragma unroll
                for (int j = 0; j < 4; ++j)
                    acc[i][j] = __builtin_amdgcn_mfma_f32_16x16x32_bf16(af[i], bfr[j], acc[i][j], 0, 0, 0);
        }
    }
    size_t cbase = (size_t)boffC * blockIdx.z;
    if (CB16) {
        __syncthreads();   // all waves done reading As/Bs
        // stage bf16 tile [128 rows][128 cols] swizzled
#pragma unroll
        for (int mi = 0; mi < 4; ++mi)
#pragma unroll
            for (int ni = 0; ni < 4; ++ni)
#pragma unroll
                for (int r = 0; r < 4; ++r) {
                    int row = wr * 64 + mi * 16 + lk * 4 + r;
                    int col = wc * 64 + ni * 16 + lr;
                    int off = (row * 256 + col * 2) ^ ((row & 7) << 4);
                    *(ushortT*)((char*)sbuf + off) = f2bf(acc[mi][ni][r] * scaleC);
                }
        __syncthreads();
        // coalesced stores: 4 consecutive lanes cover 64B of one row -> full lines
        ushortT* outp = (ushortT*)Cv;
#pragma unroll
        for (int i = 0; i < 8; ++i) {
            int idx = i * 256 + tid;
            int row = idx >> 4, seg = idx & 15;
            uint4 v = *(const uint4*)((const char*)sbuf +
                       ((row * 256 + seg * 16) ^ ((row & 7) << 4)));
            *(uint4*)(outp + cbase + (size_t)(bm + row) * ldc + bn + seg * 8) = v;
        }
    } else {
#pragma unroll
        for (int mi = 0; mi < 4; ++mi)
#pragma unroll
            for (int ni = 0; ni < 4; ++ni) {
                int col = bn + wc * 64 + ni * 16 + lr;
#pragma unroll
                for (int r = 0; r < 4; ++r) {
                    int row = bm + wr * 64 + mi * 16 + lk * 4 + r;
                    ((float*)Cv)[cbase + (size_t)row * ldc + col] = acc[mi][ni][r];
                }
            }
    }
}

// ---------------- cast / transpose helpers ----------------
__global__ __launch_bounds__(256) void k_cast4(const float* __restrict__ src,
                                               ushortT* __restrict__ dst, int n4) {
    int i = blockIdx.x * 256 + threadIdx.x;
    if (i < n4) {
        float4 v = ((const float4*)src)[i];
        ushortT o[4] = {f2bf(v.x), f2bf(v.y), f2bf(v.z), f2bf(v.w)};
        *(uint2*)(dst + (size_t)i * 4) = *(uint2*)o;
    }
}

// dst[z][b][a] bf16 = src[a*sa + b + soff + z*sz]  (sb==1), tiles 32x32
__global__ __launch_bounds__(256) void k_tcast(const float* __restrict__ src,
                                               ushortT* __restrict__ dst,
                                               long sa, long soff, long sz,
                                               long da, long dz) {
    __shared__ float tile[32][33];
    int a0 = blockIdx.x * 32, b0 = blockIdx.y * 32;
    int tx = threadIdx.x & 31, ty = threadIdx.x >> 5;
    const float* s = src + (size_t)sz * blockIdx.z + soff;
#pragma unroll
    for (int i = ty; i < 32; i += 8)
        tile[i][tx] = s[(size_t)(a0 + i) * sa + (b0 + tx)];
    __syncthreads();
    ushortT* d = dst + (size_t)dz * blockIdx.z;
#pragma unroll
    for (int i = ty; i < 32; i += 8)
        d[(size_t)(b0 + i) * da + a0 + tx] = f2bf(tile[tx][i]);
}

// wuk_t[h][r][n] = W_kvb[r][h][n]
__global__ __launch_bounds__(256) void k_wuk_cast(const float* __restrict__ wkvb,
                                                  ushortT* __restrict__ wuk) {
    int i = blockIdx.x * 256 + threadIdx.x;
    int n = i & 127, r = (i >> 7) & 511, h = i >> 16;
    wuk[i] = f2bf(wkvb[(size_t)r * 8192 + h * 256 + n]);
}

// ------- kv postprocess -> kcat bf16 (T,576) ----
__global__ __launch_bounds__(256) void k_kv_post2(const float* __restrict__ kv,
                                                  const float* __restrict__ lnw,
                                                  const float* __restrict__ cosT,
                                                  const float* __restrict__ sinT,
                                                  ushortT* __restrict__ kcat) {
    int t = blockIdx.x, tid = threadIdx.x;
    const float* row = kv + (size_t)t * 576;
    float v0 = row[tid], v1 = row[tid + 256];
    float s = v0 * v0 + v1 * v1;
    for (int o = 32; o > 0; o >>= 1) s += __shfl_down(s, o);
    __shared__ float sm[4];
    if ((tid & 63) == 0) sm[tid >> 6] = s;
    __syncthreads();
    float tot = sm[0] + sm[1] + sm[2] + sm[3];
    float inv = 1.f / sqrtf(tot / 512.f + 1e-6f);
    ushortT* out = kcat + (size_t)t * 576;
    out[tid] = f2bf(v0 * inv * lnw[tid]);
    out[tid + 256] = f2bf(v1 * inv * lnw[tid + 256]);
    if (tid < 32) {
        float c = cosT[t * 32 + tid], sn = sinT[t * 32 + tid];
        float x1 = row[512 + 2 * tid], x2 = row[512 + 2 * tid + 1];
        out[512 + 2 * tid] = f2bf(x1 * c - x2 * sn);
        out[512 + 2 * tid + 1] = f2bf(x2 * c + x1 * sn);
    }
}

// ------- rope on q_pe (bf16 qfull) -> qcat[...,512:576] (SCALE folded) ------------------
__global__ __launch_bounds__(256) void k_rope_q2(const ushortT* __restrict__ qfull,
                                                 const float* __restrict__ cosT,
                                                 const float* __restrict__ sinT,
                                                 ushortT* __restrict__ qcat) {
    int b = blockIdx.x * 8 + (threadIdx.x >> 5);
    int i = threadIdx.x & 31;
    int t = b >> 5, h = b & 31;
    const ushortT* p = qfull + (size_t)b * 192 + 128;
    float c = cosT[t * 32 + i], s = sinT[t * 32 + i];
    float x1 = bf2f(p[2 * i]), x2 = bf2f(p[2 * i + 1]);
    ushortT* q = qcat + (size_t)t * 18432 + h * 576 + 512;
    q[2 * i] = f2bf((x1 * c - x2 * s) * SCALE_F);
    q[2 * i + 1] = f2bf((x2 * c + x1 * s) * SCALE_F);
}

// ---- indexer k: sum 16 split-K partials + layernorm + neox rope + fp8 quant -> bytes ----
__global__ __launch_bounds__(128) void k_ki_post16(const float* __restrict__ kp,
                                                   const float* __restrict__ g,
                                                   const float* __restrict__ be,
                                                   const float* __restrict__ cosT,
                                                   const float* __restrict__ sinT,
                                                   uchar* __restrict__ ki8,
                                                   float* __restrict__ kscale) {
    int t = blockIdx.x, i = threadIdx.x;
    float x = 0.f;
#pragma unroll
    for (int z = 0; z < 16; ++z) x += kp[(size_t)z * 262144 + (size_t)t * 128 + i];
    float s = x;
    for (int o = 32; o > 0; o >>= 1) s += __shfl_down(s, o);
    __shared__ float sm[2];
    if ((i & 63) == 0) sm[i >> 6] = s;
    __syncthreads();
    float mean = (sm[0] + sm[1]) / 128.f;
    float d = x - mean;
    float s2 = d * d;
    for (int o = 32; o > 0; o >>= 1) s2 += __shfl_down(s2, o);
    __shared__ float sv[2];
    if ((i & 63) == 0) sv[i >> 6] = s2;
    __syncthreads();
    float var = (sv[0] + sv[1]) / 128.f;
    float nrm = d * (1.f / sqrtf(var + 1e-6f)) * g[i] + be[i];
    __shared__ float buf[128];
    buf[i] = nrm;
    __syncthreads();
    float out;
    if (i < 32)      out = buf[i] * cosT[t * 32 + i] - buf[i + 32] * sinT[t * 32 + i];
    else if (i < 64) out = buf[i] * cosT[t * 32 + i - 32] + buf[i - 32] * sinT[t * 32 + i - 32];
    else             out = nrm;
    float a = fabsf(out);
    for (int o = 32; o > 0; o >>= 1) a = fmaxf(a, __shfl_down(a, o));
    __shared__ float am[2];
    if ((i & 63) == 0) am[i >> 6] = a;
    __syncthreads();
    float amax = fmaxf(fmaxf(am[0], am[1]), 1e-10f);
    float scale = __int_as_float((((int)ceilf(log2f(amax / 448.f))) + 127) << 23);
    ki8[(size_t)t * 128 + i] = enc_e4m3(q_e4m3(out / scale));
    if (i == 0) kscale[t] = scale;
}

// ---- indexer q: sum 2 split-K partials + neox rope + fp8 quant -> bytes -----------------
__global__ __launch_bounds__(128) void k_qi_post2(const float* __restrict__ p0,
                                                  const float* __restrict__ p1,
                                                  const float* __restrict__ cosT,
                                                  const float* __restrict__ sinT,
                                                  uchar* __restrict__ qi8,
                                                  float* __restrict__ qscale) {
    int b = blockIdx.x;
    int t = b >> 5;
    int i = threadIdx.x;
    float x = p0[(size_t)b * 128 + i] + p1[(size_t)b * 128 + i];
    __shared__ float buf[128];
    buf[i] = x;
    __syncthreads();
    float out;
    if (i < 32)      out = buf[i] * cosT[t * 32 + i] - buf[i + 32] * sinT[t * 32 + i];
    else if (i < 64) out = buf[i] * cosT[t * 32 + i - 32] + buf[i - 32] * sinT[t * 32 + i - 32];
    else             out = x;
    float a = fabsf(out);
    for (int o = 32; o > 0; o >>= 1) a = fmaxf(a, __shfl_down(a, o));
    __shared__ float am[2];
    if ((i & 63) == 0) am[i >> 6] = a;
    __syncthreads();
    float amax = fmaxf(fmaxf(am[0], am[1]), 1e-10f);
    float scale = __int_as_float((((int)ceilf(log2f(amax / 448.f))) + 127) << 23);
    qi8[(size_t)b * 128 + i] = enc_e4m3(q_e4m3(out / scale));
    if (i == 0) qscale[b] = scale;
}

// ---------------- indexer weights ----------------
__global__ __launch_bounds__(256) void k_wiw(const float* __restrict__ hs,
                                             const float* __restrict__ W_iw,
                                             const float* __restrict__ qscale,
                                             float* __restrict__ wts) {
    int t = blockIdx.x, tid = threadIdx.x;
    __shared__ float hr[2048];
    for (int i = tid; i < 2048; i += 256) hr[i] = hs[(size_t)t * 2048 + i];
    __syncthreads();
    int h = tid & 31, p = tid >> 5;
    float s = 0;
    for (int k = p * 256; k < p * 256 + 256; ++k) s = fmaf(hr[k], W_iw[(size_t)k * 32 + h], s);
    __shared__ float part[8][32];
    part[p][h] = s;
    __syncthreads();
    if (tid < 32) {
        float tot = 0;
#pragma unroll
        for (int pp = 0; pp < 8; ++pp) tot += part[pp][tid];
        const float a = (float)0.08838834764831845;   // 128^-0.5
        const float b = (float)0.1767766952966369;    // 32^-0.5
        wts[t * 32 + tid] = tot * qscale[t * 32 + tid] * a * b;
    }
}

// ======== indexer score via fp8 MFMA ====
__global__ __launch_bounds__(256) void k_score8(const uchar* __restrict__ qi8,
                                                const uchar* __restrict__ ki8,
                                                const float* __restrict__ kscale,
                                                const float* __restrict__ wts,
                                                float* __restrict__ score) {
    int b = blockIdx.x;
    int ti = (int)((sqrtf(8.f * b + 1.f) - 1.f) * 0.5f);
    while ((ti + 1) * (ti + 2) / 2 <= b) ++ti;
    while (ti * (ti + 1) / 2 > b) --ti;
    int si = b - ti * (ti + 1) / 2;
    int t0 = ti * 32, s0 = si * 32;
    int tid = threadIdx.x, lane = tid & 63, w = tid >> 6;
    int qt = w >> 1, qs = w & 1;
    int col = lane & 15, g = lane >> 4;

    __shared__ __align__(16) uchar k8s[4096];
    __shared__ __align__(16) uchar q8s[32768];
    __shared__ float wts_s[32][33];

    {
        int row = tid >> 3, inner = tid & 7;
        uint4 v = *(const uint4*)(ki8 + (size_t)(s0 + row) * 128 + inner * 16);
        *(uint4*)(k8s + ((row * 128 + inner * 16) ^ ((row & 7) << 4))) = v;
    }
    for (int c = tid; c < 1024; c += 256) {
        int tl = c >> 5, h = c & 31;
        wts_s[tl][h] = wts[(size_t)(t0 + tl) * 32 + h];
    }

    float ksc = kscale[s0 + qs * 16 + col];
    int arow = qt * 16 + col;
    int brow = qs * 16 + col;
    float sacc[4] = {0.f, 0.f, 0.f, 0.f};

    for (int h0 = 0; h0 < 32; h0 += 8) {
        __syncthreads();
        for (int c = tid; c < 2048; c += 256) {
            int hh = c >> 8, row = (c >> 3) & 31, inner = c & 7;
            uint4 v = *(const uint4*)(qi8 + ((size_t)(t0 + row) * 32 + h0 + hh) * 128 + inner * 16);
            *(uint4*)(q8s + hh * 4096 + ((row * 128 + inner * 16) ^ ((row & 7) << 4))) = v;
        }
        __syncthreads();
#pragma unroll
        for (int hh = 0; hh < 8; ++hh) {
            f32x4 c4 = (f32x4){0.f, 0.f, 0.f, 0.f};
#pragma unroll
            for (int kk = 0; kk < 4; ++kk) {
                long long a = *(const long long*)(q8s + hh * 4096 +
                              ((arow * 128 + kk * 32 + g * 8) ^ ((arow & 7) << 4)));
                long long bb = *(const long long*)(k8s +
                              ((brow * 128 + kk * 32 + g * 8) ^ ((brow & 7) << 4)));
                c4 = __builtin_amdgcn_mfma_f32_16x16x32_fp8_fp8(a, bb, c4, 0, 0, 0);
            }
            int h = h0 + hh;
#pragma unroll
            for (int r = 0; r < 4; ++r)
                sacc[r] = fmaf(fmaxf(c4[r] * ksc, 0.f), wts_s[qt * 16 + g * 4 + r][h], sacc[r]);
        }
    }
    int t = t0 + qt * 16 + g * 4;
    int s = s0 + qs * 16 + col;
#pragma unroll
    for (int r = 0; r < 4; ++r)
        if (s <= t + r) score[(size_t)(t + r) * T_N + s] = sacc[r];
}

// ---------------- top-512 per row (stable ties) --------------------------
__global__ __launch_bounds__(256) void k_topk(const float* __restrict__ score,
                                              int* __restrict__ tki, int* __restrict__ tkc) {
    int t = blockIdx.x;
    int n = t + 1;
    int tid = threadIdx.x;
    if (n <= TOPK_N) {
        for (int i = tid; i < n; i += 256) tki[(size_t)t * TOPK_N + i] = i;
        if (tid == 0) tkc[t] = n;
        return;
    }
    __shared__ unsigned keys[2048];
    const float* row = score + (size_t)t * T_N;
    for (int i = tid; i < n; i += 256) {
        float f = row[i] + 0.f;
        unsigned u = __float_as_uint(f);
        u = (u & 0x80000000u) ? ~u : (u | 0x80000000u);
        keys[i] = u;
    }
    __shared__ int hist[256];
    __shared__ unsigned sh_prefix;
    __shared__ int sh_need;
    if (tid == 0) { sh_prefix = 0u; sh_need = TOPK_N; }
    __syncthreads();
    unsigned maskHi = 0;
    for (int level = 3; level >= 0; --level) {
        hist[tid] = 0;
        __syncthreads();
        unsigned prefix = sh_prefix;
        int shift = level * 8;
        for (int i = tid; i < n; i += 256) {
            unsigned kk = keys[i];
            if ((kk & maskHi) == prefix) atomicAdd(&hist[(kk >> shift) & 255], 1);
        }
        __syncthreads();
        if (tid == 0) {
            int need = sh_need, cum = 0, bsel = 255;
            for (int bb = 255; bb >= 0; --bb) {
                if (cum + hist[bb] >= need) { bsel = bb; break; }
                cum += hist[bb];
            }
            sh_need = need - cum;
            sh_prefix = prefix | ((unsigned)bsel << shift);
        }
        __syncthreads();
        maskHi |= (0xFFu << shift);
    }
    unsigned thr = sh_prefix;
    int needEq = sh_need;
    int base = tid * 8;
    int eqcnt = 0;
#pragma unroll
    for (int j = 0; j < 8; ++j) {
        int i = base + j;
        if (i < n && keys[i] == thr) eqcnt++;
    }
    __shared__ int scn[256];
    scn[tid] = eqcnt;
    __syncthreads();
    for (int off = 1; off < 256; off <<= 1) {
        int add = (tid >= off) ? scn[tid - off] : 0;
        __syncthreads();
        scn[tid] += add;
        __syncthreads();
    }
    int eq_excl = scn[tid] - eqcnt;
    int acnt = 0;
    {
        int eqr = eq_excl;
#pragma unroll
        for (int j = 0; j < 8; ++j) {
            int i = base + j;
            if (i < n) {
                unsigned kk = keys[i];
                bool a = (kk > thr) || (kk == thr && eqr < needEq);
                if (kk == thr) eqr++;
                if (a) acnt++;
            }
        }
    }
    __syncthreads();
    scn[tid] = acnt;
    __syncthreads();
    for (int off = 1; off < 256; off <<= 1) {
        int add = (tid >= off) ? scn[tid - off] : 0;
        __syncthreads();
        scn[tid] += add;
        __syncthreads();
    }
    int pos = scn[tid] - acnt;
    {
        int eqr = eq_excl;
#pragma unroll
        for (int j = 0; j < 8; ++j) {
            int i = base + j;
            if (i < n) {
                unsigned kk = keys[i];
                bool a = (kk > thr) || (kk == thr && eqr < needEq);
                if (kk == thr) eqr++;
                if (a) tki[(size_t)t * TOPK_N + (pos++)] = i;
            }
        }
    }
    if (tid == 0) tkc[t] = TOPK_N;
}

// ======== fused sparse MFMA attention, single-pass flash-style (round 11) ===============
// Changes vs r10: prefetch issued AFTER the stage barrier (MFMA covers the drain);
// coalesced olat epilogue via kbK LDS bounce (full 64B lines, no RMW).
__global__ __launch_bounds__(256, 2) void k_attn_mfma(const ushortT* __restrict__ qcat,
                                                      const ushortT* __restrict__ kcat,
                                                      const int* __restrict__ tki,
                                                      const int* __restrict__ tkc,
                                                      ushortT* __restrict__ olat) {
    int t = blockIdx.x;
    int tid = threadIdx.x;
    int lane = tid & 63;
    int w = tid >> 6;                 // 4 waves
    int S = tkc[t];
    int nchunk = (S + 31) >> 5;

    __shared__ int idx_s[512];
    __shared__ __align__(16) ushortT kbK[18 * 1024];  // [kk][32 keys][32 dims] 36864B
    __shared__ __align__(16) ushortT kbV[512 * 32];   // [512 dims][32 keys]    32768B
    __shared__ __align__(16) ushortT psc[32 * 32];    // [32 heads][32 keys]     2048B
    __shared__ float red[64];                         // [head][nt] partial sums

    idx_s[tid] = (tid < S) ? tki[(size_t)t * TOPK_N + tid] : 0;
    idx_s[tid + 256] = (tid + 256 < S) ? tki[(size_t)t * TOPK_N + tid + 256] : 0;

    int lr = lane & 15, lk = lane >> 4;
    int mt = w >> 1, nt = w & 1;      // score quadrant: heads mt*16, keys nt*16

    // q fragments in registers: head = mt*16+lr, dims kk*32 + lk*8 .. +8
    bf16x8 qf[18];
    {
        const ushortT* qrow = qcat + (size_t)t * 18432 + (size_t)(mt * 16 + lr) * 576 + lk * 8;
#pragma unroll
        for (int kk = 0; kk < 18; ++kk) qf[kk] = *(const bf16x8*)(qrow + kk * 32);
    }
    __syncthreads();

    // staging: key = tid&31, part = tid>>5 (0..7), dg = part + i*8 (16B units of 1152B row)
    int skey = tid & 31, part = tid >> 5;

    f32x4 oa[2][8];
#pragma unroll
    for (int i = 0; i < 2; ++i)
#pragma unroll
        for (int j = 0; j < 8; ++j) oa[i][j] = (f32x4){0.f, 0.f, 0.f, 0.f};
    float sm_[4] = {0.f, 0.f, 0.f, 0.f};

    uint4 sv[9];
    {   // prefetch chunk 0
        bool ok = skey < S;
        const ushortT* g = kcat + (size_t)idx_s[skey] * 576 + part * 8;
#pragma unroll
        for (int i = 0; i < 9; ++i) {
            uint4 v = {0, 0, 0, 0};
            if (ok) v = *(const uint4*)(g + i * 64);
            sv[i] = v;
        }
    }

    for (int p = 0; p < nchunk; ++p) {
        // ---- stage chunk p: K-layout + V-transposed ----
#pragma unroll
        for (int i = 0; i < 9; ++i) {
            int dg = part + i * 8;
            int off = ((skey * 64 + (dg & 3) * 16) ^ ((skey & 7) << 4)) + (dg >> 2) * 2048;
            *(uint4*)((char*)kbK + off) = sv[i];
        }
#pragma unroll
        for (int i = 0; i < 8; ++i) {           // dg < 64: V dims only
            int dg = part + i * 8;
            const ushortT* pv = (const ushortT*)&sv[i];
#pragma unroll
            for (int j = 0; j < 8; ++j) {       // dim = dg*8+j, dim&7 == j
                int off = ((dg * 8 + j) * 64 + skey * 2) ^ (j << 4);
                *(ushortT*)((char*)kbV + off) = pv[j];
            }
        }
        __syncthreads();
        // issue prefetch AFTER the barrier: its latency hides under score MFMA + exp
        if (p + 1 < nchunk) {
            int gk = (p + 1) * 32 + skey;
            bool ok = gk < S;
            const ushortT* g = kcat + (size_t)idx_s[gk] * 576 + part * 8;
#pragma unroll
            for (int i = 0; i < 9; ++i) {
                uint4 v = {0, 0, 0, 0};
                if (ok) v = *(const uint4*)(g + i * 64);
                sv[i] = v;
            }
        }
        // ---- score: C[16h][16k] for quadrant (mt, nt) ----
        f32x4 acc = (f32x4){0.f, 0.f, 0.f, 0.f};
        int brow = nt * 16 + lr;
#pragma unroll
        for (int kk = 0; kk < 18; ++kk) {
            bf16x8 b = *(const bf16x8*)((const char*)kbK + kk * 2048 +
                        ((brow * 64 + lk * 16) ^ ((brow & 7) << 4)));
            acc = __builtin_amdgcn_mfma_f32_16x16x32_bf16(qf[kk], b, acc, 0, 0, 0);
        }
        // ---- exp (m=0), accumulate sums, write P chunk ----
        int key_g = p * 32 + nt * 16 + lr;
        int hb = mt * 16 + lk * 4;
#pragma unroll
        for (int r = 0; r < 4; ++r) {
            float e = (key_g < S) ? expf(acc[r]) : 0.f;
            sm_[r] += e;
            int head = hb + r;
            int off = (head * 64 + (nt * 16 + lr) * 2) ^ ((head & 7) << 4);
            *(ushortT*)((char*)psc + off) = f2bf(e);
        }
        __syncthreads();
        // ---- PV: all 32 heads x this wave's 128 dims, K = 32 chunk keys ----
#pragma unroll
        for (int m2 = 0; m2 < 2; ++m2) {
            int arow = m2 * 16 + lr;
            bf16x8 a = *(const bf16x8*)((const char*)psc +
                        ((arow * 64 + lk * 16) ^ ((arow & 7) << 4)));
#pragma unroll
            for (int n2 = 0; n2 < 8; ++n2) {
                int dim = w * 128 + n2 * 16 + lr;
                bf16x8 b = *(const bf16x8*)((const char*)kbV +
                            ((dim * 64 + lk * 16) ^ ((dim & 7) << 4)));
                oa[m2][n2] = __builtin_amdgcn_mfma_f32_16x16x32_bf16(a, b, oa[m2][n2], 0, 0, 0);
            }
        }
        __syncthreads();
    }
    // ---- reduce per-head sums: over lr lanes, then across nt waves via LDS ----
#pragma unroll
    for (int off = 1; off < 16; off <<= 1)
#pragma unroll
        for (int r = 0; r < 4; ++r) sm_[r] += __shfl_xor(sm_[r], off);
    if (lr == 0) {
#pragma unroll
        for (int r = 0; r < 4; ++r) red[(mt * 16 + lk * 4 + r) * 2 + nt] = sm_[r];
    }
    __syncthreads();
    // ---- normalize, stage [32 heads][512 dims] bf16 into kbK (swizzled) ----
#pragma unroll
    for (int m2 = 0; m2 < 2; ++m2)
#pragma unroll
        for (int r = 0; r < 4; ++r) {
            int head = m2 * 16 + lk * 4 + r;
            float dvv = 1.f / (red[head * 2] + red[head * 2 + 1]);
#pragma unroll
            for (int n2 = 0; n2 < 8; ++n2) {
                int dim = w * 128 + n2 * 16 + lr;
                int off = (head * 1024 + dim * 2) ^ ((head & 7) << 4);
                *(ushortT*)((char*)kbK + off) = f2bf(oa[m2][n2][r] * dvv);
            }
        }
    __syncthreads();
    // ---- coalesced store: 4 consecutive lanes cover 64B of one head row ----
    ushortT* orow = olat + (size_t)t * 18432;
#pragma unroll
    for (int i = 0; i < 8; ++i) {
        int idx = i * 256 + tid;
        int head = idx >> 6, seg = idx & 63;
        uint4 v = *(const uint4*)((const char*)kbK +
                   ((head * 1024 + seg * 16) ^ ((head & 7) << 4)));
        *(uint4*)(orow + head * 512 + seg * 8) = v;
    }
}

// ---------------- launch ----------------
extern "C" void kernel_launch(void* const* d_in, const int* in_sizes, int n_in,
                              void* d_out, int out_size, void* d_ws, size_t ws_size,
                              hipStream_t stream) {
    (void)in_sizes; (void)n_in; (void)out_size; (void)ws_size;
    const int*   positions = (const int*)d_in[0];
    const float* hs        = (const float*)d_in[1];
    const float* q_c       = (const float*)d_in[2];
    const float* kv_lora   = (const float*)d_in[3];
    const float* W_qb      = (const float*)d_in[4];
    const float* W_kvb     = (const float*)d_in[5];
    const float* W_o       = (const float*)d_in[6];
    const float* kv_ln     = (const float*)d_in[7];
    const float* W_iq      = (const float*)d_in[8];
    const float* W_ik      = (const float*)d_in[9];
    const float* gamma     = (const float*)d_in[10];
    const float* beta      = (const float*)d_in[11];
    const float* W_iw      = (const float*)d_in[12];

    float* ws = (float*)d_ws;
    // workspace (float offsets); high-water 50,204,672 fl = 200.8 MB (< 218.4 proven)
    float*   cosT   = ws;                          // 65,536
    float*   sinT   = ws + 65536;                  // 65,536
    int*     tki    = (int*)(ws + 131072);         // 1,048,576
    int*     tkc    = (int*)(ws + 1179648);        // 2,048
    ushortT* kcat   = (ushortT*)(ws + 1181696);    // 589,824 fl
    float*   kscale = ws + 1771520;                // 2,048
    float*   qscale = ws + 1773568;                // 65,536
    float*   wts    = ws + 1839104;                // 65,536
    uchar*   qi8    = (uchar*)(ws + 1904640);      // 2,097,152 fl (8 MB bytes)
    uchar*   ki8    = (uchar*)(ws + 4001792);      // 65,536 fl
    // REGION R1 4067328..20844544, time-multiplexed:
    float*   kip    = ws + 4067328;                // 16 x 262,144 [step2 -> dead after 3]
    float*   qip0   = ws + 4067328;                // 8,388,608   [step4 -> dead after 5]
    float*   qip1   = ws + 12455936;               // 8,388,608   [step4 -> dead after 5]
    ushortT* wqb_t  = (ushortT*)(ws + 4067328);    // 4,718,592 fl [10 -> dead after 11]
    ushortT* qc_bf  = (ushortT*)(ws + 8785920);    // 1,572,864 fl [10 -> dead after 11]
    ushortT* wuk_t  = (ushortT*)(ws + 10358784);   // 1,048,576 fl [10 -> dead after 13]
    ushortT* wuv_t  = (ushortT*)(ws + 11407360);   // 1,048,576 fl [10 -> read at 15]
    ushortT* wo_t   = (ushortT*)(ws + 4067328);    // 4,194,304 fl [13b over dead wqb_t]
    // score / vbuf slot:
    float*   score  = ws + 20844544;               // 4,194,304 [7 -> dead after 8]
    ushortT* vbuf   = (ushortT*)(ws + 20844544);   // 4,194,304 fl [15 -> 16]
    // persistent tail:
    ushortT* qfull_bf = (ushortT*)(ws + 25038848); // 6,291,456 fl [11 -> 12,13]
    ushortT* qcat   = (ushortT*)(ws + 31330304);   // 18,874,368 fl; o written in place (14)

    // 1. rope tables
    k_rope_tables<<<T_N, 32, 0, stream>>>(positions, cosT, sinT);
    // 2. indexer k: hs @ W_ik (2048x128x2048), split-K x16 -> partials
    gemm128<false><<<dim3(1, 16, 16), 256, 0, stream>>>(
        hs, W_ik, kip, T_N, 128, 128, HID_N, 128, 128, 128, 16384, 262144);
    // 3. sum partials + LN + neox rope + fp8 quant -> ki8 bytes
    k_ki_post16<<<T_N, 128, 0, stream>>>(kip, gamma, beta, cosT, sinT, ki8, kscale);
    // 4. indexer q: q_c @ W_iq (2048x4096x1536), split-K x2 -> partials
    gemm128<false><<<dim3(32, 16, 2), 256, 0, stream>>>(
        q_c, W_iq, qip0, T_N, 4096, 768, QLORA_N, 4096, 4096, 768, 3145728, 8388608);
    // 5. sum partials + neox rope + fp8 quant -> qi8 bytes
    k_qi_post2<<<T_N * IDX_H_N, 128, 0, stream>>>(qip0, qip1, cosT, sinT, qi8, qscale);
    // 6. indexer weights
    k_wiw<<<T_N, 256, 0, stream>>>(hs, W_iw, qscale, wts);
    // 7. indexer score via fp8 MFMA
    k_score8<<<2080, 256, 0, stream>>>(qi8, ki8, kscale, wts, score);
    // 8. top-512
    k_topk<<<T_N, 256, 0, stream>>>(score, tki, tkc);
    // 9. kv rms_norm + k_pe rope -> kcat bf16
    k_kv_post2<<<T_N, 256, 0, stream>>>(kv_lora, kv_ln, cosT, sinT, kcat);
    // 10. casts / transposes (R1 free again)
    k_cast4<<<3072, 256, 0, stream>>>(q_c, qc_bf, T_N * QLORA_N / 4);
    k_tcast<<<dim3(48, 192, 1), 256, 0, stream>>>(W_qb, wqb_t, 6144, 0, 0, 1536, 0);
    k_wuk_cast<<<8192, 256, 0, stream>>>(W_kvb, wuk_t);
    k_tcast<<<dim3(16, 4, 32), 256, 0, stream>>>(W_kvb, wuv_t, 8192, 128, 256, 512, 65536);
    // 11. qfull = q_c @ W_qb (bf16 MFMA) -> bf16 (T,32,192)
    bgemm<true><<<dim3(48, 16, 1), 256, 0, stream>>>(
        qc_bf, wqb_t, qfull_bf, QLORA_N, QLORA_N, QLORA_N, 6144, 0, 0, 0, 1.f);
    // 12. rope q_pe -> qcat[...,512:576]
    k_rope_q2<<<T_N * H_N / 8, 256, 0, stream>>>(qfull_bf, cosT, sinT, qcat);
    // 13. q_lat = q_nope @ W_UK^T per head -> qcat[...,0:512] (SCALE folded)
    bgemm<true><<<dim3(4, 16, 32), 256, 0, stream>>>(
        qfull_bf, wuk_t, qcat, NOPE_N, 6144, 128, 18432, 192, 65536, 576, SCALE_F);
    // 13b. wo_t transpose (over dead wqb_t)
    k_tcast<<<dim3(128, 64, 1), 256, 0, stream>>>(W_o, wo_t, 2048, 0, 0, 4096, 0);
    // 14. fused sparse MFMA attention (single-pass) -> o written in place into qcat rows
    k_attn_mfma<<<T_N, 256, 0, stream>>>(qcat, kcat, tki, tkc, qcat);
    // 15. v = o @ W_UV per head -> vbuf bf16 (T,4096)
    bgemm<true><<<dim3(1, 16, 32), 256, 0, stream>>>(
        qcat, wuv_t, vbuf, KVLORA_N, 18432, 512, 4096, 512, 65536, 128, 1.f);
    // 16. out = vbuf @ W_o -> f32
    bgemm<false><<<dim3(16, 16, 1), 256, 0, stream>>>(
        vbuf, wo_t, (float*)d_out, H_N * VD_N, 4096, 4096, HID_N, 0, 0, 0, 1.f);
}

// Round 12
// 802.802 us; speedup vs baseline: 7.9957x; 1.2996x over previous
//
#include <hip/hip_runtime.h>
#include <hip/hip_bf16.h>

// ---------------- constants ----------------
#define T_N    2048
#define H_N    32
#define NOPE_N 128
#define ROPE_N 64
#define VD_N   128
#define QLORA_N 1536
#define KVLORA_N 512
#define IDX_H_N 32
#define IDX_D_N 128
#define TOPK_N 512
#define HID_N  2048

typedef __attribute__((ext_vector_type(8))) short bf16x8;
typedef __attribute__((ext_vector_type(4))) float f32x4;
typedef unsigned short ushortT;
typedef unsigned char uchar;

#define SCALE_F 0.07216878364870323f  // (NOPE+ROPE)^-0.5 = 192^-0.5

static __device__ __forceinline__ ushortT f2bf(float x) {
    __hip_bfloat16 b = __float2bfloat16(x);
    return *(ushortT*)&b;
}
static __device__ __forceinline__ float bf2f(ushortT u) {
    __hip_bfloat16 b = *(__hip_bfloat16*)&u;
    return __bfloat162float(b);
}

// exact RNE float -> e4m3fn grid
static __device__ __forceinline__ float q_e4m3(float x) {
    float ax = fabsf(x);
    unsigned b = __float_as_uint(ax);
    int e = (int)(b >> 23) - 126;
    int ue = (e - 4 > -9) ? (e - 4) : -9;
    float ulp = __int_as_float((ue + 127) << 23);
    float q = rintf(ax / ulp) * ulp;
    return copysignf(q, x);
}

// encode a value ALREADY on the e4m3fn grid (|q|<=448) to its fp8 byte
static __device__ __forceinline__ uchar enc_e4m3(float q) {
    unsigned b = __float_as_uint(q);
    unsigned s = (b >> 31) << 7;
    float ax = fabsf(q);
    if (ax == 0.f) return (uchar)s;
    int e = (int)((b >> 23) & 255) - 127;   // q = 1.m * 2^e
    if (e >= -6) {
        unsigned m = (b >> 20) & 7;         // exact: grid value has 3 mantissa bits
        return (uchar)(s | ((unsigned)(e + 7) << 3) | m);
    }
    unsigned M = (unsigned)rintf(ax * 512.f);  // subnormal: M * 2^-9, M in 1..7
    return (uchar)(s | M);
}

// ---------------- rope tables ----------------
__global__ void k_rope_tables(const int* __restrict__ pos, float* __restrict__ cosT,
                              float* __restrict__ sinT) {
    int t = blockIdx.x, i = threadIdx.x;
    double inv = 1.0 / pow(10000.0, (double)i / 32.0);
    double ang = (double)pos[t] * inv;
    cosT[t * 32 + i] = (float)cos(ang);
    sinT[t * 32 + i] = (float)sin(ang);
}

// ---------------- generic 128x128 f32 GEMM (BK=8), batched/split-K via blockIdx.z -------
template <bool BT>
__global__ __launch_bounds__(256) void gemm128(
    const float* __restrict__ A, const float* __restrict__ B, float* __restrict__ C,
    int M, int N, int K, int lda, int ldb, int ldc,
    long batchOffA, long batchOffB, long batchOffC) {
    const float* Ab = A + (size_t)batchOffA * blockIdx.z;
    const float* Bb = B + (size_t)batchOffB * blockIdx.z;
    int bm = blockIdx.y * 128, bn = blockIdx.x * 128;
    int tid = threadIdx.x;
    __shared__ float As[8][128];
    __shared__ float Bs[8][128];
    float acc[8][8];
#pragma unroll
    for (int i = 0; i < 8; ++i)
#pragma unroll
        for (int j = 0; j < 8; ++j) acc[i][j] = 0.f;
    int tx = tid & 15, ty = tid >> 4;
    int ar = tid >> 1, ak = (tid & 1) * 4;
    for (int k0 = 0; k0 < K; k0 += 8) {
        float4 av = *(const float4*)(Ab + (size_t)(bm + ar) * lda + k0 + ak);
        As[ak + 0][ar] = av.x; As[ak + 1][ar] = av.y;
        As[ak + 2][ar] = av.z; As[ak + 3][ar] = av.w;
        if (BT) {
            int n = tid >> 1, kk = (tid & 1) * 4;
            float4 bv = *(const float4*)(Bb + (size_t)(bn + n) * ldb + k0 + kk);
            Bs[kk + 0][n] = bv.x; Bs[kk + 1][n] = bv.y;
            Bs[kk + 2][n] = bv.z; Bs[kk + 3][n] = bv.w;
        } else {
            int kk = tid >> 5, n = (tid & 31) * 4;
            float4 bv = *(const float4*)(Bb + (size_t)(k0 + kk) * ldb + bn + n);
            Bs[kk][n + 0] = bv.x; Bs[kk][n + 1] = bv.y;
            Bs[kk][n + 2] = bv.z; Bs[kk][n + 3] = bv.w;
        }
        __syncthreads();
#pragma unroll
        for (int kk = 0; kk < 8; ++kk) {
            float4 a0 = *(const float4*)(&As[kk][ty * 8]);
            float4 a1 = *(const float4*)(&As[kk][ty * 8 + 4]);
            float4 b0 = *(const float4*)(&Bs[kk][tx * 8]);
            float4 b1 = *(const float4*)(&Bs[kk][tx * 8 + 4]);
            float a[8] = {a0.x, a0.y, a0.z, a0.w, a1.x, a1.y, a1.z, a1.w};
            float b[8] = {b0.x, b0.y, b0.z, b0.w, b1.x, b1.y, b1.z, b1.w};
#pragma unroll
            for (int i = 0; i < 8; ++i)
#pragma unroll
                for (int j = 0; j < 8; ++j) acc[i][j] = fmaf(a[i], b[j], acc[i][j]);
        }
        __syncthreads();
    }
    size_t cbase = (size_t)batchOffC * blockIdx.z;
#pragma unroll
    for (int i = 0; i < 8; ++i) {
        size_t r = bm + ty * 8 + i;
#pragma unroll
        for (int j = 0; j < 8; ++j) {
            size_t c = bn + tx * 8 + j;
            C[cbase + r * (size_t)ldc + c] = acc[i][j];
        }
    }
}

// ======== bf16 NT MFMA GEMM: A(M,K) bf16, B(N,K) bf16, 128x128 tile, BK=64 =============
// CB16 epilogue: LDS bounce -> full-64B-line coalesced uint4 stores.
template <bool CB16>
__global__ __launch_bounds__(256) void bgemm(
    const ushortT* __restrict__ A, const ushortT* __restrict__ B, void* __restrict__ Cv,
    int K, int lda, int ldb, int ldc,
    long boffA, long boffB, long boffC, float scaleC) {
    const ushortT* Ab = A + (size_t)boffA * blockIdx.z;
    const ushortT* Bb = B + (size_t)boffB * blockIdx.z;
    int bm = blockIdx.y * 128, bn = blockIdx.x * 128;
    int tid = threadIdx.x, lane = tid & 63, w = tid >> 6;
    int wr = w >> 1, wc = w & 1;
    int lr = lane & 15, lk = lane >> 4;

    __shared__ __align__(16) ushortT sbuf[16384];   // 32KB: As=sbuf, Bs=sbuf+8192
    ushortT* As = sbuf;
    ushortT* Bs = sbuf + 8192;

    f32x4 acc[4][4];
#pragma unroll
    for (int i = 0; i < 4; ++i)
#pragma unroll
        for (int j = 0; j < 4; ++j) acc[i][j] = (f32x4){0.f, 0.f, 0.f, 0.f};

    for (int kt = 0; kt < K; kt += 64) {
        __syncthreads();
#pragma unroll
        for (int q = 0; q < 4; ++q) {
            int ch = tid + q * 256;
            int row = ch >> 3, e8 = ch & 7;
            int byteoff = (row * 128 + e8 * 16) ^ ((row & 7) << 4);
            uint4 va = *(const uint4*)(Ab + (size_t)(bm + row) * lda + kt + e8 * 8);
            *(uint4*)((char*)As + byteoff) = va;
            uint4 vb = *(const uint4*)(Bb + (size_t)(bn + row) * ldb + kt + e8 * 8);
            *(uint4*)((char*)Bs + byteoff) = vb;
        }
        __syncthreads();
#pragma unroll
        for (int kk = 0; kk < 2; ++kk) {
            bf16x8 af[4], bfr[4];
#pragma unroll
            for (int i = 0; i < 4; ++i) {
                int arow = wr * 64 + i * 16 + lr;
                af[i] = *(const bf16x8*)((const char*)As +
                         ((arow * 128 + kk * 64 + lk * 16) ^ ((arow & 7) << 4)));
                int brow = wc * 64 + i * 16 + lr;
                bfr[i] = *(const bf16x8*)((const char*)Bs +
                         ((brow * 128 + kk * 64 + lk * 16) ^ ((brow & 7) << 4)));
            }
#pragma unroll
            for (int i = 0; i < 4; ++i)
#pragma unroll
                for (int j = 0; j < 4; ++j)
                    acc[i][j] = __builtin_amdgcn_mfma_f32_16x16x32_bf16(af[i], bfr[j], acc[i][j], 0, 0, 0);
        }
    }
    size_t cbase = (size_t)boffC * blockIdx.z;
    if (CB16) {
        __syncthreads();   // all waves done reading As/Bs
#pragma unroll
        for (int mi = 0; mi < 4; ++mi)
#pragma unroll
            for (int ni = 0; ni < 4; ++ni)
#pragma unroll
                for (int r = 0; r < 4; ++r) {
                    int row = wr * 64 + mi * 16 + lk * 4 + r;
                    int col = wc * 64 + ni * 16 + lr;
                    int off = (row * 256 + col * 2) ^ ((row & 7) << 4);
                    *(ushortT*)((char*)sbuf + off) = f2bf(acc[mi][ni][r] * scaleC);
                }
        __syncthreads();
        ushortT* outp = (ushortT*)Cv;
#pragma unroll
        for (int i = 0; i < 8; ++i) {
            int idx = i * 256 + tid;
            int row = idx >> 4, seg = idx & 15;
            uint4 v = *(const uint4*)((const char*)sbuf +
                       ((row * 256 + seg * 16) ^ ((row & 7) << 4)));
            *(uint4*)(outp + cbase + (size_t)(bm + row) * ldc + bn + seg * 8) = v;
        }
    } else {
#pragma unroll
        for (int mi = 0; mi < 4; ++mi)
#pragma unroll
            for (int ni = 0; ni < 4; ++ni) {
                int col = bn + wc * 64 + ni * 16 + lr;
#pragma unroll
                for (int r = 0; r < 4; ++r) {
                    int row = bm + wr * 64 + mi * 16 + lk * 4 + r;
                    ((float*)Cv)[cbase + (size_t)row * ldc + col] = acc[mi][ni][r];
                }
            }
    }
}

// ---------------- cast / transpose helpers ----------------
__global__ __launch_bounds__(256) void k_cast4(const float* __restrict__ src,
                                               ushortT* __restrict__ dst, int n4) {
    int i = blockIdx.x * 256 + threadIdx.x;
    if (i < n4) {
        float4 v = ((const float4*)src)[i];
        ushortT o[4] = {f2bf(v.x), f2bf(v.y), f2bf(v.z), f2bf(v.w)};
        *(uint2*)(dst + (size_t)i * 4) = *(uint2*)o;
    }
}

// dst[z][b][a] bf16 = src[a*sa + b + soff + z*sz]  (sb==1), tiles 32x32
__global__ __launch_bounds__(256) void k_tcast(const float* __restrict__ src,
                                               ushortT* __restrict__ dst,
                                               long sa, long soff, long sz,
                                               long da, long dz) {
    __shared__ float tile[32][33];
    int a0 = blockIdx.x * 32, b0 = blockIdx.y * 32;
    int tx = threadIdx.x & 31, ty = threadIdx.x >> 5;
    const float* s = src + (size_t)sz * blockIdx.z + soff;
#pragma unroll
    for (int i = ty; i < 32; i += 8)
        tile[i][tx] = s[(size_t)(a0 + i) * sa + (b0 + tx)];
    __syncthreads();
    ushortT* d = dst + (size_t)dz * blockIdx.z;
#pragma unroll
    for (int i = ty; i < 32; i += 8)
        d[(size_t)(b0 + i) * da + a0 + tx] = f2bf(tile[tx][i]);
}

// wuk_t[h][r][n] = W_kvb[r][h][n]
__global__ __launch_bounds__(256) void k_wuk_cast(const float* __restrict__ wkvb,
                                                  ushortT* __restrict__ wuk) {
    int i = blockIdx.x * 256 + threadIdx.x;
    int n = i & 127, r = (i >> 7) & 511, h = i >> 16;
    wuk[i] = f2bf(wkvb[(size_t)r * 8192 + h * 256 + n]);
}

// ------- kv postprocess -> kcat bf16 (T,576) ----
__global__ __launch_bounds__(256) void k_kv_post2(const float* __restrict__ kv,
                                                  const float* __restrict__ lnw,
                                                  const float* __restrict__ cosT,
                                                  const float* __restrict__ sinT,
                                                  ushortT* __restrict__ kcat) {
    int t = blockIdx.x, tid = threadIdx.x;
    const float* row = kv + (size_t)t * 576;
    float v0 = row[tid], v1 = row[tid + 256];
    float s = v0 * v0 + v1 * v1;
    for (int o = 32; o > 0; o >>= 1) s += __shfl_down(s, o);
    __shared__ float sm[4];
    if ((tid & 63) == 0) sm[tid >> 6] = s;
    __syncthreads();
    float tot = sm[0] + sm[1] + sm[2] + sm[3];
    float inv = 1.f / sqrtf(tot / 512.f + 1e-6f);
    ushortT* out = kcat + (size_t)t * 576;
    out[tid] = f2bf(v0 * inv * lnw[tid]);
    out[tid + 256] = f2bf(v1 * inv * lnw[tid + 256]);
    if (tid < 32) {
        float c = cosT[t * 32 + tid], sn = sinT[t * 32 + tid];
        float x1 = row[512 + 2 * tid], x2 = row[512 + 2 * tid + 1];
        out[512 + 2 * tid] = f2bf(x1 * c - x2 * sn);
        out[512 + 2 * tid + 1] = f2bf(x2 * c + x1 * sn);
    }
}

// ------- rope on q_pe (bf16 qfull) -> qcat[...,512:576] (SCALE folded) ------------------
__global__ __launch_bounds__(256) void k_rope_q2(const ushortT* __restrict__ qfull,
                                                 const float* __restrict__ cosT,
                                                 const float* __restrict__ sinT,
                                                 ushortT* __restrict__ qcat) {
    int b = blockIdx.x * 8 + (threadIdx.x >> 5);
    int i = threadIdx.x & 31;
    int t = b >> 5, h = b & 31;
    const ushortT* p = qfull + (size_t)b * 192 + 128;
    float c = cosT[t * 32 + i], s = sinT[t * 32 + i];
    float x1 = bf2f(p[2 * i]), x2 = bf2f(p[2 * i + 1]);
    ushortT* q = qcat + (size_t)t * 18432 + h * 576 + 512;
    q[2 * i] = f2bf((x1 * c - x2 * s) * SCALE_F);
    q[2 * i + 1] = f2bf((x2 * c + x1 * s) * SCALE_F);
}

// ---- indexer k: sum 16 split-K partials + layernorm + neox rope + fp8 quant -> bytes ----
__global__ __launch_bounds__(128) void k_ki_post16(const float* __restrict__ kp,
                                                   const float* __restrict__ g,
                                                   const float* __restrict__ be,
                                                   const float* __restrict__ cosT,
                                                   const float* __restrict__ sinT,
                                                   uchar* __restrict__ ki8,
                                                   float* __restrict__ kscale) {
    int t = blockIdx.x, i = threadIdx.x;
    float x = 0.f;
#pragma unroll
    for (int z = 0; z < 16; ++z) x += kp[(size_t)z * 262144 + (size_t)t * 128 + i];
    float s = x;
    for (int o = 32; o > 0; o >>= 1) s += __shfl_down(s, o);
    __shared__ float sm[2];
    if ((i & 63) == 0) sm[i >> 6] = s;
    __syncthreads();
    float mean = (sm[0] + sm[1]) / 128.f;
    float d = x - mean;
    float s2 = d * d;
    for (int o = 32; o > 0; o >>= 1) s2 += __shfl_down(s2, o);
    __shared__ float sv[2];
    if ((i & 63) == 0) sv[i >> 6] = s2;
    __syncthreads();
    float var = (sv[0] + sv[1]) / 128.f;
    float nrm = d * (1.f / sqrtf(var + 1e-6f)) * g[i] + be[i];
    __shared__ float buf[128];
    buf[i] = nrm;
    __syncthreads();
    float out;
    if (i < 32)      out = buf[i] * cosT[t * 32 + i] - buf[i + 32] * sinT[t * 32 + i];
    else if (i < 64) out = buf[i] * cosT[t * 32 + i - 32] + buf[i - 32] * sinT[t * 32 + i - 32];
    else             out = nrm;
    float a = fabsf(out);
    for (int o = 32; o > 0; o >>= 1) a = fmaxf(a, __shfl_down(a, o));
    __shared__ float am[2];
    if ((i & 63) == 0) am[i >> 6] = a;
    __syncthreads();
    float amax = fmaxf(fmaxf(am[0], am[1]), 1e-10f);
    float scale = __int_as_float((((int)ceilf(log2f(amax / 448.f))) + 127) << 23);
    ki8[(size_t)t * 128 + i] = enc_e4m3(q_e4m3(out / scale));
    if (i == 0) kscale[t] = scale;
}

// ---- indexer q: bf16 GEMM result + neox rope + fp8 quant -> bytes -----------------------
__global__ __launch_bounds__(128) void k_qi_post_bf(const ushortT* __restrict__ qi_bf,
                                                    const float* __restrict__ cosT,
                                                    const float* __restrict__ sinT,
                                                    uchar* __restrict__ qi8,
                                                    float* __restrict__ qscale) {
    int b = blockIdx.x;
    int t = b >> 5;
    int i = threadIdx.x;
    float x = bf2f(qi_bf[(size_t)b * 128 + i]);
    __shared__ float buf[128];
    buf[i] = x;
    __syncthreads();
    float out;
    if (i < 32)      out = buf[i] * cosT[t * 32 + i] - buf[i + 32] * sinT[t * 32 + i];
    else if (i < 64) out = buf[i] * cosT[t * 32 + i - 32] + buf[i - 32] * sinT[t * 32 + i - 32];
    else             out = x;
    float a = fabsf(out);
    for (int o = 32; o > 0; o >>= 1) a = fmaxf(a, __shfl_down(a, o));
    __shared__ float am[2];
    if ((i & 63) == 0) am[i >> 6] = a;
    __syncthreads();
    float amax = fmaxf(fmaxf(am[0], am[1]), 1e-10f);
    float scale = __int_as_float((((int)ceilf(log2f(amax / 448.f))) + 127) << 23);
    qi8[(size_t)b * 128 + i] = enc_e4m3(q_e4m3(out / scale));
    if (i == 0) qscale[b] = scale;
}

// ---------------- indexer weights ----------------
__global__ __launch_bounds__(256) void k_wiw(const float* __restrict__ hs,
                                             const float* __restrict__ W_iw,
                                             const float* __restrict__ qscale,
                                             float* __restrict__ wts) {
    int t = blockIdx.x, tid = threadIdx.x;
    __shared__ float hr[2048];
    for (int i = tid; i < 2048; i += 256) hr[i] = hs[(size_t)t * 2048 + i];
    __syncthreads();
    int h = tid & 31, p = tid >> 5;
    float s = 0;
    for (int k = p * 256; k < p * 256 + 256; ++k) s = fmaf(hr[k], W_iw[(size_t)k * 32 + h], s);
    __shared__ float part[8][32];
    part[p][h] = s;
    __syncthreads();
    if (tid < 32) {
        float tot = 0;
#pragma unroll
        for (int pp = 0; pp < 8; ++pp) tot += part[pp][tid];
        const float a = (float)0.08838834764831845;   // 128^-0.5
        const float b = (float)0.1767766952966369;    // 32^-0.5
        wts[t * 32 + tid] = tot * qscale[t * 32 + tid] * a * b;
    }
}

// ======== indexer score via fp8 MFMA ====
__global__ __launch_bounds__(256) void k_score8(const uchar* __restrict__ qi8,
                                                const uchar* __restrict__ ki8,
                                                const float* __restrict__ kscale,
                                                const float* __restrict__ wts,
                                                float* __restrict__ score) {
    int b = blockIdx.x;
    int ti = (int)((sqrtf(8.f * b + 1.f) - 1.f) * 0.5f);
    while ((ti + 1) * (ti + 2) / 2 <= b) ++ti;
    while (ti * (ti + 1) / 2 > b) --ti;
    int si = b - ti * (ti + 1) / 2;
    int t0 = ti * 32, s0 = si * 32;
    int tid = threadIdx.x, lane = tid & 63, w = tid >> 6;
    int qt = w >> 1, qs = w & 1;
    int col = lane & 15, g = lane >> 4;

    __shared__ __align__(16) uchar k8s[4096];
    __shared__ __align__(16) uchar q8s[32768];
    __shared__ float wts_s[32][33];

    {
        int row = tid >> 3, inner = tid & 7;
        uint4 v = *(const uint4*)(ki8 + (size_t)(s0 + row) * 128 + inner * 16);
        *(uint4*)(k8s + ((row * 128 + inner * 16) ^ ((row & 7) << 4))) = v;
    }
    for (int c = tid; c < 1024; c += 256) {
        int tl = c >> 5, h = c & 31;
        wts_s[tl][h] = wts[(size_t)(t0 + tl) * 32 + h];
    }

    float ksc = kscale[s0 + qs * 16 + col];
    int arow = qt * 16 + col;
    int brow = qs * 16 + col;
    float sacc[4] = {0.f, 0.f, 0.f, 0.f};

    for (int h0 = 0; h0 < 32; h0 += 8) {
        __syncthreads();
        for (int c = tid; c < 2048; c += 256) {
            int hh = c >> 8, row = (c >> 3) & 31, inner = c & 7;
            uint4 v = *(const uint4*)(qi8 + ((size_t)(t0 + row) * 32 + h0 + hh) * 128 + inner * 16);
            *(uint4*)(q8s + hh * 4096 + ((row * 128 + inner * 16) ^ ((row & 7) << 4))) = v;
        }
        __syncthreads();
#pragma unroll
        for (int hh = 0; hh < 8; ++hh) {
            f32x4 c4 = (f32x4){0.f, 0.f, 0.f, 0.f};
#pragma unroll
            for (int kk = 0; kk < 4; ++kk) {
                long long a = *(const long long*)(q8s + hh * 4096 +
                              ((arow * 128 + kk * 32 + g * 8) ^ ((arow & 7) << 4)));
                long long bb = *(const long long*)(k8s +
                              ((brow * 128 + kk * 32 + g * 8) ^ ((brow & 7) << 4)));
                c4 = __builtin_amdgcn_mfma_f32_16x16x32_fp8_fp8(a, bb, c4, 0, 0, 0);
            }
            int h = h0 + hh;
#pragma unroll
            for (int r = 0; r < 4; ++r)
                sacc[r] = fmaf(fmaxf(c4[r] * ksc, 0.f), wts_s[qt * 16 + g * 4 + r][h], sacc[r]);
        }
    }
    int t = t0 + qt * 16 + g * 4;
    int s = s0 + qs * 16 + col;
#pragma unroll
    for (int r = 0; r < 4; ++r)
        if (s <= t + r) score[(size_t)(t + r) * T_N + s] = sacc[r];
}

// ---------------- top-512 per row (stable ties) --------------------------
__global__ __launch_bounds__(256) void k_topk(const float* __restrict__ score,
                                              int* __restrict__ tki, int* __restrict__ tkc) {
    int t = blockIdx.x;
    int n = t + 1;
    int tid = threadIdx.x;
    if (n <= TOPK_N) {
        for (int i = tid; i < n; i += 256) tki[(size_t)t * TOPK_N + i] = i;
        if (tid == 0) tkc[t] = n;
        return;
    }
    __shared__ unsigned keys[2048];
    const float* row = score + (size_t)t * T_N;
    for (int i = tid; i < n; i += 256) {
        float f = row[i] + 0.f;
        unsigned u = __float_as_uint(f);
        u = (u & 0x80000000u) ? ~u : (u | 0x80000000u);
        keys[i] = u;
    }
    __shared__ int hist[256];
    __shared__ unsigned sh_prefix;
    __shared__ int sh_need;
    if (tid == 0) { sh_prefix = 0u; sh_need = TOPK_N; }
    __syncthreads();
    unsigned maskHi = 0;
    for (int level = 3; level >= 0; --level) {
        hist[tid] = 0;
        __syncthreads();
        unsigned prefix = sh_prefix;
        int shift = level * 8;
        for (int i = tid; i < n; i += 256) {
            unsigned kk = keys[i];
            if ((kk & maskHi) == prefix) atomicAdd(&hist[(kk >> shift) & 255], 1);
        }
        __syncthreads();
        if (tid == 0) {
            int need = sh_need, cum = 0, bsel = 255;
            for (int bb = 255; bb >= 0; --bb) {
                if (cum + hist[bb] >= need) { bsel = bb; break; }
                cum += hist[bb];
            }
            sh_need = need - cum;
            sh_prefix = prefix | ((unsigned)bsel << shift);
        }
        __syncthreads();
        maskHi |= (0xFFu << shift);
    }
    unsigned thr = sh_prefix;
    int needEq = sh_need;
    int base = tid * 8;
    int eqcnt = 0;
#pragma unroll
    for (int j = 0; j < 8; ++j) {
        int i = base + j;
        if (i < n && keys[i] == thr) eqcnt++;
    }
    __shared__ int scn[256];
    scn[tid] = eqcnt;
    __syncthreads();
    for (int off = 1; off < 256; off <<= 1) {
        int add = (tid >= off) ? scn[tid - off] : 0;
        __syncthreads();
        scn[tid] += add;
        __syncthreads();
    }
    int eq_excl = scn[tid] - eqcnt;
    int acnt = 0;
    {
        int eqr = eq_excl;
#pragma unroll
        for (int j = 0; j < 8; ++j) {
            int i = base + j;
            if (i < n) {
                unsigned kk = keys[i];
                bool a = (kk > thr) || (kk == thr && eqr < needEq);
                if (kk == thr) eqr++;
                if (a) acnt++;
            }
        }
    }
    __syncthreads();
    scn[tid] = acnt;
    __syncthreads();
    for (int off = 1; off < 256; off <<= 1) {
        int add = (tid >= off) ? scn[tid - off] : 0;
        __syncthreads();
        scn[tid] += add;
        __syncthreads();
    }
    int pos = scn[tid] - acnt;
    {
        int eqr = eq_excl;
#pragma unroll
        for (int j = 0; j < 8; ++j) {
            int i = base + j;
            if (i < n) {
                unsigned kk = keys[i];
                bool a = (kk > thr) || (kk == thr && eqr < needEq);
                if (kk == thr) eqr++;
                if (a) tki[(size_t)t * TOPK_N + (pos++)] = i;
            }
        }
    }
    if (tid == 0) tkc[t] = TOPK_N;
}

// ======== fused sparse MFMA attention, single-pass flash-style ===============
__global__ __launch_bounds__(256, 2) void k_attn_mfma(const ushortT* __restrict__ qcat,
                                                      const ushortT* __restrict__ kcat,
                                                      const int* __restrict__ tki,
                                                      const int* __restrict__ tkc,
                                                      ushortT* __restrict__ olat) {
    int t = blockIdx.x;
    int tid = threadIdx.x;
    int lane = tid & 63;
    int w = tid >> 6;                 // 4 waves
    int S = tkc[t];
    int nchunk = (S + 31) >> 5;

    __shared__ int idx_s[512];
    __shared__ __align__(16) ushortT kbK[18 * 1024];  // [kk][32 keys][32 dims] 36864B
    __shared__ __align__(16) ushortT kbV[512 * 32];   // [512 dims][32 keys]    32768B
    __shared__ __align__(16) ushortT psc[32 * 32];    // [32 heads][32 keys]     2048B
    __shared__ float red[64];                         // [head][nt] partial sums

    idx_s[tid] = (tid < S) ? tki[(size_t)t * TOPK_N + tid] : 0;
    idx_s[tid + 256] = (tid + 256 < S) ? tki[(size_t)t * TOPK_N + tid + 256] : 0;

    int lr = lane & 15, lk = lane >> 4;
    int mt = w >> 1, nt = w & 1;      // score quadrant: heads mt*16, keys nt*16

    bf16x8 qf[18];
    {
        const ushortT* qrow = qcat + (size_t)t * 18432 + (size_t)(mt * 16 + lr) * 576 + lk * 8;
#pragma unroll
        for (int kk = 0; kk < 18; ++kk) qf[kk] = *(const bf16x8*)(qrow + kk * 32);
    }
    __syncthreads();

    int skey = tid & 31, part = tid >> 5;

    f32x4 oa[2][8];
#pragma unroll
    for (int i = 0; i < 2; ++i)
#pragma unroll
        for (int j = 0; j < 8; ++j) oa[i][j] = (f32x4){0.f, 0.f, 0.f, 0.f};
    float sm_[4] = {0.f, 0.f, 0.f, 0.f};

    uint4 sv[9];
    {   // prefetch chunk 0
        bool ok = skey < S;
        const ushortT* g = kcat + (size_t)idx_s[skey] * 576 + part * 8;
#pragma unroll
        for (int i = 0; i < 9; ++i) {
            uint4 v = {0, 0, 0, 0};
            if (ok) v = *(const uint4*)(g + i * 64);
            sv[i] = v;
        }
    }

    for (int p = 0; p < nchunk; ++p) {
#pragma unroll
        for (int i = 0; i < 9; ++i) {
            int dg = part + i * 8;
            int off = ((skey * 64 + (dg & 3) * 16) ^ ((skey & 7) << 4)) + (dg >> 2) * 2048;
            *(uint4*)((char*)kbK + off) = sv[i];
        }
#pragma unroll
        for (int i = 0; i < 8; ++i) {
            int dg = part + i * 8;
            const ushortT* pv = (const ushortT*)&sv[i];
#pragma unroll
            for (int j = 0; j < 8; ++j) {
                int off = ((dg * 8 + j) * 64 + skey * 2) ^ (j << 4);
                *(ushortT*)((char*)kbV + off) = pv[j];
            }
        }
        __syncthreads();
        if (p + 1 < nchunk) {
            int gk = (p + 1) * 32 + skey;
            bool ok = gk < S;
            const ushortT* g = kcat + (size_t)idx_s[gk] * 576 + part * 8;
#pragma unroll
            for (int i = 0; i < 9; ++i) {
                uint4 v = {0, 0, 0, 0};
                if (ok) v = *(const uint4*)(g + i * 64);
                sv[i] = v;
            }
        }
        f32x4 acc = (f32x4){0.f, 0.f, 0.f, 0.f};
        int brow = nt * 16 + lr;
#pragma unroll
        for (int kk = 0; kk < 18; ++kk) {
            bf16x8 b = *(const bf16x8*)((const char*)kbK + kk * 2048 +
                        ((brow * 64 + lk * 16) ^ ((brow & 7) << 4)));
            acc = __builtin_amdgcn_mfma_f32_16x16x32_bf16(qf[kk], b, acc, 0, 0, 0);
        }
        int key_g = p * 32 + nt * 16 + lr;
        int hb = mt * 16 + lk * 4;
#pragma unroll
        for (int r = 0; r < 4; ++r) {
            float e = (key_g < S) ? expf(acc[r]) : 0.f;
            sm_[r] += e;
            int head = hb + r;
            int off = (head * 64 + (nt * 16 + lr) * 2) ^ ((head & 7) << 4);
            *(ushortT*)((char*)psc + off) = f2bf(e);
        }
        __syncthreads();
#pragma unroll
        for (int m2 = 0; m2 < 2; ++m2) {
            int arow = m2 * 16 + lr;
            bf16x8 a = *(const bf16x8*)((const char*)psc +
                        ((arow * 64 + lk * 16) ^ ((arow & 7) << 4)));
#pragma unroll
            for (int n2 = 0; n2 < 8; ++n2) {
                int dim = w * 128 + n2 * 16 + lr;
                bf16x8 b = *(const bf16x8*)((const char*)kbV +
                            ((dim * 64 + lk * 16) ^ ((dim & 7) << 4)));
                oa[m2][n2] = __builtin_amdgcn_mfma_f32_16x16x32_bf16(a, b, oa[m2][n2], 0, 0, 0);
            }
        }
        __syncthreads();
    }
#pragma unroll
    for (int off = 1; off < 16; off <<= 1)
#pragma unroll
        for (int r = 0; r < 4; ++r) sm_[r] += __shfl_xor(sm_[r], off);
    if (lr == 0) {
#pragma unroll
        for (int r = 0; r < 4; ++r) red[(mt * 16 + lk * 4 + r) * 2 + nt] = sm_[r];
    }
    __syncthreads();
#pragma unroll
    for (int m2 = 0; m2 < 2; ++m2)
#pragma unroll
        for (int r = 0; r < 4; ++r) {
            int head = m2 * 16 + lk * 4 + r;
            float dvv = 1.f / (red[head * 2] + red[head * 2 + 1]);
#pragma unroll
            for (int n2 = 0; n2 < 8; ++n2) {
                int dim = w * 128 + n2 * 16 + lr;
                int off = (head * 1024 + dim * 2) ^ ((head & 7) << 4);
                *(ushortT*)((char*)kbK + off) = f2bf(oa[m2][n2][r] * dvv);
            }
        }
    __syncthreads();
    ushortT* orow = olat + (size_t)t * 18432;
#pragma unroll
    for (int i = 0; i < 8; ++i) {
        int idx = i * 256 + tid;
        int head = idx >> 6, seg = idx & 63;
        uint4 v = *(const uint4*)((const char*)kbK +
                   ((head * 1024 + seg * 16) ^ ((head & 7) << 4)));
        *(uint4*)(orow + head * 512 + seg * 8) = v;
    }
}

// ---------------- launch ----------------
extern "C" void kernel_launch(void* const* d_in, const int* in_sizes, int n_in,
                              void* d_out, int out_size, void* d_ws, size_t ws_size,
                              hipStream_t stream) {
    (void)in_sizes; (void)n_in; (void)out_size; (void)ws_size;
    const int*   positions = (const int*)d_in[0];
    const float* hs        = (const float*)d_in[1];
    const float* q_c       = (const float*)d_in[2];
    const float* kv_lora   = (const float*)d_in[3];
    const float* W_qb      = (const float*)d_in[4];
    const float* W_kvb     = (const float*)d_in[5];
    const float* W_o       = (const float*)d_in[6];
    const float* kv_ln     = (const float*)d_in[7];
    const float* W_iq      = (const float*)d_in[8];
    const float* W_ik      = (const float*)d_in[9];
    const float* gamma     = (const float*)d_in[10];
    const float* beta      = (const float*)d_in[11];
    const float* W_iw      = (const float*)d_in[12];

    float* ws = (float*)d_ws;
    // workspace (float offsets); high-water 50,204,672 fl = 200.8 MB (< 218.4 proven)
    float*   cosT   = ws;                          // 65,536
    float*   sinT   = ws + 65536;                  // 65,536
    int*     tki    = (int*)(ws + 131072);         // 1,048,576
    int*     tkc    = (int*)(ws + 1179648);        // 2,048
    ushortT* kcat   = (ushortT*)(ws + 1181696);    // 589,824 fl
    float*   kscale = ws + 1771520;                // 2,048
    float*   qscale = ws + 1773568;                // 65,536
    float*   wts    = ws + 1839104;                // 65,536
    uchar*   qi8    = (uchar*)(ws + 1904640);      // 2,097,152 fl (8 MB bytes)
    uchar*   ki8    = (uchar*)(ws + 4001792);      // 65,536 fl
    // qc_bf persistent through step 11:
    ushortT* qc_bf  = (ushortT*)(ws + 4067328);    // 1,572,864 fl [2a -> read 4, 11]
    // REGION R1 5,640,192..20,844,544, time-multiplexed:
    ushortT* wiq_t  = (ushortT*)(ws + 5640192);    // 3,145,728 fl [2b -> dead after 4]
    float*   kip    = ws + 8785920;                // 4,194,304  [2 -> dead after 3]
    ushortT* qi_bf  = (ushortT*)(ws + 12980224);   // 4,194,304 fl [4 -> dead after 5]
    ushortT* wqb_t  = (ushortT*)(ws + 5640192);    // 4,718,592 fl [10, over wiq_t/kip]
    ushortT* wuk_t  = (ushortT*)(ws + 10358784);   // 1,048,576 fl [10 -> dead after 13]
    ushortT* wuv_t  = (ushortT*)(ws + 11407360);   // 1,048,576 fl [10 -> read at 15]
    ushortT* wo_t   = (ushortT*)(ws + 12980224);   // 4,194,304 fl [10, over qi_bf]
    // score / vbuf slot:
    float*   score  = ws + 20844544;               // 4,194,304 [7 -> dead after 8]
    ushortT* vbuf   = (ushortT*)(ws + 20844544);   // 4,194,304 fl [15 -> 16]
    // persistent tail:
    ushortT* qfull_bf = (ushortT*)(ws + 25038848); // 6,291,456 fl [11 -> 12,13]
    ushortT* qcat   = (ushortT*)(ws + 31330304);   // 18,874,368 fl; o written in place (14)

    // 1. rope tables
    k_rope_tables<<<T_N, 32, 0, stream>>>(positions, cosT, sinT);
    // 2a/2b. bf16 casts for the q-path GEMMs
    k_cast4<<<3072, 256, 0, stream>>>(q_c, qc_bf, T_N * QLORA_N / 4);
    k_tcast<<<dim3(48, 128, 1), 256, 0, stream>>>(W_iq, wiq_t, 4096, 0, 0, 1536, 0);
    // 2. indexer k: hs @ W_ik (2048x128x2048), split-K x16 -> partials (f32, exact)
    gemm128<false><<<dim3(1, 16, 16), 256, 0, stream>>>(
        hs, W_ik, kip, T_N, 128, 128, HID_N, 128, 128, 128, 16384, 262144);
    // 3. sum partials + LN + neox rope + fp8 quant -> ki8 bytes
    k_ki_post16<<<T_N, 128, 0, stream>>>(kip, gamma, beta, cosT, sinT, ki8, kscale);
    // 4. indexer q: qc_bf @ wiq_t (bf16 MFMA) -> qi_bf (2048x4096)
    bgemm<true><<<dim3(32, 16, 1), 256, 0, stream>>>(
        qc_bf, wiq_t, qi_bf, QLORA_N, QLORA_N, QLORA_N, 4096, 0, 0, 0, 1.f);
    // 5. neox rope + fp8 quant -> qi8 bytes
    k_qi_post_bf<<<T_N * IDX_H_N, 128, 0, stream>>>(qi_bf, cosT, sinT, qi8, qscale);
    // 6. indexer weights
    k_wiw<<<T_N, 256, 0, stream>>>(hs, W_iw, qscale, wts);
    // 7. indexer score via fp8 MFMA
    k_score8<<<2080, 256, 0, stream>>>(qi8, ki8, kscale, wts, score);
    // 8. top-512
    k_topk<<<T_N, 256, 0, stream>>>(score, tki, tkc);
    // 9. kv rms_norm + k_pe rope -> kcat bf16
    k_kv_post2<<<T_N, 256, 0, stream>>>(kv_lora, kv_ln, cosT, sinT, kcat);
    // 10. remaining weight transposes (R1 free again)
    k_tcast<<<dim3(48, 192, 1), 256, 0, stream>>>(W_qb, wqb_t, 6144, 0, 0, 1536, 0);
    k_wuk_cast<<<8192, 256, 0, stream>>>(W_kvb, wuk_t);
    k_tcast<<<dim3(16, 4, 32), 256, 0, stream>>>(W_kvb, wuv_t, 8192, 128, 256, 512, 65536);
    k_tcast<<<dim3(128, 64, 1), 256, 0, stream>>>(W_o, wo_t, 2048, 0, 0, 4096, 0);
    // 11. qfull = q_c @ W_qb (bf16 MFMA) -> bf16 (T,32,192)
    bgemm<true><<<dim3(48, 16, 1), 256, 0, stream>>>(
        qc_bf, wqb_t, qfull_bf, QLORA_N, QLORA_N, QLORA_N, 6144, 0, 0, 0, 1.f);
    // 12. rope q_pe -> qcat[...,512:576]
    k_rope_q2<<<T_N * H_N / 8, 256, 0, stream>>>(qfull_bf, cosT, sinT, qcat);
    // 13. q_lat = q_nope @ W_UK^T per head -> qcat[...,0:512] (SCALE folded)
    bgemm<true><<<dim3(4, 16, 32), 256, 0, stream>>>(
        qfull_bf, wuk_t, qcat, NOPE_N, 6144, 128, 18432, 192, 65536, 576, SCALE_F);
    // 14. fused sparse MFMA attention (single-pass) -> o written in place into qcat rows
    k_attn_mfma<<<T_N, 256, 0, stream>>>(qcat, kcat, tki, tkc, qcat);
    // 15. v = o @ W_UV per head -> vbuf bf16 (T,4096)
    bgemm<true><<<dim3(1, 16, 32), 256, 0, stream>>>(
        qcat, wuv_t, vbuf, KVLORA_N, 18432, 512, 4096, 512, 65536, 128, 1.f);
    // 16. out = vbuf @ W_o -> f32
    bgemm<false><<<dim3(16, 16, 1), 256, 0, stream>>>(
        vbuf, wo_t, (float*)d_out, H_N * VD_N, 4096, 4096, HID_N, 0, 0, 0, 1.f);
}

// Round 13
// 665.646 us; speedup vs baseline: 9.6432x; 1.2061x over previous
//
#include <hip/hip_runtime.h>
#include <hip/hip_bf16.h>

// ---------------- constants ----------------
#define T_N    2048
#define H_N    32
#define NOPE_N 128
#define ROPE_N 64
#define VD_N   128
#define QLORA_N 1536
#define KVLORA_N 512
#define IDX_H_N 32
#define IDX_D_N 128
#define TOPK_N 512
#define HID_N  2048

typedef __attribute__((ext_vector_type(8))) short bf16x8;
typedef __attribute__((ext_vector_type(4))) float f32x4;
typedef unsigned short ushortT;
typedef unsigned char uchar;

#define SCALE_F 0.07216878364870323f  // (NOPE+ROPE)^-0.5 = 192^-0.5

static __device__ __forceinline__ ushortT f2bf(float x) {
    __hip_bfloat16 b = __float2bfloat16(x);
    return *(ushortT*)&b;
}
static __device__ __forceinline__ float bf2f(ushortT u) {
    __hip_bfloat16 b = *(__hip_bfloat16*)&u;
    return __bfloat162float(b);
}

// exact RNE float -> e4m3fn grid
static __device__ __forceinline__ float q_e4m3(float x) {
    float ax = fabsf(x);
    unsigned b = __float_as_uint(ax);
    int e = (int)(b >> 23) - 126;
    int ue = (e - 4 > -9) ? (e - 4) : -9;
    float ulp = __int_as_float((ue + 127) << 23);
    float q = rintf(ax / ulp) * ulp;
    return copysignf(q, x);
}

// encode a value ALREADY on the e4m3fn grid (|q|<=448) to its fp8 byte
static __device__ __forceinline__ uchar enc_e4m3(float q) {
    unsigned b = __float_as_uint(q);
    unsigned s = (b >> 31) << 7;
    float ax = fabsf(q);
    if (ax == 0.f) return (uchar)s;
    int e = (int)((b >> 23) & 255) - 127;   // q = 1.m * 2^e
    if (e >= -6) {
        unsigned m = (b >> 20) & 7;         // exact: grid value has 3 mantissa bits
        return (uchar)(s | ((unsigned)(e + 7) << 3) | m);
    }
    unsigned M = (unsigned)rintf(ax * 512.f);  // subnormal: M * 2^-9, M in 1..7
    return (uchar)(s | M);
}

// ---------------- rope tables ----------------
__global__ void k_rope_tables(const int* __restrict__ pos, float* __restrict__ cosT,
                              float* __restrict__ sinT) {
    int t = blockIdx.x, i = threadIdx.x;
    double inv = 1.0 / pow(10000.0, (double)i / 32.0);
    double ang = (double)pos[t] * inv;
    cosT[t * 32 + i] = (float)cos(ang);
    sinT[t * 32 + i] = (float)sin(ang);
}

// ---------------- generic 128x128 f32 GEMM (BK=8), batched/split-K via blockIdx.z -------
template <bool BT>
__global__ __launch_bounds__(256) void gemm128(
    const float* __restrict__ A, const float* __restrict__ B, float* __restrict__ C,
    int M, int N, int K, int lda, int ldb, int ldc,
    long batchOffA, long batchOffB, long batchOffC) {
    const float* Ab = A + (size_t)batchOffA * blockIdx.z;
    const float* Bb = B + (size_t)batchOffB * blockIdx.z;
    int bm = blockIdx.y * 128, bn = blockIdx.x * 128;
    int tid = threadIdx.x;
    __shared__ float As[8][128];
    __shared__ float Bs[8][128];
    float acc[8][8];
#pragma unroll
    for (int i = 0; i < 8; ++i)
#pragma unroll
        for (int j = 0; j < 8; ++j) acc[i][j] = 0.f;
    int tx = tid & 15, ty = tid >> 4;
    int ar = tid >> 1, ak = (tid & 1) * 4;
    for (int k0 = 0; k0 < K; k0 += 8) {
        float4 av = *(const float4*)(Ab + (size_t)(bm + ar) * lda + k0 + ak);
        As[ak + 0][ar] = av.x; As[ak + 1][ar] = av.y;
        As[ak + 2][ar] = av.z; As[ak + 3][ar] = av.w;
        if (BT) {
            int n = tid >> 1, kk = (tid & 1) * 4;
            float4 bv = *(const float4*)(Bb + (size_t)(bn + n) * ldb + k0 + kk);
            Bs[kk + 0][n] = bv.x; Bs[kk + 1][n] = bv.y;
            Bs[kk + 2][n] = bv.z; Bs[kk + 3][n] = bv.w;
        } else {
            int kk = tid >> 5, n = (tid & 31) * 4;
            float4 bv = *(const float4*)(Bb + (size_t)(k0 + kk) * ldb + bn + n);
            Bs[kk][n + 0] = bv.x; Bs[kk][n + 1] = bv.y;
            Bs[kk][n + 2] = bv.z; Bs[kk][n + 3] = bv.w;
        }
        __syncthreads();
#pragma unroll
        for (int kk = 0; kk < 8; ++kk) {
            float4 a0 = *(const float4*)(&As[kk][ty * 8]);
            float4 a1 = *(const float4*)(&As[kk][ty * 8 + 4]);
            float4 b0 = *(const float4*)(&Bs[kk][tx * 8]);
            float4 b1 = *(const float4*)(&Bs[kk][tx * 8 + 4]);
            float a[8] = {a0.x, a0.y, a0.z, a0.w, a1.x, a1.y, a1.z, a1.w};
            float b[8] = {b0.x, b0.y, b0.z, b0.w, b1.x, b1.y, b1.z, b1.w};
#pragma unroll
            for (int i = 0; i < 8; ++i)
#pragma unroll
                for (int j = 0; j < 8; ++j) acc[i][j] = fmaf(a[i], b[j], acc[i][j]);
        }
        __syncthreads();
    }
    size_t cbase = (size_t)batchOffC * blockIdx.z;
#pragma unroll
    for (int i = 0; i < 8; ++i) {
        size_t r = bm + ty * 8 + i;
#pragma unroll
        for (int j = 0; j < 8; ++j) {
            size_t c = bn + tx * 8 + j;
            C[cbase + r * (size_t)ldc + c] = acc[i][j];
        }
    }
}

// ======== bf16 NT MFMA GEMM: A(M,K) bf16, B(N,K) bf16, 128x128 tile, BK=64 =============
// CB16 epilogue: LDS bounce -> full-64B-line coalesced uint4 stores.
template <bool CB16>
__global__ __launch_bounds__(256) void bgemm(
    const ushortT* __restrict__ A, const ushortT* __restrict__ B, void* __restrict__ Cv,
    int K, int lda, int ldb, int ldc,
    long boffA, long boffB, long boffC, float scaleC) {
    const ushortT* Ab = A + (size_t)boffA * blockIdx.z;
    const ushortT* Bb = B + (size_t)boffB * blockIdx.z;
    int bm = blockIdx.y * 128, bn = blockIdx.x * 128;
    int tid = threadIdx.x, lane = tid & 63, w = tid >> 6;
    int wr = w >> 1, wc = w & 1;
    int lr = lane & 15, lk = lane >> 4;

    __shared__ __align__(16) ushortT sbuf[16384];   // 32KB: As=sbuf, Bs=sbuf+8192
    ushortT* As = sbuf;
    ushortT* Bs = sbuf + 8192;

    f32x4 acc[4][4];
#pragma unroll
    for (int i = 0; i < 4; ++i)
#pragma unroll
        for (int j = 0; j < 4; ++j) acc[i][j] = (f32x4){0.f, 0.f, 0.f, 0.f};

    for (int kt = 0; kt < K; kt += 64) {
        __syncthreads();
#pragma unroll
        for (int q = 0; q < 4; ++q) {
            int ch = tid + q * 256;
            int row = ch >> 3, e8 = ch & 7;
            int byteoff = (row * 128 + e8 * 16) ^ ((row & 7) << 4);
            uint4 va = *(const uint4*)(Ab + (size_t)(bm + row) * lda + kt + e8 * 8);
            *(uint4*)((char*)As + byteoff) = va;
            uint4 vb = *(const uint4*)(Bb + (size_t)(bn + row) * ldb + kt + e8 * 8);
            *(uint4*)((char*)Bs + byteoff) = vb;
        }
        __syncthreads();
#pragma unroll
        for (int kk = 0; kk < 2; ++kk) {
            bf16x8 af[4], bfr[4];
#pragma unroll
            for (int i = 0; i < 4; ++i) {
                int arow = wr * 64 + i * 16 + lr;
                af[i] = *(const bf16x8*)((const char*)As +
                         ((arow * 128 + kk * 64 + lk * 16) ^ ((arow & 7) << 4)));
                int brow = wc * 64 + i * 16 + lr;
                bfr[i] = *(const bf16x8*)((const char*)Bs +
                         ((brow * 128 + kk * 64 + lk * 16) ^ ((brow & 7) << 4)));
            }
#pragma unroll
            for (int i = 0; i < 4; ++i)
#pragma unroll
                for (int j = 0; j < 4; ++j)
                    acc[i][j] = __builtin_amdgcn_mfma_f32_16x16x32_bf16(af[i], bfr[j], acc[i][j], 0, 0, 0);
        }
    }
    size_t cbase = (size_t)boffC * blockIdx.z;
    if (CB16) {
        __syncthreads();   // all waves done reading As/Bs
#pragma unroll
        for (int mi = 0; mi < 4; ++mi)
#pragma unroll
            for (int ni = 0; ni < 4; ++ni)
#pragma unroll
                for (int r = 0; r < 4; ++r) {
                    int row = wr * 64 + mi * 16 + lk * 4 + r;
                    int col = wc * 64 + ni * 16 + lr;
                    int off = (row * 256 + col * 2) ^ ((row & 7) << 4);
                    *(ushortT*)((char*)sbuf + off) = f2bf(acc[mi][ni][r] * scaleC);
                }
        __syncthreads();
        ushortT* outp = (ushortT*)Cv;
#pragma unroll
        for (int i = 0; i < 8; ++i) {
            int idx = i * 256 + tid;
            int row = idx >> 4, seg = idx & 15;
            uint4 v = *(const uint4*)((const char*)sbuf +
                       ((row * 256 + seg * 16) ^ ((row & 7) << 4)));
            *(uint4*)(outp + cbase + (size_t)(bm + row) * ldc + bn + seg * 8) = v;
        }
    } else {
#pragma unroll
        for (int mi = 0; mi < 4; ++mi)
#pragma unroll
            for (int ni = 0; ni < 4; ++ni) {
                int col = bn + wc * 64 + ni * 16 + lr;
#pragma unroll
                for (int r = 0; r < 4; ++r) {
                    int row = bm + wr * 64 + mi * 16 + lk * 4 + r;
                    ((float*)Cv)[cbase + (size_t)row * ldc + col] = acc[mi][ni][r];
                }
            }
    }
}

// ---------------- cast / transpose helpers ----------------
__global__ __launch_bounds__(256) void k_cast4(const float* __restrict__ src,
                                               ushortT* __restrict__ dst, int n4) {
    int i = blockIdx.x * 256 + threadIdx.x;
    if (i < n4) {
        float4 v = ((const float4*)src)[i];
        ushortT o[4] = {f2bf(v.x), f2bf(v.y), f2bf(v.z), f2bf(v.w)};
        *(uint2*)(dst + (size_t)i * 4) = *(uint2*)o;
    }
}

// dst[z][b][a] bf16 = src[a*sa + b + soff + z*sz]  (sb==1), tiles 32x32
__global__ __launch_bounds__(256) void k_tcast(const float* __restrict__ src,
                                               ushortT* __restrict__ dst,
                                               long sa, long soff, long sz,
                                               long da, long dz) {
    __shared__ float tile[32][33];
    int a0 = blockIdx.x * 32, b0 = blockIdx.y * 32;
    int tx = threadIdx.x & 31, ty = threadIdx.x >> 5;
    const float* s = src + (size_t)sz * blockIdx.z + soff;
#pragma unroll
    for (int i = ty; i < 32; i += 8)
        tile[i][tx] = s[(size_t)(a0 + i) * sa + (b0 + tx)];
    __syncthreads();
    ushortT* d = dst + (size_t)dz * blockIdx.z;
#pragma unroll
    for (int i = ty; i < 32; i += 8)
        d[(size_t)(b0 + i) * da + a0 + tx] = f2bf(tile[tx][i]);
}

// wuk_t[h][r][n] = W_kvb[r][h][n]
__global__ __launch_bounds__(256) void k_wuk_cast(const float* __restrict__ wkvb,
                                                  ushortT* __restrict__ wuk) {
    int i = blockIdx.x * 256 + threadIdx.x;
    int n = i & 127, r = (i >> 7) & 511, h = i >> 16;
    wuk[i] = f2bf(wkvb[(size_t)r * 8192 + h * 256 + n]);
}

// ------- kv postprocess -> kcat bf16 (T,576) ----
__global__ __launch_bounds__(256) void k_kv_post2(const float* __restrict__ kv,
                                                  const float* __restrict__ lnw,
                                                  const float* __restrict__ cosT,
                                                  const float* __restrict__ sinT,
                                                  ushortT* __restrict__ kcat) {
    int t = blockIdx.x, tid = threadIdx.x;
    const float* row = kv + (size_t)t * 576;
    float v0 = row[tid], v1 = row[tid + 256];
    float s = v0 * v0 + v1 * v1;
    for (int o = 32; o > 0; o >>= 1) s += __shfl_down(s, o);
    __shared__ float sm[4];
    if ((tid & 63) == 0) sm[tid >> 6] = s;
    __syncthreads();
    float tot = sm[0] + sm[1] + sm[2] + sm[3];
    float inv = 1.f / sqrtf(tot / 512.f + 1e-6f);
    ushortT* out = kcat + (size_t)t * 576;
    out[tid] = f2bf(v0 * inv * lnw[tid]);
    out[tid + 256] = f2bf(v1 * inv * lnw[tid + 256]);
    if (tid < 32) {
        float c = cosT[t * 32 + tid], sn = sinT[t * 32 + tid];
        float x1 = row[512 + 2 * tid], x2 = row[512 + 2 * tid + 1];
        out[512 + 2 * tid] = f2bf(x1 * c - x2 * sn);
        out[512 + 2 * tid + 1] = f2bf(x2 * c + x1 * sn);
    }
}

// ------- rope on q_pe (bf16 qfull) -> qcat[...,512:576] (SCALE folded) ------------------
__global__ __launch_bounds__(256) void k_rope_q2(const ushortT* __restrict__ qfull,
                                                 const float* __restrict__ cosT,
                                                 const float* __restrict__ sinT,
                                                 ushortT* __restrict__ qcat) {
    int b = blockIdx.x * 8 + (threadIdx.x >> 5);
    int i = threadIdx.x & 31;
    int t = b >> 5, h = b & 31;
    const ushortT* p = qfull + (size_t)b * 192 + 128;
    float c = cosT[t * 32 + i], s = sinT[t * 32 + i];
    float x1 = bf2f(p[2 * i]), x2 = bf2f(p[2 * i + 1]);
    ushortT* q = qcat + (size_t)t * 18432 + h * 576 + 512;
    q[2 * i] = f2bf((x1 * c - x2 * s) * SCALE_F);
    q[2 * i + 1] = f2bf((x2 * c + x1 * s) * SCALE_F);
}

// ---- indexer k: sum 16 split-K partials + layernorm + neox rope + fp8 quant -> bytes ----
__global__ __launch_bounds__(128) void k_ki_post16(const float* __restrict__ kp,
                                                   const float* __restrict__ g,
                                                   const float* __restrict__ be,
                                                   const float* __restrict__ cosT,
                                                   const float* __restrict__ sinT,
                                                   uchar* __restrict__ ki8,
                                                   float* __restrict__ kscale) {
    int t = blockIdx.x, i = threadIdx.x;
    float x = 0.f;
#pragma unroll
    for (int z = 0; z < 16; ++z) x += kp[(size_t)z * 262144 + (size_t)t * 128 + i];
    float s = x;
    for (int o = 32; o > 0; o >>= 1) s += __shfl_down(s, o);
    __shared__ float sm[2];
    if ((i & 63) == 0) sm[i >> 6] = s;
    __syncthreads();
    float mean = (sm[0] + sm[1]) / 128.f;
    float d = x - mean;
    float s2 = d * d;
    for (int o = 32; o > 0; o >>= 1) s2 += __shfl_down(s2, o);
    __shared__ float sv[2];
    if ((i & 63) == 0) sv[i >> 6] = s2;
    __syncthreads();
    float var = (sv[0] + sv[1]) / 128.f;
    float nrm = d * (1.f / sqrtf(var + 1e-6f)) * g[i] + be[i];
    __shared__ float buf[128];
    buf[i] = nrm;
    __syncthreads();
    float out;
    if (i < 32)      out = buf[i] * cosT[t * 32 + i] - buf[i + 32] * sinT[t * 32 + i];
    else if (i < 64) out = buf[i] * cosT[t * 32 + i - 32] + buf[i - 32] * sinT[t * 32 + i - 32];
    else             out = nrm;
    float a = fabsf(out);
    for (int o = 32; o > 0; o >>= 1) a = fmaxf(a, __shfl_down(a, o));
    __shared__ float am[2];
    if ((i & 63) == 0) am[i >> 6] = a;
    __syncthreads();
    float amax = fmaxf(fmaxf(am[0], am[1]), 1e-10f);
    float scale = __int_as_float((((int)ceilf(log2f(amax / 448.f))) + 127) << 23);
    ki8[(size_t)t * 128 + i] = enc_e4m3(q_e4m3(out / scale));
    if (i == 0) kscale[t] = scale;
}

// ---- indexer q: bf16 GEMM result + neox rope + fp8 quant -> bytes -----------------------
__global__ __launch_bounds__(128) void k_qi_post_bf(const ushortT* __restrict__ qi_bf,
                                                    const float* __restrict__ cosT,
                                                    const float* __restrict__ sinT,
                                                    uchar* __restrict__ qi8,
                                                    float* __restrict__ qscale) {
    int b = blockIdx.x;
    int t = b >> 5;
    int i = threadIdx.x;
    float x = bf2f(qi_bf[(size_t)b * 128 + i]);
    __shared__ float buf[128];
    buf[i] = x;
    __syncthreads();
    float out;
    if (i < 32)      out = buf[i] * cosT[t * 32 + i] - buf[i + 32] * sinT[t * 32 + i];
    else if (i < 64) out = buf[i] * cosT[t * 32 + i - 32] + buf[i - 32] * sinT[t * 32 + i - 32];
    else             out = x;
    float a = fabsf(out);
    for (int o = 32; o > 0; o >>= 1) a = fmaxf(a, __shfl_down(a, o));
    __shared__ float am[2];
    if ((i & 63) == 0) am[i >> 6] = a;
    __syncthreads();
    float amax = fmaxf(fmaxf(am[0], am[1]), 1e-10f);
    float scale = __int_as_float((((int)ceilf(log2f(amax / 448.f))) + 127) << 23);
    qi8[(size_t)b * 128 + i] = enc_e4m3(q_e4m3(out / scale));
    if (i == 0) qscale[b] = scale;
}

// ---------------- indexer weights ----------------
__global__ __launch_bounds__(256) void k_wiw(const float* __restrict__ hs,
                                             const float* __restrict__ W_iw,
                                             const float* __restrict__ qscale,
                                             float* __restrict__ wts) {
    int t = blockIdx.x, tid = threadIdx.x;
    __shared__ float hr[2048];
    for (int i = tid; i < 2048; i += 256) hr[i] = hs[(size_t)t * 2048 + i];
    __syncthreads();
    int h = tid & 31, p = tid >> 5;
    float s = 0;
    for (int k = p * 256; k < p * 256 + 256; ++k) s = fmaf(hr[k], W_iw[(size_t)k * 32 + h], s);
    __shared__ float part[8][32];
    part[p][h] = s;
    __syncthreads();
    if (tid < 32) {
        float tot = 0;
#pragma unroll
        for (int pp = 0; pp < 8; ++pp) tot += part[pp][tid];
        const float a = (float)0.08838834764831845;   // 128^-0.5
        const float b = (float)0.1767766952966369;    // 32^-0.5
        wts[t * 32 + tid] = tot * qscale[t * 32 + tid] * a * b;
    }
}

// ======== indexer score via fp8 MFMA ====
__global__ __launch_bounds__(256) void k_score8(const uchar* __restrict__ qi8,
                                                const uchar* __restrict__ ki8,
                                                const float* __restrict__ kscale,
                                                const float* __restrict__ wts,
                                                float* __restrict__ score) {
    int b = blockIdx.x;
    int ti = (int)((sqrtf(8.f * b + 1.f) - 1.f) * 0.5f);
    while ((ti + 1) * (ti + 2) / 2 <= b) ++ti;
    while (ti * (ti + 1) / 2 > b) --ti;
    int si = b - ti * (ti + 1) / 2;
    int t0 = ti * 32, s0 = si * 32;
    int tid = threadIdx.x, lane = tid & 63, w = tid >> 6;
    int qt = w >> 1, qs = w & 1;
    int col = lane & 15, g = lane >> 4;

    __shared__ __align__(16) uchar k8s[4096];
    __shared__ __align__(16) uchar q8s[32768];
    __shared__ float wts_s[32][33];

    {
        int row = tid >> 3, inner = tid & 7;
        uint4 v = *(const uint4*)(ki8 + (size_t)(s0 + row) * 128 + inner * 16);
        *(uint4*)(k8s + ((row * 128 + inner * 16) ^ ((row & 7) << 4))) = v;
    }
    for (int c = tid; c < 1024; c += 256) {
        int tl = c >> 5, h = c & 31;
        wts_s[tl][h] = wts[(size_t)(t0 + tl) * 32 + h];
    }

    float ksc = kscale[s0 + qs * 16 + col];
    int arow = qt * 16 + col;
    int brow = qs * 16 + col;
    float sacc[4] = {0.f, 0.f, 0.f, 0.f};

    for (int h0 = 0; h0 < 32; h0 += 8) {
        __syncthreads();
        for (int c = tid; c < 2048; c += 256) {
            int hh = c >> 8, row = (c >> 3) & 31, inner = c & 7;
            uint4 v = *(const uint4*)(qi8 + ((size_t)(t0 + row) * 32 + h0 + hh) * 128 + inner * 16);
            *(uint4*)(q8s + hh * 4096 + ((row * 128 + inner * 16) ^ ((row & 7) << 4))) = v;
        }
        __syncthreads();
#pragma unroll
        for (int hh = 0; hh < 8; ++hh) {
            f32x4 c4 = (f32x4){0.f, 0.f, 0.f, 0.f};
#pragma unroll
            for (int kk = 0; kk < 4; ++kk) {
                long long a = *(const long long*)(q8s + hh * 4096 +
                              ((arow * 128 + kk * 32 + g * 8) ^ ((arow & 7) << 4)));
                long long bb = *(const long long*)(k8s +
                              ((brow * 128 + kk * 32 + g * 8) ^ ((brow & 7) << 4)));
                c4 = __builtin_amdgcn_mfma_f32_16x16x32_fp8_fp8(a, bb, c4, 0, 0, 0);
            }
            int h = h0 + hh;
#pragma unroll
            for (int r = 0; r < 4; ++r)
                sacc[r] = fmaf(fmaxf(c4[r] * ksc, 0.f), wts_s[qt * 16 + g * 4 + r][h], sacc[r]);
        }
    }
    int t = t0 + qt * 16 + g * 4;
    int s = s0 + qs * 16 + col;
#pragma unroll
    for (int r = 0; r < 4; ++r)
        if (s <= t + r) score[(size_t)(t + r) * T_N + s] = sacc[r];
}

// ---------------- top-512 per row (stable ties) --------------------------
__global__ __launch_bounds__(256) void k_topk(const float* __restrict__ score,
                                              int* __restrict__ tki, int* __restrict__ tkc) {
    int t = blockIdx.x;
    int n = t + 1;
    int tid = threadIdx.x;
    if (n <= TOPK_N) {
        for (int i = tid; i < n; i += 256) tki[(size_t)t * TOPK_N + i] = i;
        if (tid == 0) tkc[t] = n;
        return;
    }
    __shared__ unsigned keys[2048];
    const float* row = score + (size_t)t * T_N;
    for (int i = tid; i < n; i += 256) {
        float f = row[i] + 0.f;
        unsigned u = __float_as_uint(f);
        u = (u & 0x80000000u) ? ~u : (u | 0x80000000u);
        keys[i] = u;
    }
    __shared__ int hist[256];
    __shared__ unsigned sh_prefix;
    __shared__ int sh_need;
    if (tid == 0) { sh_prefix = 0u; sh_need = TOPK_N; }
    __syncthreads();
    unsigned maskHi = 0;
    for (int level = 3; level >= 0; --level) {
        hist[tid] = 0;
        __syncthreads();
        unsigned prefix = sh_prefix;
        int shift = level * 8;
        for (int i = tid; i < n; i += 256) {
            unsigned kk = keys[i];
            if ((kk & maskHi) == prefix) atomicAdd(&hist[(kk >> shift) & 255], 1);
        }
        __syncthreads();
        if (tid == 0) {
            int need = sh_need, cum = 0, bsel = 255;
            for (int bb = 255; bb >= 0; --bb) {
                if (cum + hist[bb] >= need) { bsel = bb; break; }
                cum += hist[bb];
            }
            sh_need = need - cum;
            sh_prefix = prefix | ((unsigned)bsel << shift);
        }
        __syncthreads();
        maskHi |= (0xFFu << shift);
    }
    unsigned thr = sh_prefix;
    int needEq = sh_need;
    int base = tid * 8;
    int eqcnt = 0;
#pragma unroll
    for (int j = 0; j < 8; ++j) {
        int i = base + j;
        if (i < n && keys[i] == thr) eqcnt++;
    }
    __shared__ int scn[256];
    scn[tid] = eqcnt;
    __syncthreads();
    for (int off = 1; off < 256; off <<= 1) {
        int add = (tid >= off) ? scn[tid - off] : 0;
        __syncthreads();
        scn[tid] += add;
        __syncthreads();
    }
    int eq_excl = scn[tid] - eqcnt;
    int acnt = 0;
    {
        int eqr = eq_excl;
#pragma unroll
        for (int j = 0; j < 8; ++j) {
            int i = base + j;
            if (i < n) {
                unsigned kk = keys[i];
                bool a = (kk > thr) || (kk == thr && eqr < needEq);
                if (kk == thr) eqr++;
                if (a) acnt++;
            }
        }
    }
    __syncthreads();
    scn[tid] = acnt;
    __syncthreads();
    for (int off = 1; off < 256; off <<= 1) {
        int add = (tid >= off) ? scn[tid - off] : 0;
        __syncthreads();
        scn[tid] += add;
        __syncthreads();
    }
    int pos = scn[tid] - acnt;
    {
        int eqr = eq_excl;
#pragma unroll
        for (int j = 0; j < 8; ++j) {
            int i = base + j;
            if (i < n) {
                unsigned kk = keys[i];
                bool a = (kk > thr) || (kk == thr && eqr < needEq);
                if (kk == thr) eqr++;
                if (a) tki[(size_t)t * TOPK_N + (pos++)] = i;
            }
        }
    }
    if (tid == 0) tkc[t] = TOPK_N;
}

// ======== fused sparse MFMA attention, single-pass flash-style (round 13) ===============
// Change vs r12: coalesced gather lane map (skey = w*8 + lane>>3, part = lane&7) so 8
// consecutive lanes read 128 consecutive bytes of one kcat row (~4x fewer L2 requests);
// kbV layout gains a dim-dependent key-group rotation to keep writes at ~4-way conflicts.
__global__ __launch_bounds__(256, 2) void k_attn_mfma(const ushortT* __restrict__ qcat,
                                                      const ushortT* __restrict__ kcat,
                                                      const int* __restrict__ tki,
                                                      const int* __restrict__ tkc,
                                                      ushortT* __restrict__ olat) {
    int t = blockIdx.x;
    int tid = threadIdx.x;
    int lane = tid & 63;
    int w = tid >> 6;                 // 4 waves
    int S = tkc[t];
    int nchunk = (S + 31) >> 5;

    __shared__ int idx_s[512];
    __shared__ __align__(16) ushortT kbK[18 * 1024];  // [kk][32 keys][32 dims] 36864B
    __shared__ __align__(16) ushortT kbV[512 * 32];   // [512 dims][32 keys, grp-rotated]
    __shared__ __align__(16) ushortT psc[32 * 32];    // [32 heads][32 keys]     2048B
    __shared__ float red[64];                         // [head][nt] partial sums

    idx_s[tid] = (tid < S) ? tki[(size_t)t * TOPK_N + tid] : 0;
    idx_s[tid + 256] = (tid + 256 < S) ? tki[(size_t)t * TOPK_N + tid + 256] : 0;

    int lr = lane & 15, lk = lane >> 4;
    int mt = w >> 1, nt = w & 1;      // score quadrant: heads mt*16, keys nt*16

    bf16x8 qf[18];
    {
        const ushortT* qrow = qcat + (size_t)t * 18432 + (size_t)(mt * 16 + lr) * 576 + lk * 8;
#pragma unroll
        for (int kk = 0; kk < 18; ++kk) qf[kk] = *(const bf16x8*)(qrow + kk * 32);
    }
    __syncthreads();

    // coalesced staging map: 8 lanes cover 128 consecutive bytes of one key row
    int skey = (w << 3) | (lane >> 3);   // 0..31
    int part = lane & 7;                 // 16B chunk index within each 128B group

    f32x4 oa[2][8];
#pragma unroll
    for (int i = 0; i < 2; ++i)
#pragma unroll
        for (int j = 0; j < 8; ++j) oa[i][j] = (f32x4){0.f, 0.f, 0.f, 0.f};
    float sm_[4] = {0.f, 0.f, 0.f, 0.f};

    uint4 sv[9];
    {   // prefetch chunk 0
        bool ok = skey < S;
        const ushortT* g = kcat + (size_t)idx_s[skey] * 576 + part * 8;
#pragma unroll
        for (int i = 0; i < 9; ++i) {
            uint4 v = {0, 0, 0, 0};
            if (ok) v = *(const uint4*)(g + i * 64);
            sv[i] = v;
        }
    }

    for (int p = 0; p < nchunk; ++p) {
        // ---- stage chunk p: K-layout + V-transposed (grp-rotated) ----
#pragma unroll
        for (int i = 0; i < 9; ++i) {
            int dg = part + i * 8;
            int off = ((skey * 64 + (dg & 3) * 16) ^ ((skey & 7) << 4)) + (dg >> 2) * 2048;
            *(uint4*)((char*)kbK + off) = sv[i];
        }
#pragma unroll
        for (int i = 0; i < 8; ++i) {           // dg < 64: V dims only
            int dg = part + i * 8;
            int inner = ((((skey >> 3) + (dg & 3)) & 3) << 4) | ((skey & 7) << 1);
            const ushortT* pv = (const ushortT*)&sv[i];
#pragma unroll
            for (int j = 0; j < 8; ++j) {       // dim = dg*8+j, dim&7 == j
                int off = ((dg * 8 + j) * 64 + inner) ^ (j << 4);
                *(ushortT*)((char*)kbV + off) = pv[j];
            }
        }
        __syncthreads();
        // issue prefetch AFTER the barrier: latency hides under score MFMA + exp
        if (p + 1 < nchunk) {
            int gk = (p + 1) * 32 + skey;
            bool ok = gk < S;
            const ushortT* g = kcat + (size_t)idx_s[gk] * 576 + part * 8;
#pragma unroll
            for (int i = 0; i < 9; ++i) {
                uint4 v = {0, 0, 0, 0};
                if (ok) v = *(const uint4*)(g + i * 64);
                sv[i] = v;
            }
        }
        // ---- score: C[16h][16k] for quadrant (mt, nt) ----
        f32x4 acc = (f32x4){0.f, 0.f, 0.f, 0.f};
        int brow = nt * 16 + lr;
#pragma unroll
        for (int kk = 0; kk < 18; ++kk) {
            bf16x8 b = *(const bf16x8*)((const char*)kbK + kk * 2048 +
                        ((brow * 64 + lk * 16) ^ ((brow & 7) << 4)));
            acc = __builtin_amdgcn_mfma_f32_16x16x32_bf16(qf[kk], b, acc, 0, 0, 0);
        }
        // ---- exp (m=0), accumulate sums, write P chunk ----
        int key_g = p * 32 + nt * 16 + lr;
        int hb = mt * 16 + lk * 4;
#pragma unroll
        for (int r = 0; r < 4; ++r) {
            float e = (key_g < S) ? expf(acc[r]) : 0.f;
            sm_[r] += e;
            int head = hb + r;
            int off = (head * 64 + (nt * 16 + lr) * 2) ^ ((head & 7) << 4);
            *(ushortT*)((char*)psc + off) = f2bf(e);
        }
        __syncthreads();
        // ---- PV: all 32 heads x this wave's 128 dims, K = 32 chunk keys ----
#pragma unroll
        for (int m2 = 0; m2 < 2; ++m2) {
            int arow = m2 * 16 + lr;
            bf16x8 a = *(const bf16x8*)((const char*)psc +
                        ((arow * 64 + lk * 16) ^ ((arow & 7) << 4)));
#pragma unroll
            for (int n2 = 0; n2 < 8; ++n2) {
                int dim = w * 128 + n2 * 16 + lr;
                int grp = (lk + ((dim >> 3) & 3)) & 3;
                bf16x8 b = *(const bf16x8*)((const char*)kbV +
                            ((dim * 64 + (grp << 4)) ^ ((dim & 7) << 4)));
                oa[m2][n2] = __builtin_amdgcn_mfma_f32_16x16x32_bf16(a, b, oa[m2][n2], 0, 0, 0);
            }
        }
        __syncthreads();
    }
    // ---- reduce per-head sums: over lr lanes, then across nt waves via LDS ----
#pragma unroll
    for (int off = 1; off < 16; off <<= 1)
#pragma unroll
        for (int r = 0; r < 4; ++r) sm_[r] += __shfl_xor(sm_[r], off);
    if (lr == 0) {
#pragma unroll
        for (int r = 0; r < 4; ++r) red[(mt * 16 + lk * 4 + r) * 2 + nt] = sm_[r];
    }
    __syncthreads();
    // ---- normalize, stage [32 heads][512 dims] bf16 into kbK (swizzled) ----
#pragma unroll
    for (int m2 = 0; m2 < 2; ++m2)
#pragma unroll
        for (int r = 0; r < 4; ++r) {
            int head = m2 * 16 + lk * 4 + r;
            float dvv = 1.f / (red[head * 2] + red[head * 2 + 1]);
#pragma unroll
            for (int n2 = 0; n2 < 8; ++n2) {
                int dim = w * 128 + n2 * 16 + lr;
                int off = (head * 1024 + dim * 2) ^ ((head & 7) << 4);
                *(ushortT*)((char*)kbK + off) = f2bf(oa[m2][n2][r] * dvv);
            }
        }
    __syncthreads();
    // ---- coalesced store: 4 consecutive lanes cover 64B of one head row ----
    ushortT* orow = olat + (size_t)t * 18432;
#pragma unroll
    for (int i = 0; i < 8; ++i) {
        int idx = i * 256 + tid;
        int head = idx >> 6, seg = idx & 63;
        uint4 v = *(const uint4*)((const char*)kbK +
                   ((head * 1024 + seg * 16) ^ ((head & 7) << 4)));
        *(uint4*)(orow + head * 512 + seg * 8) = v;
    }
}

// ---------------- launch ----------------
extern "C" void kernel_launch(void* const* d_in, const int* in_sizes, int n_in,
                              void* d_out, int out_size, void* d_ws, size_t ws_size,
                              hipStream_t stream) {
    (void)in_sizes; (void)n_in; (void)out_size; (void)ws_size;
    const int*   positions = (const int*)d_in[0];
    const float* hs        = (const float*)d_in[1];
    const float* q_c       = (const float*)d_in[2];
    const float* kv_lora   = (const float*)d_in[3];
    const float* W_qb      = (const float*)d_in[4];
    const float* W_kvb     = (const float*)d_in[5];
    const float* W_o       = (const float*)d_in[6];
    const float* kv_ln     = (const float*)d_in[7];
    const float* W_iq      = (const float*)d_in[8];
    const float* W_ik      = (const float*)d_in[9];
    const float* gamma     = (const float*)d_in[10];
    const float* beta      = (const float*)d_in[11];
    const float* W_iw      = (const float*)d_in[12];

    float* ws = (float*)d_ws;
    // workspace (float offsets); high-water 50,204,672 fl = 200.8 MB (< 218.4 proven)
    float*   cosT   = ws;                          // 65,536
    float*   sinT   = ws + 65536;                  // 65,536
    int*     tki    = (int*)(ws + 131072);         // 1,048,576
    int*     tkc    = (int*)(ws + 1179648);        // 2,048
    ushortT* kcat   = (ushortT*)(ws + 1181696);    // 589,824 fl
    float*   kscale = ws + 1771520;                // 2,048
    float*   qscale = ws + 1773568;                // 65,536
    float*   wts    = ws + 1839104;                // 65,536
    uchar*   qi8    = (uchar*)(ws + 1904640);      // 2,097,152 fl (8 MB bytes)
    uchar*   ki8    = (uchar*)(ws + 4001792);      // 65,536 fl
    // qc_bf persistent through step 11:
    ushortT* qc_bf  = (ushortT*)(ws + 4067328);    // 1,572,864 fl [2a -> read 4, 11]
    // REGION R1 5,640,192..20,844,544, time-multiplexed:
    ushortT* wiq_t  = (ushortT*)(ws + 5640192);    // 3,145,728 fl [2b -> dead after 4]
    float*   kip    = ws + 8785920;                // 4,194,304  [2 -> dead after 3]
    ushortT* qi_bf  = (ushortT*)(ws + 12980224);   // 4,194,304 fl [4 -> dead after 5]
    ushortT* wqb_t  = (ushortT*)(ws + 5640192);    // 4,718,592 fl [10, over wiq_t/kip]
    ushortT* wuk_t  = (ushortT*)(ws + 10358784);   // 1,048,576 fl [10 -> dead after 13]
    ushortT* wuv_t  = (ushortT*)(ws + 11407360);   // 1,048,576 fl [10 -> read at 15]
    ushortT* wo_t   = (ushortT*)(ws + 12980224);   // 4,194,304 fl [10, over qi_bf]
    // score / vbuf slot:
    float*   score  = ws + 20844544;               // 4,194,304 [7 -> dead after 8]
    ushortT* vbuf   = (ushortT*)(ws + 20844544);   // 4,194,304 fl [15 -> 16]
    // persistent tail:
    ushortT* qfull_bf = (ushortT*)(ws + 25038848); // 6,291,456 fl [11 -> 12,13]
    ushortT* qcat   = (ushortT*)(ws + 31330304);   // 18,874,368 fl; o written in place (14)

    // 1. rope tables
    k_rope_tables<<<T_N, 32, 0, stream>>>(positions, cosT, sinT);
    // 2a/2b. bf16 casts for the q-path GEMMs
    k_cast4<<<3072, 256, 0, stream>>>(q_c, qc_bf, T_N * QLORA_N / 4);
    k_tcast<<<dim3(48, 128, 1), 256, 0, stream>>>(W_iq, wiq_t, 4096, 0, 0, 1536, 0);
    // 2. indexer k: hs @ W_ik (2048x128x2048), split-K x16 -> partials (f32, exact)
    gemm128<false><<<dim3(1, 16, 16), 256, 0, stream>>>(
        hs, W_ik, kip, T_N, 128, 128, HID_N, 128, 128, 128, 16384, 262144);
    // 3. sum partials + LN + neox rope + fp8 quant -> ki8 bytes
    k_ki_post16<<<T_N, 128, 0, stream>>>(kip, gamma, beta, cosT, sinT, ki8, kscale);
    // 4. indexer q: qc_bf @ wiq_t (bf16 MFMA) -> qi_bf (2048x4096)
    bgemm<true><<<dim3(32, 16, 1), 256, 0, stream>>>(
        qc_bf, wiq_t, qi_bf, QLORA_N, QLORA_N, QLORA_N, 4096, 0, 0, 0, 1.f);
    // 5. neox rope + fp8 quant -> qi8 bytes
    k_qi_post_bf<<<T_N * IDX_H_N, 128, 0, stream>>>(qi_bf, cosT, sinT, qi8, qscale);
    // 6. indexer weights
    k_wiw<<<T_N, 256, 0, stream>>>(hs, W_iw, qscale, wts);
    // 7. indexer score via fp8 MFMA
    k_score8<<<2080, 256, 0, stream>>>(qi8, ki8, kscale, wts, score);
    // 8. top-512
    k_topk<<<T_N, 256, 0, stream>>>(score, tki, tkc);
    // 9. kv rms_norm + k_pe rope -> kcat bf16
    k_kv_post2<<<T_N, 256, 0, stream>>>(kv_lora, kv_ln, cosT, sinT, kcat);
    // 10. remaining weight transposes (R1 free again)
    k_tcast<<<dim3(48, 192, 1), 256, 0, stream>>>(W_qb, wqb_t, 6144, 0, 0, 1536, 0);
    k_wuk_cast<<<8192, 256, 0, stream>>>(W_kvb, wuk_t);
    k_tcast<<<dim3(16, 4, 32), 256, 0, stream>>>(W_kvb, wuv_t, 8192, 128, 256, 512, 65536);
    k_tcast<<<dim3(128, 64, 1), 256, 0, stream>>>(W_o, wo_t, 2048, 0, 0, 4096, 0);
    // 11. qfull = q_c @ W_qb (bf16 MFMA) -> bf16 (T,32,192)
    bgemm<true><<<dim3(48, 16, 1), 256, 0, stream>>>(
        qc_bf, wqb_t, qfull_bf, QLORA_N, QLORA_N, QLORA_N, 6144, 0, 0, 0, 1.f);
    // 12. rope q_pe -> qcat[...,512:576]
    k_rope_q2<<<T_N * H_N / 8, 256, 0, stream>>>(qfull_bf, cosT, sinT, qcat);
    // 13. q_lat = q_nope @ W_UK^T per head -> qcat[...,0:512] (SCALE folded)
    bgemm<true><<<dim3(4, 16, 32), 256, 0, stream>>>(
        qfull_bf, wuk_t, qcat, NOPE_N, 6144, 128, 18432, 192, 65536, 576, SCALE_F);
    // 14. fused sparse MFMA attention (single-pass) -> o written in place into qcat rows
    k_attn_mfma<<<T_N, 256, 0, stream>>>(qcat, kcat, tki, tkc, qcat);
    // 15. v = o @ W_UV per head -> vbuf bf16 (T,4096)
    bgemm<true><<<dim3(1, 16, 32), 256, 0, stream>>>(
        qcat, wuv_t, vbuf, KVLORA_N, 18432, 512, 4096, 512, 65536, 128, 1.f);
    // 16. out = vbuf @ W_o -> f32
    bgemm<false><<<dim3(16, 16, 1), 256, 0, stream>>>(
        vbuf, wo_t, (float*)d_out, H_N * VD_N, 4096, 4096, HID_N, 0, 0, 0, 1.f);
}